// Round 7
// baseline (2788.892 us; speedup 1.0000x reference)
//
#include <hip/hip_runtime.h>

// ---------------------------------------------------------------------------
// CoSSL round 7: L3/L4 conv -> im2col(bf16) + MFMA GEMM (fp32 accum, fused
// bias+batch-stats epilogue). L1/L2 stay fp32 direct conv. Head unchanged.
// Activations: [p*128+n][c][h][w], p=0 -> q (feats[:,1]), p=1 -> k (feats[:,0]).
// ---------------------------------------------------------------------------

#define NIMG 128
typedef __attribute__((ext_vector_type(8))) short bf16x8;
typedef __attribute__((ext_vector_type(4))) float f32x4;
typedef __attribute__((ext_vector_type(4))) unsigned int u32x4;
typedef unsigned long long ull;

__device__ __forceinline__ unsigned short f2bf(float f) {
  unsigned u = __float_as_uint(f);
  unsigned r = (u + 0x7fffu + ((u >> 16) & 1u)) >> 16;
  return (unsigned short)r;
}

// ---------------- weight prep ------------------------------------------------
// t1/t2: old [(ci*9+tap)][co] fp32 for direct conv.
// wb3: [64][160] bf16, k = tap*16+ci (zeros k>=144). wb4: [128][576], k = tap*64+ci.
__global__ __launch_bounds__(256) void wtr2_k(
    const float* __restrict__ w1, const float* __restrict__ w2,
    const float* __restrict__ w3, const float* __restrict__ w4,
    float* __restrict__ t1, float* __restrict__ t2,
    unsigned short* __restrict__ wb3, unsigned short* __restrict__ wb4) {
  const int i = blockIdx.x * 256 + threadIdx.x;
  if (i < 36) { int co = i / 9, r = i % 9; t1[r * 4 + co] = w1[i]; }
  if (i < 576) { int co = i / 36, r = i % 36; t2[r * 16 + co] = w2[i]; }
  if (i < 64 * 160) {
    int co = i / 160, k = i % 160;
    int tap = k >> 4, ci = k & 15;
    float v = (k < 144) ? w3[co * 144 + ci * 9 + tap] : 0.f;
    wb3[i] = f2bf(v);
  }
  if (i < 128 * 576) {
    int co = i / 576, k = i % 576;
    int tap = k / 64, ci = k & 63;
    wb4[i] = f2bf(w4[co * 576 + ci * 9 + tap]);
  }
}

// ---------------- direct conv (L1/L2) + fused stats --------------------------
template<int Cin, int Cout, int COB, int Hin, int Win, int TH, int CIC, int SPT, bool FIRST>
__global__ __launch_bounds__(256) void conv2_k(const float* __restrict__ in,
    const float* __restrict__ wt, const float* __restrict__ bias,
    float* __restrict__ y, float* __restrict__ st) {
  constexpr int Hout = Hin / 2, Wout = Win / 2, HW = Hout * Wout;
  constexpr int R2 = 2 * TH + 1, W2 = Win + 2;
  constexpr int TILE = CIC * R2 * W2;
  __shared__ float tile[TILE];
  __shared__ float ws1[4][COB], ws2[4][COB];
  const int tid = threadIdx.x;
  const int pn = blockIdx.z;
  const int co0 = blockIdx.y * COB;
  const int h0 = blockIdx.x * TH;
  const int base_ih = 2 * h0 - 1;
  const float* ibase;
  if (FIRST) {
    const int n = pn & 127;
    const int sel = (pn >> 7) == 0 ? 1 : 0;
    ibase = in + (size_t)(n * 2 + sel) * (size_t)(Hin * Win);
  } else {
    ibase = in + (size_t)pn * Cin * (size_t)(Hin * Win);
  }
  int th[SPT], tw[SPT];
#pragma unroll
  for (int s = 0; s < SPT; ++s) {
    const int sp = tid + s * 256;
    th[s] = sp / Wout; tw[s] = sp - th[s] * Wout;
  }
  float acc[COB * SPT];
#pragma unroll
  for (int i = 0; i < COB * SPT; ++i) acc[i] = 0.f;
  for (int st0 = 0; st0 < Cin; st0 += CIC) {
    for (int idx = tid; idx < TILE; idx += 256) {
      const int ci = idx / (R2 * W2);
      const int rem = idx - ci * (R2 * W2);
      const int r = rem / W2;
      const int c = rem - r * W2;
      const int ih = base_ih + r;
      const int iw = c - 1;
      float v = 0.f;
      if (ih >= 0 && iw >= 0 && iw < Win)
        v = ibase[(size_t)(st0 + ci) * (Hin * Win) + ih * Win + iw];
      tile[idx] = v;
    }
    __syncthreads();
    for (int ci = 0; ci < CIC; ++ci) {
      const float* tci = tile + ci * (R2 * W2);
      const size_t wrow = ((size_t)(st0 + ci) * 9) * Cout + co0;
#pragma unroll
      for (int kh = 0; kh < 3; ++kh) {
        float2 fa[SPT], fb[SPT];
#pragma unroll
        for (int s = 0; s < SPT; ++s) {
          const float* p = tci + (2 * th[s] + kh) * W2 + 2 * tw[s];
          fa[s] = *(const float2*)p;
          fb[s] = *(const float2*)(p + 2);
        }
#pragma unroll
        for (int kw = 0; kw < 3; ++kw) {
          const float* wp = wt + wrow + (kh * 3 + kw) * Cout;
#pragma unroll
          for (int co = 0; co < COB; ++co) {
            const float wv = wp[co];
#pragma unroll
            for (int s = 0; s < SPT; ++s) {
              const float fv = (kw == 0) ? fa[s].x : (kw == 1) ? fa[s].y : fb[s].x;
              acc[co * SPT + s] = fmaf(fv, wv, acc[co * SPT + s]);
            }
          }
        }
      }
    }
    __syncthreads();
  }
  const int lane = tid & 63, wid = tid >> 6;
  const int p = pn >> 7;
  const size_t obase = ((size_t)pn * Cout + co0) * (size_t)HW + (size_t)h0 * Wout;
#pragma unroll
  for (int co = 0; co < COB; ++co) {
    const float bv = bias[co0 + co];
    float s1 = 0.f, s2 = 0.f;
#pragma unroll
    for (int s = 0; s < SPT; ++s) {
      const float v = acc[co * SPT + s] + bv;
      y[obase + (size_t)co * HW + tid + s * 256] = v;
      s1 += v; s2 += v * v;
    }
#pragma unroll
    for (int m = 32; m >= 1; m >>= 1) { s1 += __shfl_xor(s1, m); s2 += __shfl_xor(s2, m); }
    if (lane == 0) { ws1[wid][co] = s1; ws2[wid][co] = s2; }
  }
  __syncthreads();
  if (tid < COB) {
    const float t1 = ws1[0][tid] + ws1[1][tid] + ws1[2][tid] + ws1[3][tid];
    const float t2 = ws2[0][tid] + ws2[1][tid] + ws2[2][tid] + ws2[3][tid];
    atomicAdd(&st[p * Cout + co0 + tid], t1);
    atomicAdd(&st[256 + p * Cout + co0 + tid], t2);
  }
}

// ---------------- im2col: X[pnl][Cin][H][W] f32 -> bb[pnl][SP][KP] bf16 ------
// k-order tap-major: k = tap*Cin + ci; zeros for OOB and k >= 9*Cin.
template<int Cin, int H, int W, int KP>
__global__ __launch_bounds__(256) void im2col_k(const float* __restrict__ x,
    unsigned short* __restrict__ bb) {
  constexpr int Ho = H / 2, Wo = W / 2;
  constexpr int SPC = 128;
  const int pnl = blockIdx.y;
  const int sp0 = blockIdx.x * SPC;
  const float* xb = x + (size_t)pnl * Cin * (H * W);
  unsigned short* bbase = bb + ((size_t)pnl * (Ho * Wo)) * KP;
  for (int idx = threadIdx.x; idx < SPC * 9; idx += 256) {
    const int spl = idx / 9, tap = idx - spl * 9;
    const int sp = sp0 + spl;
    const int ho = sp / Wo, wo = sp - ho * Wo;
    const int kh = tap / 3, kw = tap - kh * 3;
    const int ih = 2 * ho - 1 + kh, iw = 2 * wo - 1 + kw;
    unsigned short* dst = bbase + (size_t)sp * KP + tap * Cin;
    if ((unsigned)ih < (unsigned)H && (unsigned)iw < (unsigned)W) {
      const float* src = xb + ih * W + iw;
#pragma unroll
      for (int c0 = 0; c0 < Cin; c0 += 4) {
        ull pk = (ull)f2bf(src[(size_t)(c0 + 0) * (H * W)])
               | ((ull)f2bf(src[(size_t)(c0 + 1) * (H * W)]) << 16)
               | ((ull)f2bf(src[(size_t)(c0 + 2) * (H * W)]) << 32)
               | ((ull)f2bf(src[(size_t)(c0 + 3) * (H * W)]) << 48);
        *(ull*)(dst + c0) = pk;
      }
    } else {
#pragma unroll
      for (int c0 = 0; c0 < Cin; c0 += 4) *(ull*)(dst + c0) = 0ull;
    }
  }
  constexpr int PADK = KP - 9 * Cin;
  if (PADK > 0) {
    for (int idx = threadIdx.x; idx < SPC * PADK; idx += 256) {
      const int spl = idx / PADK, k = 9 * Cin + (idx - spl * PADK);
      bbase[((size_t)(sp0 + spl)) * KP + k] = 0;
    }
  }
}

// ---------------- MFMA conv-GEMM: C[co][sp] = sum_k WB[co][k]*BB[sp][k] ------
// + bias, write Y fp32, fused batch stats. One pnl per blockIdx.y.
template<int M, int SPB, int KP, int KC, int WCO, int WSP, int HWout, int Cout>
__global__ __launch_bounds__(256) void cgemm_k(
    const unsigned short* __restrict__ bb, const unsigned short* __restrict__ wb,
    const float* __restrict__ bias, float* __restrict__ y,
    float* __restrict__ st, int path) {
  constexpr int KCP = KC + 8;
  constexpr int MT = WCO / 16, NT = WSP / 16, KS = KC / 32;
  constexpr int NWN = SPB / WSP;
  __shared__ unsigned short wl[M][KCP];
  __shared__ unsigned short bl[SPB][KCP];
  const int tid = threadIdx.x;
  const int pnl = blockIdx.y;
  const int sp0 = blockIdx.x * SPB;
  const int lane = tid & 63, wid = tid >> 6;
  const int wm = wid / NWN, wn = wid - wm * NWN;
  const int l15 = lane & 15, lg = lane >> 4;
  const unsigned short* bsrc = bb + ((size_t)pnl * HWout + sp0) * KP;

  f32x4 acc[MT][NT];
#pragma unroll
  for (int mt = 0; mt < MT; ++mt)
#pragma unroll
    for (int nt = 0; nt < NT; ++nt) acc[mt][nt] = (f32x4){0.f, 0.f, 0.f, 0.f};

  for (int k0 = 0; k0 < KP; k0 += KC) {
    for (int it = tid; it < M * (KC / 8); it += 256) {
      const int row = it / (KC / 8), seg = it - row * (KC / 8);
      const u32x4 v = *(const u32x4*)(wb + (size_t)row * KP + k0 + seg * 8);
      *(u32x4*)(&wl[row][seg * 8]) = v;
    }
    for (int it = tid; it < SPB * (KC / 8); it += 256) {
      const int row = it / (KC / 8), seg = it - row * (KC / 8);
      const u32x4 v = *(const u32x4*)(bsrc + (size_t)row * KP + k0 + seg * 8);
      *(u32x4*)(&bl[row][seg * 8]) = v;
    }
    __syncthreads();
#pragma unroll
    for (int ks = 0; ks < KS; ++ks) {
      bf16x8 af[MT], bfr[NT];
#pragma unroll
      for (int mt = 0; mt < MT; ++mt)
        af[mt] = *(const bf16x8*)(&wl[wm * WCO + mt * 16 + l15][ks * 32 + lg * 8]);
#pragma unroll
      for (int nt = 0; nt < NT; ++nt)
        bfr[nt] = *(const bf16x8*)(&bl[wn * WSP + nt * 16 + l15][ks * 32 + lg * 8]);
#pragma unroll
      for (int mt = 0; mt < MT; ++mt)
#pragma unroll
        for (int nt = 0; nt < NT; ++nt)
          acc[mt][nt] = __builtin_amdgcn_mfma_f32_16x16x32_bf16(af[mt], bfr[nt], acc[mt][nt], 0, 0, 0);
    }
    __syncthreads();
  }

  // epilogue: bias, Y write (fp32), fused stats (C layout: row=(l>>4)*4+i, col=l&15)
  float* yb = y + (size_t)pnl * Cout * HWout;
#pragma unroll
  for (int mt = 0; mt < MT; ++mt) {
#pragma unroll
    for (int i = 0; i < 4; ++i) {
      const int co = wm * WCO + mt * 16 + lg * 4 + i;
      const float bv = bias[co];
      float s1 = 0.f, s2 = 0.f;
#pragma unroll
      for (int nt = 0; nt < NT; ++nt) {
        const float v = acc[mt][nt][i] + bv;
        yb[(size_t)co * HWout + sp0 + wn * WSP + nt * 16 + l15] = v;
        s1 += v; s2 += v * v;
      }
#pragma unroll
      for (int m = 1; m < 16; m <<= 1) { s1 += __shfl_xor(s1, m); s2 += __shfl_xor(s2, m); }
      if (l15 == 0) {
        atomicAdd(&st[path * Cout + co], s1);
        atomicAdd(&st[256 + path * Cout + co], s2);
      }
    }
  }
}

// ---------------- BN (from fused stats) + relu + 3x3 s1 p1 avgpool ----------
__global__ __launch_bounds__(256) void bnpool2_k(const float* __restrict__ y,
    const float* __restrict__ st, const float* __restrict__ g,
    const float* __restrict__ be, float* __restrict__ x,
    int Cout, int H, int W, float invCnt) {
  const int pn = blockIdx.z, c = blockIdx.y;
  const int HW = H * W;
  const int sp = blockIdx.x * 256 + threadIdx.x;
  if (sp >= HW) return;
  const int h = sp / W, w0 = sp - (sp / W) * W;
  const int p = pn >> 7;
  const float mean = st[p * Cout + c] * invCnt;
  const float var = fmaxf(st[256 + p * Cout + c] * invCnt - mean * mean, 0.f);
  const float a = g[c] * rsqrtf(var + 1e-5f);
  const float b = be[c] - mean * a;
  const float* yp = y + ((size_t)pn * Cout + c) * (size_t)HW;
  float acc = 0.f;
#pragma unroll
  for (int dh = -1; dh <= 1; ++dh) {
    int hh = h + dh;
    if ((unsigned)hh >= (unsigned)H) continue;
#pragma unroll
    for (int dw = -1; dw <= 1; ++dw) {
      int ww = w0 + dw;
      if ((unsigned)ww >= (unsigned)W) continue;
      acc += fmaxf(fmaf(a, yp[hh * W + ww], b), 0.f);
    }
  }
  x[((size_t)pn * Cout + c) * (size_t)HW + sp] = acc * (1.f / 9.f);
}

// ---------------- global mean + l2norm, coalesced; also writes qkT ----------
__global__ __launch_bounds__(256) void feat2_k(const float* __restrict__ x,
    float* __restrict__ qk, float* __restrict__ qkT) {
  const int pn = blockIdx.x;
  const int tid = threadIdx.x;
  const int lane = tid & 63, wid = tid >> 6;
  __shared__ float fm[128];
  __shared__ float red[128];
  const float* xb = x + (size_t)pn * 128 * 512;
  for (int c = wid; c < 128; c += 4) {
    const float* xp = xb + (size_t)c * 512;
    float s = 0.f;
#pragma unroll
    for (int r = 0; r < 8; ++r) s += xp[lane + r * 64];
#pragma unroll
    for (int m = 32; m >= 1; m >>= 1) s += __shfl_xor(s, m);
    if (lane == 0) fm[c] = s * (1.f / 512.f);
  }
  __syncthreads();
  if (tid < 128) red[tid] = fm[tid] * fm[tid];
  __syncthreads();
  for (int step = 64; step > 0; step >>= 1) {
    if (tid < step) red[tid] += red[tid + step];
    __syncthreads();
  }
  const float inv = 1.f / fmaxf(sqrtf(red[0]), 1e-12f);
  if (tid < 128) {
    const float v = fm[tid] * inv;
    qk[(size_t)pn * 128 + tid] = v;
    if (pn < 128) qkT[(size_t)tid * 128 + pn] = v;
  }
}

// ---------------- 1/||ref row|| ---------------------------------------------
__global__ __launch_bounds__(256) void refnorm_k(const float* __restrict__ rf,
    float* __restrict__ rinv) {
  const int n = blockIdx.x;
  float s = 0.f;
  for (int i = threadIdx.x; i < 2304; i += 256) {
    float v = rf[(size_t)n * 2304 + i];
    s += v * v;
  }
  __shared__ float red[256];
  red[threadIdx.x] = s;
  __syncthreads();
  for (int step = 128; step > 0; step >>= 1) {
    if (threadIdx.x < step) red[threadIdx.x] += red[threadIdx.x + step];
    __syncthreads();
  }
  if (threadIdx.x == 0) rinv[n] = 1.f / fmaxf(sqrtf(red[0]), 1e-12f);
}

// ---------------- rfT[k][n] = reff[n][k] * rinv[n] --------------------------
__global__ __launch_bounds__(256) void reft_k(const float* __restrict__ rf,
    const float* __restrict__ rinv, float* __restrict__ rfT) {
  const int flat = blockIdx.x * 256 + threadIdx.x;
  const int n = flat / 2304, k = flat - n * 2304;
  rfT[(size_t)k * 128 + n] = rf[flat] * rinv[n];
}

// ---------------- score_neg = q @ MoCoQueue (8 rows/block) ------------------
__global__ __launch_bounds__(256) void sneg2_k(const float* __restrict__ qkT,
    const float* __restrict__ moco, float* __restrict__ out) {
  const int j = blockIdx.x * 256 + threadIdx.x;
  const int n0 = blockIdx.y * 8;
  float acc[8] = {0.f};
#pragma unroll 4
  for (int k = 0; k < 128; ++k) {
    const float rv = moco[(size_t)k * 2048 + j];
    const float* qp = qkT + (size_t)k * 128 + n0;
#pragma unroll
    for (int i = 0; i < 8; ++i) acc[i] = fmaf(qp[i], rv, acc[i]);
  }
#pragma unroll
  for (int i = 0; i < 8; ++i) out[(size_t)(n0 + i) * 2048 + j] = acc[i];
}

// ---------------- score_ref = rfT^T @ RefQueue (8 rows/block) ---------------
__global__ __launch_bounds__(256) void sref2_k(const float* __restrict__ rfT,
    const float* __restrict__ rq, float* __restrict__ out) {
  const int j = blockIdx.x * 256 + threadIdx.x;
  const int n0 = blockIdx.y * 8;
  float acc[8] = {0.f};
#pragma unroll 4
  for (int k = 0; k < 2304; ++k) {
    const float rv = rq[(size_t)k * 2048 + j];
    const float* rp = rfT + (size_t)k * 128 + n0;
#pragma unroll
    for (int i = 0; i < 8; ++i) acc[i] = fmaf(rp[i], rv, acc[i]);
  }
#pragma unroll
  for (int i = 0; i < 8; ++i) out[(size_t)(n0 + i) * 2048 + j] = acc[i];
}

// ---------------- top-5 per row of masked score_ref -------------------------
__global__ __launch_bounds__(256) void topk_k(const float* __restrict__ sref,
    const float* __restrict__ iq, const int* __restrict__ idxs,
    int* __restrict__ top) {
  const int n = blockIdx.x;
  const float target = (float)idxs[n];
  float vals[8];
#pragma unroll
  for (int r = 0; r < 8; ++r) {
    const int j = threadIdx.x + r * 256;
    const bool m = (iq[j] == target);
    vals[r] = m ? -__builtin_inff() : sref[(size_t)n * 2048 + j];
  }
  __shared__ float sv[256];
  __shared__ int si[256];
  __shared__ int chosen[5];
  for (int rnd = 0; rnd < 5; ++rnd) {
    float bv = -__builtin_inff();
    int bi = 1 << 30;
#pragma unroll
    for (int r = 0; r < 8; ++r) {
      const int j = threadIdx.x + r * 256;
      bool taken = false;
      for (int t = 0; t < rnd; ++t) taken |= (chosen[t] == j);
      const float v = vals[r];
      if (!taken && (v > bv || (v == bv && j < bi))) { bv = v; bi = j; }
    }
    sv[threadIdx.x] = bv; si[threadIdx.x] = bi;
    __syncthreads();
    for (int step = 128; step > 0; step >>= 1) {
      if (threadIdx.x < step) {
        const float ov = sv[threadIdx.x + step];
        const int oi = si[threadIdx.x + step];
        if (ov > sv[threadIdx.x] || (ov == sv[threadIdx.x] && oi < si[threadIdx.x])) {
          sv[threadIdx.x] = ov; si[threadIdx.x] = oi;
        }
      }
      __syncthreads();
    }
    if (threadIdx.x == 0) chosen[rnd] = si[0];
    __syncthreads();
  }
  if (threadIdx.x < 5) top[n * 5 + threadIdx.x] = chosen[threadIdx.x];
}

// ---------------- score_pos + first columns ---------------------------------
__global__ __launch_bounds__(128) void spos_k(const float* __restrict__ qk,
    float* __restrict__ out) {
  const int n = threadIdx.x;
  float s = 0.f;
  for (int c = 0; c < 128; ++c)
    s = fmaf(qk[(size_t)n * 128 + c], qk[(size_t)(NIMG + n) * 128 + c], s);
  out[(size_t)n * 2049] = s;
  out[(size_t)NIMG * 2049 + (size_t)n * 2049] = 1.f;
}

// ---------------- final assembly --------------------------------------------
__global__ __launch_bounds__(256) void asm_k(const float* __restrict__ sneg,
    const float* __restrict__ sref, const float* __restrict__ iq,
    const int* __restrict__ idxs, const int* __restrict__ top,
    float* __restrict__ out) {
  const int n = blockIdx.y;
  const int j = blockIdx.x * 256 + threadIdx.x;
  const int t0 = top[n * 5 + 0], t1 = top[n * 5 + 1], t2 = top[n * 5 + 2];
  const int t3 = top[n * 5 + 3], t4 = top[n * 5 + 4];
  const float target = (float)idxs[n];
  const bool m = (iq[j] == target);
  const float sr = sref[(size_t)n * 2048 + j];
  const float sr2 = m ? 1.f : sr;
  const bool istop = (j == t0) | (j == t1) | (j == t2) | (j == t3) | (j == t4);
  const float wgt = istop ? 1.f : -1.f;
  out[(size_t)n * 2049 + 1 + j] = sneg[(size_t)n * 2048 + j] * sr2 * wgt;
  const float mf = istop ? 1.f : (m ? 1.f : 0.f);
  out[(size_t)NIMG * 2049 + (size_t)n * 2049 + 1 + j] = mf;
}

// ---------------------------------------------------------------------------
extern "C" void kernel_launch(void* const* d_in, const int* in_sizes, int n_in,
                              void* d_out, int out_size, void* d_ws, size_t ws_size,
                              hipStream_t stream) {
  const float* feats = (const float*)d_in[0];
  const float* reff  = (const float*)d_in[1];
  const int*   idxs  = (const int*)d_in[2];
  const float* moco  = (const float*)d_in[3];
  const float* refq  = (const float*)d_in[4];
  const float* iq    = (const float*)d_in[5];
  const float* w[4]  = {(const float*)d_in[6],  (const float*)d_in[10],
                        (const float*)d_in[14], (const float*)d_in[18]};
  const float* b[4]  = {(const float*)d_in[7],  (const float*)d_in[11],
                        (const float*)d_in[15], (const float*)d_in[19]};
  const float* g[4]  = {(const float*)d_in[8],  (const float*)d_in[12],
                        (const float*)d_in[16], (const float*)d_in[20]};
  const float* be[4] = {(const float*)d_in[9],  (const float*)d_in[13],
                        (const float*)d_in[17], (const float*)d_in[21]};
  float* out = (float*)d_out;

  // workspace layout (floats)
  const size_t BIG = 33554432;  // 2*128*131072
  float* X    = (float*)d_ws;
  float* Y    = X + BIG;
  float* ST   = Y + BIG;            // 4 layers x 512
  float* WT1  = ST + 2048;          // 36
  float* WT2  = WT1 + 64;           // 576
  unsigned short* WB3 = (unsigned short*)(WT2 + 640);   // 64*160 bf16
  unsigned short* WB4 = WB3 + 64 * 160;                 // 128*576 bf16
  float* QK   = (float*)(WB4 + 128 * 576);              // 2*128*128
  float* QKT  = QK + 32768;         // 128*128
  float* RINV = QKT + 16384;        // 128
  float* RFT  = RINV + 128;         // 2304*128
  float* SNEG = RFT + 294912;       // 128*2048
  float* SREF = SNEG + 262144;      // 128*2048
  int*   TOP  = (int*)(SREF + 262144);                  // 128*5
  unsigned short* BB = (unsigned short*)(TOP + 256);    // im2col: 128*2048*160 bf16 max

  wtr2_k<<<288, 256, 0, stream>>>(w[0], w[1], w[2], w[3], WT1, WT2, WB3, WB4);
  hipMemsetAsync(ST, 0, 2048 * sizeof(float), stream);

  // ---- layer 1: (1 -> 4), 1024x128 -> 512x64 (fp32 direct) ----
  conv2_k<1, 4, 4, 1024, 128, 8, 1, 2, true>
      <<<dim3(64, 1, 256), 256, 0, stream>>>(feats, WT1, b[0], Y, ST);
  bnpool2_k<<<dim3(128, 4, 256), 256, 0, stream>>>(Y, ST, g[0], be[0], X, 4, 512, 64,
                                                   1.f / (128.f * 32768.f));
  // ---- layer 2: (4 -> 16), 512x64 -> 256x32 (fp32 direct) ----
  conv2_k<4, 16, 16, 512, 64, 16, 2, 2, false>
      <<<dim3(16, 1, 256), 256, 0, stream>>>(X, WT2, b[1], Y, ST + 512);
  bnpool2_k<<<dim3(32, 16, 256), 256, 0, stream>>>(Y, ST + 512, g[1], be[1], X, 16, 256, 32,
                                                   1.f / (128.f * 8192.f));
  // ---- layer 3: (16 -> 64), 256x32 -> 128x16 via MFMA, 2 pn-passes ----
  for (int pass = 0; pass < 2; ++pass) {
    const size_t xo = (size_t)pass * 128 * 16 * 8192;
    const size_t yo = (size_t)pass * 128 * 64 * 2048;
    im2col_k<16, 256, 32, 160><<<dim3(16, 128), 256, 0, stream>>>(X + xo, BB);
    cgemm_k<64, 256, 160, 32, 64, 64, 2048, 64>
        <<<dim3(8, 128), 256, 0, stream>>>(BB, WB3, b[2], Y + yo, ST + 1024, pass);
  }
  bnpool2_k<<<dim3(8, 64, 256), 256, 0, stream>>>(Y, ST + 1024, g[2], be[2], X, 64, 128, 16,
                                                  1.f / (128.f * 2048.f));
  // ---- layer 4: (64 -> 128), 128x16 -> 64x8 via MFMA, 2 pn-passes ----
  for (int pass = 0; pass < 2; ++pass) {
    const size_t xo = (size_t)pass * 128 * 64 * 2048;
    const size_t yo = (size_t)pass * 128 * 128 * 512;
    im2col_k<64, 128, 16, 576><<<dim3(4, 128), 256, 0, stream>>>(X + xo, BB);
    cgemm_k<128, 128, 576, 64, 32, 128, 512, 128>
        <<<dim3(4, 128), 256, 0, stream>>>(BB, WB4, b[3], Y + yo, ST + 1536, pass);
  }
  bnpool2_k<<<dim3(2, 128, 256), 256, 0, stream>>>(Y, ST + 1536, g[3], be[3], X, 128, 64, 8,
                                                   1.f / (128.f * 512.f));

  // ---- head ----
  feat2_k<<<256, 256, 0, stream>>>(X, QK, QKT);
  refnorm_k<<<128, 256, 0, stream>>>(reff, RINV);
  reft_k<<<1152, 256, 0, stream>>>(reff, RINV, RFT);
  sneg2_k<<<dim3(8, 16), 256, 0, stream>>>(QKT, moco, SNEG);
  sref2_k<<<dim3(8, 16), 256, 0, stream>>>(RFT, refq, SREF);
  topk_k<<<128, 256, 0, stream>>>(SREF, iq, idxs, TOP);
  spos_k<<<1, 128, 0, stream>>>(QK, out);
  asm_k<<<dim3(8, 128), 256, 0, stream>>>(SNEG, SREF, iq, idxs, TOP, out);
}

// Round 8
// 1817.895 us; speedup vs baseline: 1.5341x; 1.5341x over previous
//
#include <hip/hip_runtime.h>

// ---------------------------------------------------------------------------
// CoSSL round 8: fix cgemm epilogue — global atomicAdd stats (524K atomics to
// 128 words = 4096-deep serial chains, R7: 510us @ 0.4% MfmaUtil) replaced by
// block-level LDS reduce + deterministic per-block partials + redstat_k.
// L3/L4 = im2col(bf16) + MFMA GEMM. L1/L2 fp32 direct conv. Head unchanged.
// Activations: [p*128+n][c][h][w], p=0 -> q (feats[:,1]), p=1 -> k (feats[:,0]).
// ---------------------------------------------------------------------------

#define NIMG 128
typedef __attribute__((ext_vector_type(8))) short bf16x8;
typedef __attribute__((ext_vector_type(4))) float f32x4;
typedef __attribute__((ext_vector_type(4))) unsigned int u32x4;
typedef unsigned long long ull;

__device__ __forceinline__ unsigned short f2bf(float f) {
  unsigned u = __float_as_uint(f);
  unsigned r = (u + 0x7fffu + ((u >> 16) & 1u)) >> 16;
  return (unsigned short)r;
}

// ---------------- weight prep ------------------------------------------------
__global__ __launch_bounds__(256) void wtr2_k(
    const float* __restrict__ w1, const float* __restrict__ w2,
    const float* __restrict__ w3, const float* __restrict__ w4,
    float* __restrict__ t1, float* __restrict__ t2,
    unsigned short* __restrict__ wb3, unsigned short* __restrict__ wb4) {
  const int i = blockIdx.x * 256 + threadIdx.x;
  if (i < 36) { int co = i / 9, r = i % 9; t1[r * 4 + co] = w1[i]; }
  if (i < 576) { int co = i / 36, r = i % 36; t2[r * 16 + co] = w2[i]; }
  if (i < 64 * 160) {
    int co = i / 160, k = i % 160;
    int tap = k >> 4, ci = k & 15;
    float v = (k < 144) ? w3[co * 144 + ci * 9 + tap] : 0.f;
    wb3[i] = f2bf(v);
  }
  if (i < 128 * 576) {
    int co = i / 576, k = i % 576;
    int tap = k / 64, ci = k & 63;
    wb4[i] = f2bf(w4[co * 576 + ci * 9 + tap]);
  }
}

// ---------------- direct conv (L1/L2) + fused stats --------------------------
template<int Cin, int Cout, int COB, int Hin, int Win, int TH, int CIC, int SPT, bool FIRST>
__global__ __launch_bounds__(256) void conv2_k(const float* __restrict__ in,
    const float* __restrict__ wt, const float* __restrict__ bias,
    float* __restrict__ y, float* __restrict__ st) {
  constexpr int Hout = Hin / 2, Wout = Win / 2, HW = Hout * Wout;
  constexpr int R2 = 2 * TH + 1, W2 = Win + 2;
  constexpr int TILE = CIC * R2 * W2;
  __shared__ float tile[TILE];
  __shared__ float ws1[4][COB], ws2[4][COB];
  const int tid = threadIdx.x;
  const int pn = blockIdx.z;
  const int co0 = blockIdx.y * COB;
  const int h0 = blockIdx.x * TH;
  const int base_ih = 2 * h0 - 1;
  const float* ibase;
  if (FIRST) {
    const int n = pn & 127;
    const int sel = (pn >> 7) == 0 ? 1 : 0;
    ibase = in + (size_t)(n * 2 + sel) * (size_t)(Hin * Win);
  } else {
    ibase = in + (size_t)pn * Cin * (size_t)(Hin * Win);
  }
  int th[SPT], tw[SPT];
#pragma unroll
  for (int s = 0; s < SPT; ++s) {
    const int sp = tid + s * 256;
    th[s] = sp / Wout; tw[s] = sp - th[s] * Wout;
  }
  float acc[COB * SPT];
#pragma unroll
  for (int i = 0; i < COB * SPT; ++i) acc[i] = 0.f;
  for (int st0 = 0; st0 < Cin; st0 += CIC) {
    for (int idx = tid; idx < TILE; idx += 256) {
      const int ci = idx / (R2 * W2);
      const int rem = idx - ci * (R2 * W2);
      const int r = rem / W2;
      const int c = rem - r * W2;
      const int ih = base_ih + r;
      const int iw = c - 1;
      float v = 0.f;
      if (ih >= 0 && iw >= 0 && iw < Win)
        v = ibase[(size_t)(st0 + ci) * (Hin * Win) + ih * Win + iw];
      tile[idx] = v;
    }
    __syncthreads();
    for (int ci = 0; ci < CIC; ++ci) {
      const float* tci = tile + ci * (R2 * W2);
      const size_t wrow = ((size_t)(st0 + ci) * 9) * Cout + co0;
#pragma unroll
      for (int kh = 0; kh < 3; ++kh) {
        float2 fa[SPT], fb[SPT];
#pragma unroll
        for (int s = 0; s < SPT; ++s) {
          const float* p = tci + (2 * th[s] + kh) * W2 + 2 * tw[s];
          fa[s] = *(const float2*)p;
          fb[s] = *(const float2*)(p + 2);
        }
#pragma unroll
        for (int kw = 0; kw < 3; ++kw) {
          const float* wp = wt + wrow + (kh * 3 + kw) * Cout;
#pragma unroll
          for (int co = 0; co < COB; ++co) {
            const float wv = wp[co];
#pragma unroll
            for (int s = 0; s < SPT; ++s) {
              const float fv = (kw == 0) ? fa[s].x : (kw == 1) ? fa[s].y : fb[s].x;
              acc[co * SPT + s] = fmaf(fv, wv, acc[co * SPT + s]);
            }
          }
        }
      }
    }
    __syncthreads();
  }
  const int lane = tid & 63, wid = tid >> 6;
  const int p = pn >> 7;
  const size_t obase = ((size_t)pn * Cout + co0) * (size_t)HW + (size_t)h0 * Wout;
#pragma unroll
  for (int co = 0; co < COB; ++co) {
    const float bv = bias[co0 + co];
    float s1 = 0.f, s2 = 0.f;
#pragma unroll
    for (int s = 0; s < SPT; ++s) {
      const float v = acc[co * SPT + s] + bv;
      y[obase + (size_t)co * HW + tid + s * 256] = v;
      s1 += v; s2 += v * v;
    }
#pragma unroll
    for (int m = 32; m >= 1; m >>= 1) { s1 += __shfl_xor(s1, m); s2 += __shfl_xor(s2, m); }
    if (lane == 0) { ws1[wid][co] = s1; ws2[wid][co] = s2; }
  }
  __syncthreads();
  if (tid < COB) {
    const float t1 = ws1[0][tid] + ws1[1][tid] + ws1[2][tid] + ws1[3][tid];
    const float t2 = ws2[0][tid] + ws2[1][tid] + ws2[2][tid] + ws2[3][tid];
    atomicAdd(&st[p * Cout + co0 + tid], t1);
    atomicAdd(&st[256 + p * Cout + co0 + tid], t2);
  }
}

// ---------------- im2col: X[pnl][Cin][H][W] f32 -> bb[pnl][SP][KP] bf16 ------
template<int Cin, int H, int W, int KP>
__global__ __launch_bounds__(256) void im2col_k(const float* __restrict__ x,
    unsigned short* __restrict__ bb) {
  constexpr int Ho = H / 2, Wo = W / 2;
  constexpr int SPC = 128;
  const int pnl = blockIdx.y;
  const int sp0 = blockIdx.x * SPC;
  const float* xb = x + (size_t)pnl * Cin * (H * W);
  unsigned short* bbase = bb + ((size_t)pnl * (Ho * Wo)) * KP;
  for (int idx = threadIdx.x; idx < SPC * 9; idx += 256) {
    const int spl = idx / 9, tap = idx - spl * 9;
    const int sp = sp0 + spl;
    const int ho = sp / Wo, wo = sp - ho * Wo;
    const int kh = tap / 3, kw = tap - kh * 3;
    const int ih = 2 * ho - 1 + kh, iw = 2 * wo - 1 + kw;
    unsigned short* dst = bbase + (size_t)sp * KP + tap * Cin;
    if ((unsigned)ih < (unsigned)H && (unsigned)iw < (unsigned)W) {
      const float* src = xb + ih * W + iw;
#pragma unroll
      for (int c0 = 0; c0 < Cin; c0 += 4) {
        ull pk = (ull)f2bf(src[(size_t)(c0 + 0) * (H * W)])
               | ((ull)f2bf(src[(size_t)(c0 + 1) * (H * W)]) << 16)
               | ((ull)f2bf(src[(size_t)(c0 + 2) * (H * W)]) << 32)
               | ((ull)f2bf(src[(size_t)(c0 + 3) * (H * W)]) << 48);
        *(ull*)(dst + c0) = pk;
      }
    } else {
#pragma unroll
      for (int c0 = 0; c0 < Cin; c0 += 4) *(ull*)(dst + c0) = 0ull;
    }
  }
  constexpr int PADK = KP - 9 * Cin;
  if (PADK > 0) {
    for (int idx = threadIdx.x; idx < SPC * PADK; idx += 256) {
      const int spl = idx / PADK, k = 9 * Cin + (idx - spl * PADK);
      bbase[((size_t)(sp0 + spl)) * KP + k] = 0;
    }
  }
}

// ---------------- MFMA conv-GEMM + per-block partial stats (NO global atomics)
template<int M, int SPB, int KP, int KC, int WCO, int WSP, int HWout, int Cout>
__global__ __launch_bounds__(256) void cgemm_k(
    const unsigned short* __restrict__ bb, const unsigned short* __restrict__ wb,
    const float* __restrict__ bias, float* __restrict__ y,
    float* __restrict__ part1, float* __restrict__ part2) {
  constexpr int KCP = KC + 8;
  constexpr int MT = WCO / 16, NT = WSP / 16, KS = KC / 32;
  constexpr int NWN = SPB / WSP;
  __shared__ unsigned short wl[M][KCP];
  __shared__ unsigned short bl[SPB][KCP];
  __shared__ float ss1[Cout], ss2[Cout];
  const int tid = threadIdx.x;
  const int pnl = blockIdx.y;
  const int sp0 = blockIdx.x * SPB;
  const int lane = tid & 63, wid = tid >> 6;
  const int wm = wid / NWN, wn = wid - wm * NWN;
  const int l15 = lane & 15, lg = lane >> 4;
  const unsigned short* bsrc = bb + ((size_t)pnl * HWout + sp0) * KP;

  for (int i = tid; i < Cout; i += 256) { ss1[i] = 0.f; ss2[i] = 0.f; }

  f32x4 acc[MT][NT];
#pragma unroll
  for (int mt = 0; mt < MT; ++mt)
#pragma unroll
    for (int nt = 0; nt < NT; ++nt) acc[mt][nt] = (f32x4){0.f, 0.f, 0.f, 0.f};

  for (int k0 = 0; k0 < KP; k0 += KC) {
    for (int it = tid; it < M * (KC / 8); it += 256) {
      const int row = it / (KC / 8), seg = it - row * (KC / 8);
      const u32x4 v = *(const u32x4*)(wb + (size_t)row * KP + k0 + seg * 8);
      *(u32x4*)(&wl[row][seg * 8]) = v;
    }
    for (int it = tid; it < SPB * (KC / 8); it += 256) {
      const int row = it / (KC / 8), seg = it - row * (KC / 8);
      const u32x4 v = *(const u32x4*)(bsrc + (size_t)row * KP + k0 + seg * 8);
      *(u32x4*)(&bl[row][seg * 8]) = v;
    }
    __syncthreads();
#pragma unroll
    for (int ks = 0; ks < KS; ++ks) {
      bf16x8 af[MT], bfr[NT];
#pragma unroll
      for (int mt = 0; mt < MT; ++mt)
        af[mt] = *(const bf16x8*)(&wl[wm * WCO + mt * 16 + l15][ks * 32 + lg * 8]);
#pragma unroll
      for (int nt = 0; nt < NT; ++nt)
        bfr[nt] = *(const bf16x8*)(&bl[wn * WSP + nt * 16 + l15][ks * 32 + lg * 8]);
#pragma unroll
      for (int mt = 0; mt < MT; ++mt)
#pragma unroll
        for (int nt = 0; nt < NT; ++nt)
          acc[mt][nt] = __builtin_amdgcn_mfma_f32_16x16x32_bf16(af[mt], bfr[nt], acc[mt][nt], 0, 0, 0);
    }
    __syncthreads();
  }

  // epilogue: bias, Y write (fp32), LDS-reduced stats -> per-block partials.
  // C layout: row=(l>>4)*4+i, col=l&15.
  float* yb = y + (size_t)pnl * Cout * HWout;
#pragma unroll
  for (int mt = 0; mt < MT; ++mt) {
#pragma unroll
    for (int i = 0; i < 4; ++i) {
      const int co = wm * WCO + mt * 16 + lg * 4 + i;
      const float bv = bias[co];
      float s1 = 0.f, s2 = 0.f;
#pragma unroll
      for (int nt = 0; nt < NT; ++nt) {
        const float v = acc[mt][nt][i] + bv;
        yb[(size_t)co * HWout + sp0 + wn * WSP + nt * 16 + l15] = v;
        s1 += v; s2 += v * v;
      }
#pragma unroll
      for (int m = 1; m < 16; m <<= 1) { s1 += __shfl_xor(s1, m); s2 += __shfl_xor(s2, m); }
      if (l15 == 0) {
        atomicAdd(&ss1[co], s1);   // LDS atomic: <=4 adds per address per block
        atomicAdd(&ss2[co], s2);
      }
    }
  }
  __syncthreads();
  const int blkid = blockIdx.y * gridDim.x + blockIdx.x;
  const int nblk = gridDim.x * gridDim.y;
  for (int i = tid; i < Cout; i += 256) {
    part1[(size_t)i * nblk + blkid] = ss1[i];
    part2[(size_t)i * nblk + blkid] = ss2[i];
  }
}

// ---------------- reduce partials -> st (deterministic) ---------------------
__global__ __launch_bounds__(256) void redstat_k(const float* __restrict__ p1,
    const float* __restrict__ p2, float* __restrict__ st, int path, int Cout,
    int nblk) {
  const int co = blockIdx.x;
  float s1 = 0.f, s2 = 0.f;
  for (int i = threadIdx.x; i < nblk; i += 256) {
    s1 += p1[(size_t)co * nblk + i];
    s2 += p2[(size_t)co * nblk + i];
  }
  __shared__ float r1[256], r2[256];
  r1[threadIdx.x] = s1; r2[threadIdx.x] = s2;
  __syncthreads();
  for (int stp = 128; stp > 0; stp >>= 1) {
    if (threadIdx.x < stp) {
      r1[threadIdx.x] += r1[threadIdx.x + stp];
      r2[threadIdx.x] += r2[threadIdx.x + stp];
    }
    __syncthreads();
  }
  if (threadIdx.x == 0) {
    st[path * Cout + co] = r1[0];
    st[256 + path * Cout + co] = r2[0];
  }
}

// ---------------- BN (from fused stats) + relu + 3x3 s1 p1 avgpool ----------
__global__ __launch_bounds__(256) void bnpool2_k(const float* __restrict__ y,
    const float* __restrict__ st, const float* __restrict__ g,
    const float* __restrict__ be, float* __restrict__ x,
    int Cout, int H, int W, float invCnt) {
  const int pn = blockIdx.z, c = blockIdx.y;
  const int HW = H * W;
  const int sp = blockIdx.x * 256 + threadIdx.x;
  if (sp >= HW) return;
  const int h = sp / W, w0 = sp - (sp / W) * W;
  const int p = pn >> 7;
  const float mean = st[p * Cout + c] * invCnt;
  const float var = fmaxf(st[256 + p * Cout + c] * invCnt - mean * mean, 0.f);
  const float a = g[c] * rsqrtf(var + 1e-5f);
  const float b = be[c] - mean * a;
  const float* yp = y + ((size_t)pn * Cout + c) * (size_t)HW;
  float acc = 0.f;
#pragma unroll
  for (int dh = -1; dh <= 1; ++dh) {
    int hh = h + dh;
    if ((unsigned)hh >= (unsigned)H) continue;
#pragma unroll
    for (int dw = -1; dw <= 1; ++dw) {
      int ww = w0 + dw;
      if ((unsigned)ww >= (unsigned)W) continue;
      acc += fmaxf(fmaf(a, yp[hh * W + ww], b), 0.f);
    }
  }
  x[((size_t)pn * Cout + c) * (size_t)HW + sp] = acc * (1.f / 9.f);
}

// ---------------- global mean + l2norm, coalesced; also writes qkT ----------
__global__ __launch_bounds__(256) void feat2_k(const float* __restrict__ x,
    float* __restrict__ qk, float* __restrict__ qkT) {
  const int pn = blockIdx.x;
  const int tid = threadIdx.x;
  const int lane = tid & 63, wid = tid >> 6;
  __shared__ float fm[128];
  __shared__ float red[128];
  const float* xb = x + (size_t)pn * 128 * 512;
  for (int c = wid; c < 128; c += 4) {
    const float* xp = xb + (size_t)c * 512;
    float s = 0.f;
#pragma unroll
    for (int r = 0; r < 8; ++r) s += xp[lane + r * 64];
#pragma unroll
    for (int m = 32; m >= 1; m >>= 1) s += __shfl_xor(s, m);
    if (lane == 0) fm[c] = s * (1.f / 512.f);
  }
  __syncthreads();
  if (tid < 128) red[tid] = fm[tid] * fm[tid];
  __syncthreads();
  for (int step = 64; step > 0; step >>= 1) {
    if (tid < step) red[tid] += red[tid + step];
    __syncthreads();
  }
  const float inv = 1.f / fmaxf(sqrtf(red[0]), 1e-12f);
  if (tid < 128) {
    const float v = fm[tid] * inv;
    qk[(size_t)pn * 128 + tid] = v;
    if (pn < 128) qkT[(size_t)tid * 128 + pn] = v;
  }
}

// ---------------- 1/||ref row|| ---------------------------------------------
__global__ __launch_bounds__(256) void refnorm_k(const float* __restrict__ rf,
    float* __restrict__ rinv) {
  const int n = blockIdx.x;
  float s = 0.f;
  for (int i = threadIdx.x; i < 2304; i += 256) {
    float v = rf[(size_t)n * 2304 + i];
    s += v * v;
  }
  __shared__ float red[256];
  red[threadIdx.x] = s;
  __syncthreads();
  for (int step = 128; step > 0; step >>= 1) {
    if (threadIdx.x < step) red[threadIdx.x] += red[threadIdx.x + step];
    __syncthreads();
  }
  if (threadIdx.x == 0) rinv[n] = 1.f / fmaxf(sqrtf(red[0]), 1e-12f);
}

// ---------------- rfT[k][n] = reff[n][k] * rinv[n] --------------------------
__global__ __launch_bounds__(256) void reft_k(const float* __restrict__ rf,
    const float* __restrict__ rinv, float* __restrict__ rfT) {
  const int flat = blockIdx.x * 256 + threadIdx.x;
  const int n = flat / 2304, k = flat - n * 2304;
  rfT[(size_t)k * 128 + n] = rf[flat] * rinv[n];
}

// ---------------- score_neg = q @ MoCoQueue (8 rows/block) ------------------
__global__ __launch_bounds__(256) void sneg2_k(const float* __restrict__ qkT,
    const float* __restrict__ moco, float* __restrict__ out) {
  const int j = blockIdx.x * 256 + threadIdx.x;
  const int n0 = blockIdx.y * 8;
  float acc[8] = {0.f};
#pragma unroll 4
  for (int k = 0; k < 128; ++k) {
    const float rv = moco[(size_t)k * 2048 + j];
    const float* qp = qkT + (size_t)k * 128 + n0;
#pragma unroll
    for (int i = 0; i < 8; ++i) acc[i] = fmaf(qp[i], rv, acc[i]);
  }
#pragma unroll
  for (int i = 0; i < 8; ++i) out[(size_t)(n0 + i) * 2048 + j] = acc[i];
}

// ---------------- score_ref = rfT^T @ RefQueue (8 rows/block) ---------------
__global__ __launch_bounds__(256) void sref2_k(const float* __restrict__ rfT,
    const float* __restrict__ rq, float* __restrict__ out) {
  const int j = blockIdx.x * 256 + threadIdx.x;
  const int n0 = blockIdx.y * 8;
  float acc[8] = {0.f};
#pragma unroll 4
  for (int k = 0; k < 2304; ++k) {
    const float rv = rq[(size_t)k * 2048 + j];
    const float* rp = rfT + (size_t)k * 128 + n0;
#pragma unroll
    for (int i = 0; i < 8; ++i) acc[i] = fmaf(rp[i], rv, acc[i]);
  }
#pragma unroll
  for (int i = 0; i < 8; ++i) out[(size_t)(n0 + i) * 2048 + j] = acc[i];
}

// ---------------- top-5 per row of masked score_ref -------------------------
__global__ __launch_bounds__(256) void topk_k(const float* __restrict__ sref,
    const float* __restrict__ iq, const int* __restrict__ idxs,
    int* __restrict__ top) {
  const int n = blockIdx.x;
  const float target = (float)idxs[n];
  float vals[8];
#pragma unroll
  for (int r = 0; r < 8; ++r) {
    const int j = threadIdx.x + r * 256;
    const bool m = (iq[j] == target);
    vals[r] = m ? -__builtin_inff() : sref[(size_t)n * 2048 + j];
  }
  __shared__ float sv[256];
  __shared__ int si[256];
  __shared__ int chosen[5];
  for (int rnd = 0; rnd < 5; ++rnd) {
    float bv = -__builtin_inff();
    int bi = 1 << 30;
#pragma unroll
    for (int r = 0; r < 8; ++r) {
      const int j = threadIdx.x + r * 256;
      bool taken = false;
      for (int t = 0; t < rnd; ++t) taken |= (chosen[t] == j);
      const float v = vals[r];
      if (!taken && (v > bv || (v == bv && j < bi))) { bv = v; bi = j; }
    }
    sv[threadIdx.x] = bv; si[threadIdx.x] = bi;
    __syncthreads();
    for (int step = 128; step > 0; step >>= 1) {
      if (threadIdx.x < step) {
        const float ov = sv[threadIdx.x + step];
        const int oi = si[threadIdx.x + step];
        if (ov > sv[threadIdx.x] || (ov == sv[threadIdx.x] && oi < si[threadIdx.x])) {
          sv[threadIdx.x] = ov; si[threadIdx.x] = oi;
        }
      }
      __syncthreads();
    }
    if (threadIdx.x == 0) chosen[rnd] = si[0];
    __syncthreads();
  }
  if (threadIdx.x < 5) top[n * 5 + threadIdx.x] = chosen[threadIdx.x];
}

// ---------------- score_pos + first columns ---------------------------------
__global__ __launch_bounds__(128) void spos_k(const float* __restrict__ qk,
    float* __restrict__ out) {
  const int n = threadIdx.x;
  float s = 0.f;
  for (int c = 0; c < 128; ++c)
    s = fmaf(qk[(size_t)n * 128 + c], qk[(size_t)(NIMG + n) * 128 + c], s);
  out[(size_t)n * 2049] = s;
  out[(size_t)NIMG * 2049 + (size_t)n * 2049] = 1.f;
}

// ---------------- final assembly --------------------------------------------
__global__ __launch_bounds__(256) void asm_k(const float* __restrict__ sneg,
    const float* __restrict__ sref, const float* __restrict__ iq,
    const int* __restrict__ idxs, const int* __restrict__ top,
    float* __restrict__ out) {
  const int n = blockIdx.y;
  const int j = blockIdx.x * 256 + threadIdx.x;
  const int t0 = top[n * 5 + 0], t1 = top[n * 5 + 1], t2 = top[n * 5 + 2];
  const int t3 = top[n * 5 + 3], t4 = top[n * 5 + 4];
  const float target = (float)idxs[n];
  const bool m = (iq[j] == target);
  const float sr = sref[(size_t)n * 2048 + j];
  const float sr2 = m ? 1.f : sr;
  const bool istop = (j == t0) | (j == t1) | (j == t2) | (j == t3) | (j == t4);
  const float wgt = istop ? 1.f : -1.f;
  out[(size_t)n * 2049 + 1 + j] = sneg[(size_t)n * 2048 + j] * sr2 * wgt;
  const float mf = istop ? 1.f : (m ? 1.f : 0.f);
  out[(size_t)NIMG * 2049 + (size_t)n * 2049 + 1 + j] = mf;
}

// ---------------------------------------------------------------------------
extern "C" void kernel_launch(void* const* d_in, const int* in_sizes, int n_in,
                              void* d_out, int out_size, void* d_ws, size_t ws_size,
                              hipStream_t stream) {
  const float* feats = (const float*)d_in[0];
  const float* reff  = (const float*)d_in[1];
  const int*   idxs  = (const int*)d_in[2];
  const float* moco  = (const float*)d_in[3];
  const float* refq  = (const float*)d_in[4];
  const float* iq    = (const float*)d_in[5];
  const float* w[4]  = {(const float*)d_in[6],  (const float*)d_in[10],
                        (const float*)d_in[14], (const float*)d_in[18]};
  const float* b[4]  = {(const float*)d_in[7],  (const float*)d_in[11],
                        (const float*)d_in[15], (const float*)d_in[19]};
  const float* g[4]  = {(const float*)d_in[8],  (const float*)d_in[12],
                        (const float*)d_in[16], (const float*)d_in[20]};
  const float* be[4] = {(const float*)d_in[9],  (const float*)d_in[13],
                        (const float*)d_in[17], (const float*)d_in[21]};
  float* out = (float*)d_out;

  // workspace layout (floats)
  const size_t BIG = 33554432;  // 2*128*131072
  float* X    = (float*)d_ws;
  float* Y    = X + BIG;
  float* ST   = Y + BIG;            // 4 layers x 512
  float* WT1  = ST + 2048;          // 36
  float* WT2  = WT1 + 64;           // 576
  unsigned short* WB3 = (unsigned short*)(WT2 + 640);   // 64*160 bf16
  unsigned short* WB4 = WB3 + 64 * 160;                 // 128*576 bf16
  float* QK   = (float*)(WB4 + 128 * 576);              // 2*128*128
  float* QKT  = QK + 32768;         // 128*128
  float* RINV = QKT + 16384;        // 128
  float* RFT  = RINV + 128;         // 2304*128
  float* SNEG = RFT + 294912;       // 128*2048
  float* SREF = SNEG + 262144;      // 128*2048
  int*   TOP  = (int*)(SREF + 262144);                  // 128*5
  unsigned short* BB = (unsigned short*)(TOP + 256);    // im2col: 128*2048*160 bf16 max
  // stats partials alias the (dead-until-head) SNEG area: 2 x 65536 floats max
  float* PART1 = SNEG;
  float* PART2 = SNEG + 65536;

  wtr2_k<<<288, 256, 0, stream>>>(w[0], w[1], w[2], w[3], WT1, WT2, WB3, WB4);
  hipMemsetAsync(ST, 0, 2048 * sizeof(float), stream);

  // ---- layer 1: (1 -> 4), 1024x128 -> 512x64 (fp32 direct) ----
  conv2_k<1, 4, 4, 1024, 128, 8, 1, 2, true>
      <<<dim3(64, 1, 256), 256, 0, stream>>>(feats, WT1, b[0], Y, ST);
  bnpool2_k<<<dim3(128, 4, 256), 256, 0, stream>>>(Y, ST, g[0], be[0], X, 4, 512, 64,
                                                   1.f / (128.f * 32768.f));
  // ---- layer 2: (4 -> 16), 512x64 -> 256x32 (fp32 direct) ----
  conv2_k<4, 16, 16, 512, 64, 16, 2, 2, false>
      <<<dim3(16, 1, 256), 256, 0, stream>>>(X, WT2, b[1], Y, ST + 512);
  bnpool2_k<<<dim3(32, 16, 256), 256, 0, stream>>>(Y, ST + 512, g[1], be[1], X, 16, 256, 32,
                                                   1.f / (128.f * 8192.f));
  // ---- layer 3: (16 -> 64), 256x32 -> 128x16 via MFMA, 2 pn-passes ----
  for (int pass = 0; pass < 2; ++pass) {
    const size_t xo = (size_t)pass * 128 * 16 * 8192;
    const size_t yo = (size_t)pass * 128 * 64 * 2048;
    im2col_k<16, 256, 32, 160><<<dim3(16, 128), 256, 0, stream>>>(X + xo, BB);
    cgemm_k<64, 256, 160, 32, 64, 64, 2048, 64>
        <<<dim3(8, 128), 256, 0, stream>>>(BB, WB3, b[2], Y + yo, PART1, PART2);
    redstat_k<<<64, 256, 0, stream>>>(PART1, PART2, ST + 1024, pass, 64, 8 * 128);
  }
  bnpool2_k<<<dim3(8, 64, 256), 256, 0, stream>>>(Y, ST + 1024, g[2], be[2], X, 64, 128, 16,
                                                  1.f / (128.f * 2048.f));
  // ---- layer 4: (64 -> 128), 128x16 -> 64x8 via MFMA, 2 pn-passes ----
  for (int pass = 0; pass < 2; ++pass) {
    const size_t xo = (size_t)pass * 128 * 64 * 2048;
    const size_t yo = (size_t)pass * 128 * 128 * 512;
    im2col_k<64, 128, 16, 576><<<dim3(4, 128), 256, 0, stream>>>(X + xo, BB);
    cgemm_k<128, 128, 576, 64, 32, 128, 512, 128>
        <<<dim3(4, 128), 256, 0, stream>>>(BB, WB4, b[3], Y + yo, PART1, PART2);
    redstat_k<<<128, 256, 0, stream>>>(PART1, PART2, ST + 1536, pass, 128, 4 * 128);
  }
  bnpool2_k<<<dim3(2, 128, 256), 256, 0, stream>>>(Y, ST + 1536, g[3], be[3], X, 128, 64, 8,
                                                   1.f / (128.f * 512.f));

  // ---- head ----
  feat2_k<<<256, 256, 0, stream>>>(X, QK, QKT);
  refnorm_k<<<128, 256, 0, stream>>>(reff, RINV);
  reft_k<<<1152, 256, 0, stream>>>(reff, RINV, RFT);
  sneg2_k<<<dim3(8, 16), 256, 0, stream>>>(QKT, moco, SNEG);
  sref2_k<<<dim3(8, 16), 256, 0, stream>>>(RFT, refq, SREF);
  topk_k<<<128, 256, 0, stream>>>(SREF, iq, idxs, TOP);
  spos_k<<<1, 128, 0, stream>>>(QK, out);
  asm_k<<<dim3(8, 128), 256, 0, stream>>>(SNEG, SREF, iq, idxs, TOP, out);
}

// Round 9
// 1583.470 us; speedup vs baseline: 1.7613x; 1.1480x over previous
//
#include <hip/hip_runtime.h>

// ---------------------------------------------------------------------------
// CoSSL round 9: sref split-K (was: 128 blocks, 2304-deep serial k-loop,
// 290us @ 5.8% occupancy / 3.7% VALU). Now 768 blocks x 384-k chunks +
// reduce. L3/L4 = im2col(bf16)+MFMA+LDS-stats. L1/L2 fp32 direct conv.
// Activations: [p*128+n][c][h][w], p=0 -> q (feats[:,1]), p=1 -> k (feats[:,0]).
// ---------------------------------------------------------------------------

#define NIMG 128
typedef __attribute__((ext_vector_type(8))) short bf16x8;
typedef __attribute__((ext_vector_type(4))) float f32x4;
typedef __attribute__((ext_vector_type(4))) unsigned int u32x4;
typedef unsigned long long ull;

__device__ __forceinline__ unsigned short f2bf(float f) {
  unsigned u = __float_as_uint(f);
  unsigned r = (u + 0x7fffu + ((u >> 16) & 1u)) >> 16;
  return (unsigned short)r;
}

// ---------------- weight prep ------------------------------------------------
__global__ __launch_bounds__(256) void wtr2_k(
    const float* __restrict__ w1, const float* __restrict__ w2,
    const float* __restrict__ w3, const float* __restrict__ w4,
    float* __restrict__ t1, float* __restrict__ t2,
    unsigned short* __restrict__ wb3, unsigned short* __restrict__ wb4) {
  const int i = blockIdx.x * 256 + threadIdx.x;
  if (i < 36) { int co = i / 9, r = i % 9; t1[r * 4 + co] = w1[i]; }
  if (i < 576) { int co = i / 36, r = i % 36; t2[r * 16 + co] = w2[i]; }
  if (i < 64 * 160) {
    int co = i / 160, k = i % 160;
    int tap = k >> 4, ci = k & 15;
    float v = (k < 144) ? w3[co * 144 + ci * 9 + tap] : 0.f;
    wb3[i] = f2bf(v);
  }
  if (i < 128 * 576) {
    int co = i / 576, k = i % 576;
    int tap = k / 64, ci = k & 63;
    wb4[i] = f2bf(w4[co * 576 + ci * 9 + tap]);
  }
}

// ---------------- direct conv (L1/L2) + fused stats --------------------------
template<int Cin, int Cout, int COB, int Hin, int Win, int TH, int CIC, int SPT, bool FIRST>
__global__ __launch_bounds__(256) void conv2_k(const float* __restrict__ in,
    const float* __restrict__ wt, const float* __restrict__ bias,
    float* __restrict__ y, float* __restrict__ st) {
  constexpr int Hout = Hin / 2, Wout = Win / 2, HW = Hout * Wout;
  constexpr int R2 = 2 * TH + 1, W2 = Win + 2;
  constexpr int TILE = CIC * R2 * W2;
  __shared__ float tile[TILE];
  __shared__ float ws1[4][COB], ws2[4][COB];
  const int tid = threadIdx.x;
  const int pn = blockIdx.z;
  const int co0 = blockIdx.y * COB;
  const int h0 = blockIdx.x * TH;
  const int base_ih = 2 * h0 - 1;
  const float* ibase;
  if (FIRST) {
    const int n = pn & 127;
    const int sel = (pn >> 7) == 0 ? 1 : 0;
    ibase = in + (size_t)(n * 2 + sel) * (size_t)(Hin * Win);
  } else {
    ibase = in + (size_t)pn * Cin * (size_t)(Hin * Win);
  }
  int th[SPT], tw[SPT];
#pragma unroll
  for (int s = 0; s < SPT; ++s) {
    const int sp = tid + s * 256;
    th[s] = sp / Wout; tw[s] = sp - th[s] * Wout;
  }
  float acc[COB * SPT];
#pragma unroll
  for (int i = 0; i < COB * SPT; ++i) acc[i] = 0.f;
  for (int st0 = 0; st0 < Cin; st0 += CIC) {
    for (int idx = tid; idx < TILE; idx += 256) {
      const int ci = idx / (R2 * W2);
      const int rem = idx - ci * (R2 * W2);
      const int r = rem / W2;
      const int c = rem - r * W2;
      const int ih = base_ih + r;
      const int iw = c - 1;
      float v = 0.f;
      if (ih >= 0 && iw >= 0 && iw < Win)
        v = ibase[(size_t)(st0 + ci) * (Hin * Win) + ih * Win + iw];
      tile[idx] = v;
    }
    __syncthreads();
    for (int ci = 0; ci < CIC; ++ci) {
      const float* tci = tile + ci * (R2 * W2);
      const size_t wrow = ((size_t)(st0 + ci) * 9) * Cout + co0;
#pragma unroll
      for (int kh = 0; kh < 3; ++kh) {
        float2 fa[SPT], fb[SPT];
#pragma unroll
        for (int s = 0; s < SPT; ++s) {
          const float* p = tci + (2 * th[s] + kh) * W2 + 2 * tw[s];
          fa[s] = *(const float2*)p;
          fb[s] = *(const float2*)(p + 2);
        }
#pragma unroll
        for (int kw = 0; kw < 3; ++kw) {
          const float* wp = wt + wrow + (kh * 3 + kw) * Cout;
#pragma unroll
          for (int co = 0; co < COB; ++co) {
            const float wv = wp[co];
#pragma unroll
            for (int s = 0; s < SPT; ++s) {
              const float fv = (kw == 0) ? fa[s].x : (kw == 1) ? fa[s].y : fb[s].x;
              acc[co * SPT + s] = fmaf(fv, wv, acc[co * SPT + s]);
            }
          }
        }
      }
    }
    __syncthreads();
  }
  const int lane = tid & 63, wid = tid >> 6;
  const int p = pn >> 7;
  const size_t obase = ((size_t)pn * Cout + co0) * (size_t)HW + (size_t)h0 * Wout;
#pragma unroll
  for (int co = 0; co < COB; ++co) {
    const float bv = bias[co0 + co];
    float s1 = 0.f, s2 = 0.f;
#pragma unroll
    for (int s = 0; s < SPT; ++s) {
      const float v = acc[co * SPT + s] + bv;
      y[obase + (size_t)co * HW + tid + s * 256] = v;
      s1 += v; s2 += v * v;
    }
#pragma unroll
    for (int m = 32; m >= 1; m >>= 1) { s1 += __shfl_xor(s1, m); s2 += __shfl_xor(s2, m); }
    if (lane == 0) { ws1[wid][co] = s1; ws2[wid][co] = s2; }
  }
  __syncthreads();
  if (tid < COB) {
    const float t1 = ws1[0][tid] + ws1[1][tid] + ws1[2][tid] + ws1[3][tid];
    const float t2 = ws2[0][tid] + ws2[1][tid] + ws2[2][tid] + ws2[3][tid];
    atomicAdd(&st[p * Cout + co0 + tid], t1);
    atomicAdd(&st[256 + p * Cout + co0 + tid], t2);
  }
}

// ---------------- im2col: X[pnl][Cin][H][W] f32 -> bb[pnl][SP][KP] bf16 ------
template<int Cin, int H, int W, int KP>
__global__ __launch_bounds__(256) void im2col_k(const float* __restrict__ x,
    unsigned short* __restrict__ bb) {
  constexpr int Ho = H / 2, Wo = W / 2;
  constexpr int SPC = 128;
  const int pnl = blockIdx.y;
  const int sp0 = blockIdx.x * SPC;
  const float* xb = x + (size_t)pnl * Cin * (H * W);
  unsigned short* bbase = bb + ((size_t)pnl * (Ho * Wo)) * KP;
  for (int idx = threadIdx.x; idx < SPC * 9; idx += 256) {
    const int spl = idx / 9, tap = idx - spl * 9;
    const int sp = sp0 + spl;
    const int ho = sp / Wo, wo = sp - ho * Wo;
    const int kh = tap / 3, kw = tap - kh * 3;
    const int ih = 2 * ho - 1 + kh, iw = 2 * wo - 1 + kw;
    unsigned short* dst = bbase + (size_t)sp * KP + tap * Cin;
    if ((unsigned)ih < (unsigned)H && (unsigned)iw < (unsigned)W) {
      const float* src = xb + ih * W + iw;
#pragma unroll
      for (int c0 = 0; c0 < Cin; c0 += 4) {
        ull pk = (ull)f2bf(src[(size_t)(c0 + 0) * (H * W)])
               | ((ull)f2bf(src[(size_t)(c0 + 1) * (H * W)]) << 16)
               | ((ull)f2bf(src[(size_t)(c0 + 2) * (H * W)]) << 32)
               | ((ull)f2bf(src[(size_t)(c0 + 3) * (H * W)]) << 48);
        *(ull*)(dst + c0) = pk;
      }
    } else {
#pragma unroll
      for (int c0 = 0; c0 < Cin; c0 += 4) *(ull*)(dst + c0) = 0ull;
    }
  }
  constexpr int PADK = KP - 9 * Cin;
  if (PADK > 0) {
    for (int idx = threadIdx.x; idx < SPC * PADK; idx += 256) {
      const int spl = idx / PADK, k = 9 * Cin + (idx - spl * PADK);
      bbase[((size_t)(sp0 + spl)) * KP + k] = 0;
    }
  }
}

// ---------------- MFMA conv-GEMM + per-block partial stats ------------------
template<int M, int SPB, int KP, int KC, int WCO, int WSP, int HWout, int Cout>
__global__ __launch_bounds__(256) void cgemm_k(
    const unsigned short* __restrict__ bb, const unsigned short* __restrict__ wb,
    const float* __restrict__ bias, float* __restrict__ y,
    float* __restrict__ part1, float* __restrict__ part2) {
  constexpr int KCP = KC + 8;
  constexpr int MT = WCO / 16, NT = WSP / 16, KS = KC / 32;
  constexpr int NWN = SPB / WSP;
  __shared__ unsigned short wl[M][KCP];
  __shared__ unsigned short bl[SPB][KCP];
  __shared__ float ss1[Cout], ss2[Cout];
  const int tid = threadIdx.x;
  const int pnl = blockIdx.y;
  const int sp0 = blockIdx.x * SPB;
  const int lane = tid & 63, wid = tid >> 6;
  const int wm = wid / NWN, wn = wid - wm * NWN;
  const int l15 = lane & 15, lg = lane >> 4;
  const unsigned short* bsrc = bb + ((size_t)pnl * HWout + sp0) * KP;

  for (int i = tid; i < Cout; i += 256) { ss1[i] = 0.f; ss2[i] = 0.f; }

  f32x4 acc[MT][NT];
#pragma unroll
  for (int mt = 0; mt < MT; ++mt)
#pragma unroll
    for (int nt = 0; nt < NT; ++nt) acc[mt][nt] = (f32x4){0.f, 0.f, 0.f, 0.f};

  for (int k0 = 0; k0 < KP; k0 += KC) {
    for (int it = tid; it < M * (KC / 8); it += 256) {
      const int row = it / (KC / 8), seg = it - row * (KC / 8);
      const u32x4 v = *(const u32x4*)(wb + (size_t)row * KP + k0 + seg * 8);
      *(u32x4*)(&wl[row][seg * 8]) = v;
    }
    for (int it = tid; it < SPB * (KC / 8); it += 256) {
      const int row = it / (KC / 8), seg = it - row * (KC / 8);
      const u32x4 v = *(const u32x4*)(bsrc + (size_t)row * KP + k0 + seg * 8);
      *(u32x4*)(&bl[row][seg * 8]) = v;
    }
    __syncthreads();
#pragma unroll
    for (int ks = 0; ks < KS; ++ks) {
      bf16x8 af[MT], bfr[NT];
#pragma unroll
      for (int mt = 0; mt < MT; ++mt)
        af[mt] = *(const bf16x8*)(&wl[wm * WCO + mt * 16 + l15][ks * 32 + lg * 8]);
#pragma unroll
      for (int nt = 0; nt < NT; ++nt)
        bfr[nt] = *(const bf16x8*)(&bl[wn * WSP + nt * 16 + l15][ks * 32 + lg * 8]);
#pragma unroll
      for (int mt = 0; mt < MT; ++mt)
#pragma unroll
        for (int nt = 0; nt < NT; ++nt)
          acc[mt][nt] = __builtin_amdgcn_mfma_f32_16x16x32_bf16(af[mt], bfr[nt], acc[mt][nt], 0, 0, 0);
    }
    __syncthreads();
  }

  float* yb = y + (size_t)pnl * Cout * HWout;
#pragma unroll
  for (int mt = 0; mt < MT; ++mt) {
#pragma unroll
    for (int i = 0; i < 4; ++i) {
      const int co = wm * WCO + mt * 16 + lg * 4 + i;
      const float bv = bias[co];
      float s1 = 0.f, s2 = 0.f;
#pragma unroll
      for (int nt = 0; nt < NT; ++nt) {
        const float v = acc[mt][nt][i] + bv;
        yb[(size_t)co * HWout + sp0 + wn * WSP + nt * 16 + l15] = v;
        s1 += v; s2 += v * v;
      }
#pragma unroll
      for (int m = 1; m < 16; m <<= 1) { s1 += __shfl_xor(s1, m); s2 += __shfl_xor(s2, m); }
      if (l15 == 0) {
        atomicAdd(&ss1[co], s1);
        atomicAdd(&ss2[co], s2);
      }
    }
  }
  __syncthreads();
  const int blkid = blockIdx.y * gridDim.x + blockIdx.x;
  const int nblk = gridDim.x * gridDim.y;
  for (int i = tid; i < Cout; i += 256) {
    part1[(size_t)i * nblk + blkid] = ss1[i];
    part2[(size_t)i * nblk + blkid] = ss2[i];
  }
}

// ---------------- reduce partials -> st (deterministic) ---------------------
__global__ __launch_bounds__(256) void redstat_k(const float* __restrict__ p1,
    const float* __restrict__ p2, float* __restrict__ st, int path, int Cout,
    int nblk) {
  const int co = blockIdx.x;
  float s1 = 0.f, s2 = 0.f;
  for (int i = threadIdx.x; i < nblk; i += 256) {
    s1 += p1[(size_t)co * nblk + i];
    s2 += p2[(size_t)co * nblk + i];
  }
  __shared__ float r1[256], r2[256];
  r1[threadIdx.x] = s1; r2[threadIdx.x] = s2;
  __syncthreads();
  for (int stp = 128; stp > 0; stp >>= 1) {
    if (threadIdx.x < stp) {
      r1[threadIdx.x] += r1[threadIdx.x + stp];
      r2[threadIdx.x] += r2[threadIdx.x + stp];
    }
    __syncthreads();
  }
  if (threadIdx.x == 0) {
    st[path * Cout + co] = r1[0];
    st[256 + path * Cout + co] = r2[0];
  }
}

// ---------------- BN (from fused stats) + relu + 3x3 s1 p1 avgpool ----------
__global__ __launch_bounds__(256) void bnpool2_k(const float* __restrict__ y,
    const float* __restrict__ st, const float* __restrict__ g,
    const float* __restrict__ be, float* __restrict__ x,
    int Cout, int H, int W, float invCnt) {
  const int pn = blockIdx.z, c = blockIdx.y;
  const int HW = H * W;
  const int sp = blockIdx.x * 256 + threadIdx.x;
  if (sp >= HW) return;
  const int h = sp / W, w0 = sp - (sp / W) * W;
  const int p = pn >> 7;
  const float mean = st[p * Cout + c] * invCnt;
  const float var = fmaxf(st[256 + p * Cout + c] * invCnt - mean * mean, 0.f);
  const float a = g[c] * rsqrtf(var + 1e-5f);
  const float b = be[c] - mean * a;
  const float* yp = y + ((size_t)pn * Cout + c) * (size_t)HW;
  float acc = 0.f;
#pragma unroll
  for (int dh = -1; dh <= 1; ++dh) {
    int hh = h + dh;
    if ((unsigned)hh >= (unsigned)H) continue;
#pragma unroll
    for (int dw = -1; dw <= 1; ++dw) {
      int ww = w0 + dw;
      if ((unsigned)ww >= (unsigned)W) continue;
      acc += fmaxf(fmaf(a, yp[hh * W + ww], b), 0.f);
    }
  }
  x[((size_t)pn * Cout + c) * (size_t)HW + sp] = acc * (1.f / 9.f);
}

// ---------------- global mean + l2norm, coalesced; also writes qkT ----------
__global__ __launch_bounds__(256) void feat2_k(const float* __restrict__ x,
    float* __restrict__ qk, float* __restrict__ qkT) {
  const int pn = blockIdx.x;
  const int tid = threadIdx.x;
  const int lane = tid & 63, wid = tid >> 6;
  __shared__ float fm[128];
  __shared__ float red[128];
  const float* xb = x + (size_t)pn * 128 * 512;
  for (int c = wid; c < 128; c += 4) {
    const float* xp = xb + (size_t)c * 512;
    float s = 0.f;
#pragma unroll
    for (int r = 0; r < 8; ++r) s += xp[lane + r * 64];
#pragma unroll
    for (int m = 32; m >= 1; m >>= 1) s += __shfl_xor(s, m);
    if (lane == 0) fm[c] = s * (1.f / 512.f);
  }
  __syncthreads();
  if (tid < 128) red[tid] = fm[tid] * fm[tid];
  __syncthreads();
  for (int step = 64; step > 0; step >>= 1) {
    if (tid < step) red[tid] += red[tid + step];
    __syncthreads();
  }
  const float inv = 1.f / fmaxf(sqrtf(red[0]), 1e-12f);
  if (tid < 128) {
    const float v = fm[tid] * inv;
    qk[(size_t)pn * 128 + tid] = v;
    if (pn < 128) qkT[(size_t)tid * 128 + pn] = v;
  }
}

// ---------------- 1/||ref row|| ---------------------------------------------
__global__ __launch_bounds__(256) void refnorm_k(const float* __restrict__ rf,
    float* __restrict__ rinv) {
  const int n = blockIdx.x;
  float s = 0.f;
  for (int i = threadIdx.x; i < 2304; i += 256) {
    float v = rf[(size_t)n * 2304 + i];
    s += v * v;
  }
  __shared__ float red[256];
  red[threadIdx.x] = s;
  __syncthreads();
  for (int step = 128; step > 0; step >>= 1) {
    if (threadIdx.x < step) red[threadIdx.x] += red[threadIdx.x + step];
    __syncthreads();
  }
  if (threadIdx.x == 0) rinv[n] = 1.f / fmaxf(sqrtf(red[0]), 1e-12f);
}

// ---------------- rfT[k][n] = reff[n][k] * rinv[n] --------------------------
__global__ __launch_bounds__(256) void reft_k(const float* __restrict__ rf,
    const float* __restrict__ rinv, float* __restrict__ rfT) {
  const int flat = blockIdx.x * 256 + threadIdx.x;
  const int n = flat / 2304, k = flat - n * 2304;
  rfT[(size_t)k * 128 + n] = rf[flat] * rinv[n];
}

// ---------------- score_neg = q @ MoCoQueue (8 rows/block) ------------------
__global__ __launch_bounds__(256) void sneg2_k(const float* __restrict__ qkT,
    const float* __restrict__ moco, float* __restrict__ out) {
  const int j = blockIdx.x * 256 + threadIdx.x;
  const int n0 = blockIdx.y * 8;
  float acc[8] = {0.f};
#pragma unroll 4
  for (int k = 0; k < 128; ++k) {
    const float rv = moco[(size_t)k * 2048 + j];
    const float* qp = qkT + (size_t)k * 128 + n0;
#pragma unroll
    for (int i = 0; i < 8; ++i) acc[i] = fmaf(qp[i], rv, acc[i]);
  }
#pragma unroll
  for (int i = 0; i < 8; ++i) out[(size_t)(n0 + i) * 2048 + j] = acc[i];
}

// ---------------- score_ref split-K: partial over k-chunk -------------------
// part[c][n][j] = sum_{k in chunk c} rfT[k][n]*rq[k][j]
template<int KCH>
__global__ __launch_bounds__(256) void sref3_k(const float* __restrict__ rfT,
    const float* __restrict__ rq, float* __restrict__ part) {
  const int j = blockIdx.x * 256 + threadIdx.x;
  const int n0 = blockIdx.y * 8;
  const int kc = blockIdx.z;
  const int kbeg = kc * KCH;
  float acc[8] = {0.f};
#pragma unroll 4
  for (int k = kbeg; k < kbeg + KCH; ++k) {
    const float rv = rq[(size_t)k * 2048 + j];
    const float* rp = rfT + (size_t)k * 128 + n0;
#pragma unroll
    for (int i = 0; i < 8; ++i) acc[i] = fmaf(rp[i], rv, acc[i]);
  }
  float* pb = part + (size_t)kc * (128 * 2048);
#pragma unroll
  for (int i = 0; i < 8; ++i) pb[(size_t)(n0 + i) * 2048 + j] = acc[i];
}

// ---------------- reduce split-K partials -> SREF ---------------------------
template<int NCH>
__global__ __launch_bounds__(256) void sredr_k(const float* __restrict__ part,
    float* __restrict__ out) {
  const int j = blockIdx.x * 256 + threadIdx.x;
  const int n = blockIdx.y;
  const size_t off = (size_t)n * 2048 + j;
  float s = 0.f;
#pragma unroll
  for (int c = 0; c < NCH; ++c) s += part[(size_t)c * (128 * 2048) + off];
  out[off] = s;
}

// ---------------- top-5 per row of masked score_ref -------------------------
__global__ __launch_bounds__(256) void topk_k(const float* __restrict__ sref,
    const float* __restrict__ iq, const int* __restrict__ idxs,
    int* __restrict__ top) {
  const int n = blockIdx.x;
  const float target = (float)idxs[n];
  float vals[8];
#pragma unroll
  for (int r = 0; r < 8; ++r) {
    const int j = threadIdx.x + r * 256;
    const bool m = (iq[j] == target);
    vals[r] = m ? -__builtin_inff() : sref[(size_t)n * 2048 + j];
  }
  __shared__ float sv[256];
  __shared__ int si[256];
  __shared__ int chosen[5];
  for (int rnd = 0; rnd < 5; ++rnd) {
    float bv = -__builtin_inff();
    int bi = 1 << 30;
#pragma unroll
    for (int r = 0; r < 8; ++r) {
      const int j = threadIdx.x + r * 256;
      bool taken = false;
      for (int t = 0; t < rnd; ++t) taken |= (chosen[t] == j);
      const float v = vals[r];
      if (!taken && (v > bv || (v == bv && j < bi))) { bv = v; bi = j; }
    }
    sv[threadIdx.x] = bv; si[threadIdx.x] = bi;
    __syncthreads();
    for (int step = 128; step > 0; step >>= 1) {
      if (threadIdx.x < step) {
        const float ov = sv[threadIdx.x + step];
        const int oi = si[threadIdx.x + step];
        if (ov > sv[threadIdx.x] || (ov == sv[threadIdx.x] && oi < si[threadIdx.x])) {
          sv[threadIdx.x] = ov; si[threadIdx.x] = oi;
        }
      }
      __syncthreads();
    }
    if (threadIdx.x == 0) chosen[rnd] = si[0];
    __syncthreads();
  }
  if (threadIdx.x < 5) top[n * 5 + threadIdx.x] = chosen[threadIdx.x];
}

// ---------------- score_pos + first columns ---------------------------------
__global__ __launch_bounds__(128) void spos_k(const float* __restrict__ qk,
    float* __restrict__ out) {
  const int n = threadIdx.x;
  float s = 0.f;
  for (int c = 0; c < 128; ++c)
    s = fmaf(qk[(size_t)n * 128 + c], qk[(size_t)(NIMG + n) * 128 + c], s);
  out[(size_t)n * 2049] = s;
  out[(size_t)NIMG * 2049 + (size_t)n * 2049] = 1.f;
}

// ---------------- final assembly --------------------------------------------
__global__ __launch_bounds__(256) void asm_k(const float* __restrict__ sneg,
    const float* __restrict__ sref, const float* __restrict__ iq,
    const int* __restrict__ idxs, const int* __restrict__ top,
    float* __restrict__ out) {
  const int n = blockIdx.y;
  const int j = blockIdx.x * 256 + threadIdx.x;
  const int t0 = top[n * 5 + 0], t1 = top[n * 5 + 1], t2 = top[n * 5 + 2];
  const int t3 = top[n * 5 + 3], t4 = top[n * 5 + 4];
  const float target = (float)idxs[n];
  const bool m = (iq[j] == target);
  const float sr = sref[(size_t)n * 2048 + j];
  const float sr2 = m ? 1.f : sr;
  const bool istop = (j == t0) | (j == t1) | (j == t2) | (j == t3) | (j == t4);
  const float wgt = istop ? 1.f : -1.f;
  out[(size_t)n * 2049 + 1 + j] = sneg[(size_t)n * 2048 + j] * sr2 * wgt;
  const float mf = istop ? 1.f : (m ? 1.f : 0.f);
  out[(size_t)NIMG * 2049 + (size_t)n * 2049 + 1 + j] = mf;
}

// ---------------------------------------------------------------------------
extern "C" void kernel_launch(void* const* d_in, const int* in_sizes, int n_in,
                              void* d_out, int out_size, void* d_ws, size_t ws_size,
                              hipStream_t stream) {
  const float* feats = (const float*)d_in[0];
  const float* reff  = (const float*)d_in[1];
  const int*   idxs  = (const int*)d_in[2];
  const float* moco  = (const float*)d_in[3];
  const float* refq  = (const float*)d_in[4];
  const float* iq    = (const float*)d_in[5];
  const float* w[4]  = {(const float*)d_in[6],  (const float*)d_in[10],
                        (const float*)d_in[14], (const float*)d_in[18]};
  const float* b[4]  = {(const float*)d_in[7],  (const float*)d_in[11],
                        (const float*)d_in[15], (const float*)d_in[19]};
  const float* g[4]  = {(const float*)d_in[8],  (const float*)d_in[12],
                        (const float*)d_in[16], (const float*)d_in[20]};
  const float* be[4] = {(const float*)d_in[9],  (const float*)d_in[13],
                        (const float*)d_in[17], (const float*)d_in[21]};
  float* out = (float*)d_out;

  // workspace layout (floats)
  const size_t BIG = 33554432;  // 2*128*131072
  float* X    = (float*)d_ws;
  float* Y    = X + BIG;
  float* ST   = Y + BIG;            // 4 layers x 512
  float* WT1  = ST + 2048;          // 36
  float* WT2  = WT1 + 64;           // 576
  unsigned short* WB3 = (unsigned short*)(WT2 + 640);   // 64*160 bf16
  unsigned short* WB4 = WB3 + 64 * 160;                 // 128*576 bf16
  float* QK   = (float*)(WB4 + 128 * 576);              // 2*128*128
  float* QKT  = QK + 32768;         // 128*128
  float* RINV = QKT + 16384;        // 128
  float* RFT  = RINV + 128;         // 2304*128
  float* SNEG = RFT + 294912;       // 128*2048
  float* SREF = SNEG + 262144;      // 128*2048
  int*   TOP  = (int*)(SREF + 262144);                  // 128*5
  unsigned short* BB = (unsigned short*)(TOP + 256);    // im2col: 83.9 MB max
  // cgemm stats partials alias the (dead-until-head) SNEG area
  float* PART1 = SNEG;
  float* PART2 = SNEG + 65536;
  // sref split-K partials alias the (dead-after-L4) BB area: 6 x 1M floats
  float* SPART = (float*)BB;

  wtr2_k<<<288, 256, 0, stream>>>(w[0], w[1], w[2], w[3], WT1, WT2, WB3, WB4);
  hipMemsetAsync(ST, 0, 2048 * sizeof(float), stream);

  // ---- layer 1: (1 -> 4), 1024x128 -> 512x64 (fp32 direct) ----
  conv2_k<1, 4, 4, 1024, 128, 8, 1, 2, true>
      <<<dim3(64, 1, 256), 256, 0, stream>>>(feats, WT1, b[0], Y, ST);
  bnpool2_k<<<dim3(128, 4, 256), 256, 0, stream>>>(Y, ST, g[0], be[0], X, 4, 512, 64,
                                                   1.f / (128.f * 32768.f));
  // ---- layer 2: (4 -> 16), 512x64 -> 256x32 (fp32 direct) ----
  conv2_k<4, 16, 16, 512, 64, 16, 2, 2, false>
      <<<dim3(16, 1, 256), 256, 0, stream>>>(X, WT2, b[1], Y, ST + 512);
  bnpool2_k<<<dim3(32, 16, 256), 256, 0, stream>>>(Y, ST + 512, g[1], be[1], X, 16, 256, 32,
                                                   1.f / (128.f * 8192.f));
  // ---- layer 3: (16 -> 64), 256x32 -> 128x16 via MFMA, 2 pn-passes ----
  for (int pass = 0; pass < 2; ++pass) {
    const size_t xo = (size_t)pass * 128 * 16 * 8192;
    const size_t yo = (size_t)pass * 128 * 64 * 2048;
    im2col_k<16, 256, 32, 160><<<dim3(16, 128), 256, 0, stream>>>(X + xo, BB);
    cgemm_k<64, 256, 160, 32, 64, 64, 2048, 64>
        <<<dim3(8, 128), 256, 0, stream>>>(BB, WB3, b[2], Y + yo, PART1, PART2);
    redstat_k<<<64, 256, 0, stream>>>(PART1, PART2, ST + 1024, pass, 64, 8 * 128);
  }
  bnpool2_k<<<dim3(8, 64, 256), 256, 0, stream>>>(Y, ST + 1024, g[2], be[2], X, 64, 128, 16,
                                                  1.f / (128.f * 2048.f));
  // ---- layer 4: (64 -> 128), 128x16 -> 64x8 via MFMA, 2 pn-passes ----
  for (int pass = 0; pass < 2; ++pass) {
    const size_t xo = (size_t)pass * 128 * 64 * 2048;
    const size_t yo = (size_t)pass * 128 * 128 * 512;
    im2col_k<64, 128, 16, 576><<<dim3(4, 128), 256, 0, stream>>>(X + xo, BB);
    cgemm_k<128, 128, 576, 64, 32, 128, 512, 128>
        <<<dim3(4, 128), 256, 0, stream>>>(BB, WB4, b[3], Y + yo, PART1, PART2);
    redstat_k<<<128, 256, 0, stream>>>(PART1, PART2, ST + 1536, pass, 128, 4 * 128);
  }
  bnpool2_k<<<dim3(2, 128, 256), 256, 0, stream>>>(Y, ST + 1536, g[3], be[3], X, 128, 64, 8,
                                                   1.f / (128.f * 512.f));

  // ---- head ----
  feat2_k<<<256, 256, 0, stream>>>(X, QK, QKT);
  refnorm_k<<<128, 256, 0, stream>>>(reff, RINV);
  reft_k<<<1152, 256, 0, stream>>>(reff, RINV, RFT);
  sneg2_k<<<dim3(8, 16), 256, 0, stream>>>(QKT, moco, SNEG);
  sref3_k<384><<<dim3(8, 16, 6), 256, 0, stream>>>(RFT, refq, SPART);
  sredr_k<6><<<dim3(8, 128), 256, 0, stream>>>(SPART, SREF);
  topk_k<<<128, 256, 0, stream>>>(SREF, iq, idxs, TOP);
  spos_k<<<1, 128, 0, stream>>>(QK, out);
  asm_k<<<dim3(8, 128), 256, 0, stream>>>(SNEG, SREF, iq, idxs, TOP, out);
}

// Round 11
// 1440.378 us; speedup vs baseline: 1.9362x; 1.0993x over previous
//
#include <hip/hip_runtime.h>

// ---------------------------------------------------------------------------
// CoSSL round 11 (resubmit of R10 after container infra failure):
// conv2_k stats -> per-block partials + redstat (no global atomic chains).
// L3/L4 = im2col(bf16)+MFMA. sref split-K. Head otherwise unchanged.
// Activations: [p*128+n][c][h][w], p=0 -> q (feats[:,1]), p=1 -> k (feats[:,0]).
// ---------------------------------------------------------------------------

#define NIMG 128
typedef __attribute__((ext_vector_type(8))) short bf16x8;
typedef __attribute__((ext_vector_type(4))) float f32x4;
typedef __attribute__((ext_vector_type(4))) unsigned int u32x4;
typedef unsigned long long ull;

__device__ __forceinline__ unsigned short f2bf(float f) {
  unsigned u = __float_as_uint(f);
  unsigned r = (u + 0x7fffu + ((u >> 16) & 1u)) >> 16;
  return (unsigned short)r;
}

// ---------------- weight prep ------------------------------------------------
__global__ __launch_bounds__(256) void wtr2_k(
    const float* __restrict__ w1, const float* __restrict__ w2,
    const float* __restrict__ w3, const float* __restrict__ w4,
    float* __restrict__ t1, float* __restrict__ t2,
    unsigned short* __restrict__ wb3, unsigned short* __restrict__ wb4) {
  const int i = blockIdx.x * 256 + threadIdx.x;
  if (i < 36) { int co = i / 9, r = i % 9; t1[r * 4 + co] = w1[i]; }
  if (i < 576) { int co = i / 36, r = i % 36; t2[r * 16 + co] = w2[i]; }
  if (i < 64 * 160) {
    int co = i / 160, k = i % 160;
    int tap = k >> 4, ci = k & 15;
    float v = (k < 144) ? w3[co * 144 + ci * 9 + tap] : 0.f;
    wb3[i] = f2bf(v);
  }
  if (i < 128 * 576) {
    int co = i / 576, k = i % 576;
    int tap = k / 64, ci = k & 63;
    wb4[i] = f2bf(w4[co * 576 + ci * 9 + tap]);
  }
}

// ---------------- direct conv (L1/L2) + per-block stats partials ------------
template<int Cin, int Cout, int COB, int Hin, int Win, int TH, int CIC, int SPT, bool FIRST>
__global__ __launch_bounds__(256) void conv2_k(const float* __restrict__ in,
    const float* __restrict__ wt, const float* __restrict__ bias,
    float* __restrict__ y, float* __restrict__ part1, float* __restrict__ part2) {
  constexpr int Hout = Hin / 2, Wout = Win / 2, HW = Hout * Wout;
  constexpr int R2 = 2 * TH + 1, W2 = Win + 2;
  constexpr int TILE = CIC * R2 * W2;
  __shared__ float tile[TILE];
  __shared__ float ws1[4][COB], ws2[4][COB];
  const int tid = threadIdx.x;
  const int pn = blockIdx.z;
  const int co0 = blockIdx.y * COB;
  const int h0 = blockIdx.x * TH;
  const int base_ih = 2 * h0 - 1;
  const float* ibase;
  if (FIRST) {
    const int n = pn & 127;
    const int sel = (pn >> 7) == 0 ? 1 : 0;
    ibase = in + (size_t)(n * 2 + sel) * (size_t)(Hin * Win);
  } else {
    ibase = in + (size_t)pn * Cin * (size_t)(Hin * Win);
  }
  int th[SPT], tw[SPT];
#pragma unroll
  for (int s = 0; s < SPT; ++s) {
    const int sp = tid + s * 256;
    th[s] = sp / Wout; tw[s] = sp - th[s] * Wout;
  }
  float acc[COB * SPT];
#pragma unroll
  for (int i = 0; i < COB * SPT; ++i) acc[i] = 0.f;
  for (int st0 = 0; st0 < Cin; st0 += CIC) {
    for (int idx = tid; idx < TILE; idx += 256) {
      const int ci = idx / (R2 * W2);
      const int rem = idx - ci * (R2 * W2);
      const int r = rem / W2;
      const int c = rem - r * W2;
      const int ih = base_ih + r;
      const int iw = c - 1;
      float v = 0.f;
      if (ih >= 0 && iw >= 0 && iw < Win)
        v = ibase[(size_t)(st0 + ci) * (Hin * Win) + ih * Win + iw];
      tile[idx] = v;
    }
    __syncthreads();
    for (int ci = 0; ci < CIC; ++ci) {
      const float* tci = tile + ci * (R2 * W2);
      const size_t wrow = ((size_t)(st0 + ci) * 9) * Cout + co0;
#pragma unroll
      for (int kh = 0; kh < 3; ++kh) {
        float2 fa[SPT], fb[SPT];
#pragma unroll
        for (int s = 0; s < SPT; ++s) {
          const float* p = tci + (2 * th[s] + kh) * W2 + 2 * tw[s];
          fa[s] = *(const float2*)p;
          fb[s] = *(const float2*)(p + 2);
        }
#pragma unroll
        for (int kw = 0; kw < 3; ++kw) {
          const float* wp = wt + wrow + (kh * 3 + kw) * Cout;
#pragma unroll
          for (int co = 0; co < COB; ++co) {
            const float wv = wp[co];
#pragma unroll
            for (int s = 0; s < SPT; ++s) {
              const float fv = (kw == 0) ? fa[s].x : (kw == 1) ? fa[s].y : fb[s].x;
              acc[co * SPT + s] = fmaf(fv, wv, acc[co * SPT + s]);
            }
          }
        }
      }
    }
    __syncthreads();
  }
  const int lane = tid & 63, wid = tid >> 6;
  const int p = pn >> 7;
  const size_t obase = ((size_t)pn * Cout + co0) * (size_t)HW + (size_t)h0 * Wout;
#pragma unroll
  for (int co = 0; co < COB; ++co) {
    const float bv = bias[co0 + co];
    float s1 = 0.f, s2 = 0.f;
#pragma unroll
    for (int s = 0; s < SPT; ++s) {
      const float v = acc[co * SPT + s] + bv;
      y[obase + (size_t)co * HW + tid + s * 256] = v;
      s1 += v; s2 += v * v;
    }
#pragma unroll
    for (int m = 32; m >= 1; m >>= 1) { s1 += __shfl_xor(s1, m); s2 += __shfl_xor(s2, m); }
    if (lane == 0) { ws1[wid][co] = s1; ws2[wid][co] = s2; }
  }
  __syncthreads();
  // per-block partials (no global atomics): index (p*Cout+co) x per-path block
  if (tid < COB) {
    const float t1 = ws1[0][tid] + ws1[1][tid] + ws1[2][tid] + ws1[3][tid];
    const float t2 = ws2[0][tid] + ws2[1][tid] + ws2[2][tid] + ws2[3][tid];
    const int nblk = 128 * gridDim.x * gridDim.y;
    const int blk = ((pn & 127) * gridDim.y + blockIdx.y) * gridDim.x + blockIdx.x;
    part1[(size_t)(p * Cout + co0 + tid) * nblk + blk] = t1;
    part2[(size_t)(p * Cout + co0 + tid) * nblk + blk] = t2;
  }
}

// ---------------- im2col: X[pnl][Cin][H][W] f32 -> bb[pnl][SP][KP] bf16 ------
template<int Cin, int H, int W, int KP>
__global__ __launch_bounds__(256) void im2col_k(const float* __restrict__ x,
    unsigned short* __restrict__ bb) {
  constexpr int Ho = H / 2, Wo = W / 2;
  constexpr int SPC = 128;
  const int pnl = blockIdx.y;
  const int sp0 = blockIdx.x * SPC;
  const float* xb = x + (size_t)pnl * Cin * (H * W);
  unsigned short* bbase = bb + ((size_t)pnl * (Ho * Wo)) * KP;
  for (int idx = threadIdx.x; idx < SPC * 9; idx += 256) {
    const int spl = idx / 9, tap = idx - spl * 9;
    const int sp = sp0 + spl;
    const int ho = sp / Wo, wo = sp - ho * Wo;
    const int kh = tap / 3, kw = tap - kh * 3;
    const int ih = 2 * ho - 1 + kh, iw = 2 * wo - 1 + kw;
    unsigned short* dst = bbase + (size_t)sp * KP + tap * Cin;
    if ((unsigned)ih < (unsigned)H && (unsigned)iw < (unsigned)W) {
      const float* src = xb + ih * W + iw;
#pragma unroll
      for (int c0 = 0; c0 < Cin; c0 += 4) {
        ull pk = (ull)f2bf(src[(size_t)(c0 + 0) * (H * W)])
               | ((ull)f2bf(src[(size_t)(c0 + 1) * (H * W)]) << 16)
               | ((ull)f2bf(src[(size_t)(c0 + 2) * (H * W)]) << 32)
               | ((ull)f2bf(src[(size_t)(c0 + 3) * (H * W)]) << 48);
        *(ull*)(dst + c0) = pk;
      }
    } else {
#pragma unroll
      for (int c0 = 0; c0 < Cin; c0 += 4) *(ull*)(dst + c0) = 0ull;
    }
  }
  constexpr int PADK = KP - 9 * Cin;
  if (PADK > 0) {
    for (int idx = threadIdx.x; idx < SPC * PADK; idx += 256) {
      const int spl = idx / PADK, k = 9 * Cin + (idx - spl * PADK);
      bbase[((size_t)(sp0 + spl)) * KP + k] = 0;
    }
  }
}

// ---------------- MFMA conv-GEMM + per-block partial stats ------------------
template<int M, int SPB, int KP, int KC, int WCO, int WSP, int HWout, int Cout>
__global__ __launch_bounds__(256) void cgemm_k(
    const unsigned short* __restrict__ bb, const unsigned short* __restrict__ wb,
    const float* __restrict__ bias, float* __restrict__ y,
    float* __restrict__ part1, float* __restrict__ part2) {
  constexpr int KCP = KC + 8;
  constexpr int MT = WCO / 16, NT = WSP / 16, KS = KC / 32;
  constexpr int NWN = SPB / WSP;
  __shared__ unsigned short wl[M][KCP];
  __shared__ unsigned short bl[SPB][KCP];
  __shared__ float ss1[Cout], ss2[Cout];
  const int tid = threadIdx.x;
  const int pnl = blockIdx.y;
  const int sp0 = blockIdx.x * SPB;
  const int lane = tid & 63, wid = tid >> 6;
  const int wm = wid / NWN, wn = wid - wm * NWN;
  const int l15 = lane & 15, lg = lane >> 4;
  const unsigned short* bsrc = bb + ((size_t)pnl * HWout + sp0) * KP;

  for (int i = tid; i < Cout; i += 256) { ss1[i] = 0.f; ss2[i] = 0.f; }

  f32x4 acc[MT][NT];
#pragma unroll
  for (int mt = 0; mt < MT; ++mt)
#pragma unroll
    for (int nt = 0; nt < NT; ++nt) acc[mt][nt] = (f32x4){0.f, 0.f, 0.f, 0.f};

  for (int k0 = 0; k0 < KP; k0 += KC) {
    for (int it = tid; it < M * (KC / 8); it += 256) {
      const int row = it / (KC / 8), seg = it - row * (KC / 8);
      const u32x4 v = *(const u32x4*)(wb + (size_t)row * KP + k0 + seg * 8);
      *(u32x4*)(&wl[row][seg * 8]) = v;
    }
    for (int it = tid; it < SPB * (KC / 8); it += 256) {
      const int row = it / (KC / 8), seg = it - row * (KC / 8);
      const u32x4 v = *(const u32x4*)(bsrc + (size_t)row * KP + k0 + seg * 8);
      *(u32x4*)(&bl[row][seg * 8]) = v;
    }
    __syncthreads();
#pragma unroll
    for (int ks = 0; ks < KS; ++ks) {
      bf16x8 af[MT], bfr[NT];
#pragma unroll
      for (int mt = 0; mt < MT; ++mt)
        af[mt] = *(const bf16x8*)(&wl[wm * WCO + mt * 16 + l15][ks * 32 + lg * 8]);
#pragma unroll
      for (int nt = 0; nt < NT; ++nt)
        bfr[nt] = *(const bf16x8*)(&bl[wn * WSP + nt * 16 + l15][ks * 32 + lg * 8]);
#pragma unroll
      for (int mt = 0; mt < MT; ++mt)
#pragma unroll
        for (int nt = 0; nt < NT; ++nt)
          acc[mt][nt] = __builtin_amdgcn_mfma_f32_16x16x32_bf16(af[mt], bfr[nt], acc[mt][nt], 0, 0, 0);
    }
    __syncthreads();
  }

  float* yb = y + (size_t)pnl * Cout * HWout;
#pragma unroll
  for (int mt = 0; mt < MT; ++mt) {
#pragma unroll
    for (int i = 0; i < 4; ++i) {
      const int co = wm * WCO + mt * 16 + lg * 4 + i;
      const float bv = bias[co];
      float s1 = 0.f, s2 = 0.f;
#pragma unroll
      for (int nt = 0; nt < NT; ++nt) {
        const float v = acc[mt][nt][i] + bv;
        yb[(size_t)co * HWout + sp0 + wn * WSP + nt * 16 + l15] = v;
        s1 += v; s2 += v * v;
      }
#pragma unroll
      for (int m = 1; m < 16; m <<= 1) { s1 += __shfl_xor(s1, m); s2 += __shfl_xor(s2, m); }
      if (l15 == 0) {
        atomicAdd(&ss1[co], s1);
        atomicAdd(&ss2[co], s2);
      }
    }
  }
  __syncthreads();
  const int blkid = blockIdx.y * gridDim.x + blockIdx.x;
  const int nblk = gridDim.x * gridDim.y;
  for (int i = tid; i < Cout; i += 256) {
    part1[(size_t)i * nblk + blkid] = ss1[i];
    part2[(size_t)i * nblk + blkid] = ss2[i];
  }
}

// ---------------- reduce partials -> st (deterministic) ---------------------
__global__ __launch_bounds__(256) void redstat_k(const float* __restrict__ p1,
    const float* __restrict__ p2, float* __restrict__ st, int path, int Cout,
    int nblk) {
  const int co = blockIdx.x;
  float s1 = 0.f, s2 = 0.f;
  for (int i = threadIdx.x; i < nblk; i += 256) {
    s1 += p1[(size_t)co * nblk + i];
    s2 += p2[(size_t)co * nblk + i];
  }
  __shared__ float r1[256], r2[256];
  r1[threadIdx.x] = s1; r2[threadIdx.x] = s2;
  __syncthreads();
  for (int stp = 128; stp > 0; stp >>= 1) {
    if (threadIdx.x < stp) {
      r1[threadIdx.x] += r1[threadIdx.x + stp];
      r2[threadIdx.x] += r2[threadIdx.x + stp];
    }
    __syncthreads();
  }
  if (threadIdx.x == 0) {
    st[path * Cout + co] = r1[0];
    st[256 + path * Cout + co] = r2[0];
  }
}

// ---------------- BN (from fused stats) + relu + 3x3 s1 p1 avgpool ----------
__global__ __launch_bounds__(256) void bnpool2_k(const float* __restrict__ y,
    const float* __restrict__ st, const float* __restrict__ g,
    const float* __restrict__ be, float* __restrict__ x,
    int Cout, int H, int W, float invCnt) {
  const int pn = blockIdx.z, c = blockIdx.y;
  const int HW = H * W;
  const int sp = blockIdx.x * 256 + threadIdx.x;
  if (sp >= HW) return;
  const int h = sp / W, w0 = sp - (sp / W) * W;
  const int p = pn >> 7;
  const float mean = st[p * Cout + c] * invCnt;
  const float var = fmaxf(st[256 + p * Cout + c] * invCnt - mean * mean, 0.f);
  const float a = g[c] * rsqrtf(var + 1e-5f);
  const float b = be[c] - mean * a;
  const float* yp = y + ((size_t)pn * Cout + c) * (size_t)HW;
  float acc = 0.f;
#pragma unroll
  for (int dh = -1; dh <= 1; ++dh) {
    int hh = h + dh;
    if ((unsigned)hh >= (unsigned)H) continue;
#pragma unroll
    for (int dw = -1; dw <= 1; ++dw) {
      int ww = w0 + dw;
      if ((unsigned)ww >= (unsigned)W) continue;
      acc += fmaxf(fmaf(a, yp[hh * W + ww], b), 0.f);
    }
  }
  x[((size_t)pn * Cout + c) * (size_t)HW + sp] = acc * (1.f / 9.f);
}

// ---------------- global mean + l2norm, coalesced; also writes qkT ----------
__global__ __launch_bounds__(256) void feat2_k(const float* __restrict__ x,
    float* __restrict__ qk, float* __restrict__ qkT) {
  const int pn = blockIdx.x;
  const int tid = threadIdx.x;
  const int lane = tid & 63, wid = tid >> 6;
  __shared__ float fm[128];
  __shared__ float red[128];
  const float* xb = x + (size_t)pn * 128 * 512;
  for (int c = wid; c < 128; c += 4) {
    const float* xp = xb + (size_t)c * 512;
    float s = 0.f;
#pragma unroll
    for (int r = 0; r < 8; ++r) s += xp[lane + r * 64];
#pragma unroll
    for (int m = 32; m >= 1; m >>= 1) s += __shfl_xor(s, m);
    if (lane == 0) fm[c] = s * (1.f / 512.f);
  }
  __syncthreads();
  if (tid < 128) red[tid] = fm[tid] * fm[tid];
  __syncthreads();
  for (int step = 64; step > 0; step >>= 1) {
    if (tid < step) red[tid] += red[tid + step];
    __syncthreads();
  }
  const float inv = 1.f / fmaxf(sqrtf(red[0]), 1e-12f);
  if (tid < 128) {
    const float v = fm[tid] * inv;
    qk[(size_t)pn * 128 + tid] = v;
    if (pn < 128) qkT[(size_t)tid * 128 + pn] = v;
  }
}

// ---------------- 1/||ref row|| ---------------------------------------------
__global__ __launch_bounds__(256) void refnorm_k(const float* __restrict__ rf,
    float* __restrict__ rinv) {
  const int n = blockIdx.x;
  float s = 0.f;
  for (int i = threadIdx.x; i < 2304; i += 256) {
    float v = rf[(size_t)n * 2304 + i];
    s += v * v;
  }
  __shared__ float red[256];
  red[threadIdx.x] = s;
  __syncthreads();
  for (int step = 128; step > 0; step >>= 1) {
    if (threadIdx.x < step) red[threadIdx.x] += red[threadIdx.x + step];
    __syncthreads();
  }
  if (threadIdx.x == 0) rinv[n] = 1.f / fmaxf(sqrtf(red[0]), 1e-12f);
}

// ---------------- rfT[k][n] = reff[n][k] * rinv[n] --------------------------
__global__ __launch_bounds__(256) void reft_k(const float* __restrict__ rf,
    const float* __restrict__ rinv, float* __restrict__ rfT) {
  const int flat = blockIdx.x * 256 + threadIdx.x;
  const int n = flat / 2304, k = flat - n * 2304;
  rfT[(size_t)k * 128 + n] = rf[flat] * rinv[n];
}

// ---------------- score_neg = q @ MoCoQueue (8 rows/block) ------------------
__global__ __launch_bounds__(256) void sneg2_k(const float* __restrict__ qkT,
    const float* __restrict__ moco, float* __restrict__ out) {
  const int j = blockIdx.x * 256 + threadIdx.x;
  const int n0 = blockIdx.y * 8;
  float acc[8] = {0.f};
#pragma unroll 4
  for (int k = 0; k < 128; ++k) {
    const float rv = moco[(size_t)k * 2048 + j];
    const float* qp = qkT + (size_t)k * 128 + n0;
#pragma unroll
    for (int i = 0; i < 8; ++i) acc[i] = fmaf(qp[i], rv, acc[i]);
  }
#pragma unroll
  for (int i = 0; i < 8; ++i) out[(size_t)(n0 + i) * 2048 + j] = acc[i];
}

// ---------------- score_ref split-K: partial over k-chunk -------------------
template<int KCH>
__global__ __launch_bounds__(256) void sref3_k(const float* __restrict__ rfT,
    const float* __restrict__ rq, float* __restrict__ part) {
  const int j = blockIdx.x * 256 + threadIdx.x;
  const int n0 = blockIdx.y * 8;
  const int kc = blockIdx.z;
  const int kbeg = kc * KCH;
  float acc[8] = {0.f};
#pragma unroll 4
  for (int k = kbeg; k < kbeg + KCH; ++k) {
    const float rv = rq[(size_t)k * 2048 + j];
    const float* rp = rfT + (size_t)k * 128 + n0;
#pragma unroll
    for (int i = 0; i < 8; ++i) acc[i] = fmaf(rp[i], rv, acc[i]);
  }
  float* pb = part + (size_t)kc * (128 * 2048);
#pragma unroll
  for (int i = 0; i < 8; ++i) pb[(size_t)(n0 + i) * 2048 + j] = acc[i];
}

// ---------------- reduce split-K partials -> SREF ---------------------------
template<int NCH>
__global__ __launch_bounds__(256) void sredr_k(const float* __restrict__ part,
    float* __restrict__ out) {
  const int j = blockIdx.x * 256 + threadIdx.x;
  const int n = blockIdx.y;
  const size_t off = (size_t)n * 2048 + j;
  float s = 0.f;
#pragma unroll
  for (int c = 0; c < NCH; ++c) s += part[(size_t)c * (128 * 2048) + off];
  out[off] = s;
}

// ---------------- top-5 per row of masked score_ref -------------------------
__global__ __launch_bounds__(256) void topk_k(const float* __restrict__ sref,
    const float* __restrict__ iq, const int* __restrict__ idxs,
    int* __restrict__ top) {
  const int n = blockIdx.x;
  const float target = (float)idxs[n];
  float vals[8];
#pragma unroll
  for (int r = 0; r < 8; ++r) {
    const int j = threadIdx.x + r * 256;
    const bool m = (iq[j] == target);
    vals[r] = m ? -__builtin_inff() : sref[(size_t)n * 2048 + j];
  }
  __shared__ float sv[256];
  __shared__ int si[256];
  __shared__ int chosen[5];
  for (int rnd = 0; rnd < 5; ++rnd) {
    float bv = -__builtin_inff();
    int bi = 1 << 30;
#pragma unroll
    for (int r = 0; r < 8; ++r) {
      const int j = threadIdx.x + r * 256;
      bool taken = false;
      for (int t = 0; t < rnd; ++t) taken |= (chosen[t] == j);
      const float v = vals[r];
      if (!taken && (v > bv || (v == bv && j < bi))) { bv = v; bi = j; }
    }
    sv[threadIdx.x] = bv; si[threadIdx.x] = bi;
    __syncthreads();
    for (int step = 128; step > 0; step >>= 1) {
      if (threadIdx.x < step) {
        const float ov = sv[threadIdx.x + step];
        const int oi = si[threadIdx.x + step];
        if (ov > sv[threadIdx.x] || (ov == sv[threadIdx.x] && oi < si[threadIdx.x])) {
          sv[threadIdx.x] = ov; si[threadIdx.x] = oi;
        }
      }
      __syncthreads();
    }
    if (threadIdx.x == 0) chosen[rnd] = si[0];
    __syncthreads();
  }
  if (threadIdx.x < 5) top[n * 5 + threadIdx.x] = chosen[threadIdx.x];
}

// ---------------- score_pos + first columns ---------------------------------
__global__ __launch_bounds__(128) void spos_k(const float* __restrict__ qk,
    float* __restrict__ out) {
  const int n = threadIdx.x;
  float s = 0.f;
  for (int c = 0; c < 128; ++c)
    s = fmaf(qk[(size_t)n * 128 + c], qk[(size_t)(NIMG + n) * 128 + c], s);
  out[(size_t)n * 2049] = s;
  out[(size_t)NIMG * 2049 + (size_t)n * 2049] = 1.f;
}

// ---------------- final assembly --------------------------------------------
__global__ __launch_bounds__(256) void asm_k(const float* __restrict__ sneg,
    const float* __restrict__ sref, const float* __restrict__ iq,
    const int* __restrict__ idxs, const int* __restrict__ top,
    float* __restrict__ out) {
  const int n = blockIdx.y;
  const int j = blockIdx.x * 256 + threadIdx.x;
  const int t0 = top[n * 5 + 0], t1 = top[n * 5 + 1], t2 = top[n * 5 + 2];
  const int t3 = top[n * 5 + 3], t4 = top[n * 5 + 4];
  const float target = (float)idxs[n];
  const bool m = (iq[j] == target);
  const float sr = sref[(size_t)n * 2048 + j];
  const float sr2 = m ? 1.f : sr;
  const bool istop = (j == t0) | (j == t1) | (j == t2) | (j == t3) | (j == t4);
  const float wgt = istop ? 1.f : -1.f;
  out[(size_t)n * 2049 + 1 + j] = sneg[(size_t)n * 2048 + j] * sr2 * wgt;
  const float mf = istop ? 1.f : (m ? 1.f : 0.f);
  out[(size_t)NIMG * 2049 + (size_t)n * 2049 + 1 + j] = mf;
}

// ---------------------------------------------------------------------------
extern "C" void kernel_launch(void* const* d_in, const int* in_sizes, int n_in,
                              void* d_out, int out_size, void* d_ws, size_t ws_size,
                              hipStream_t stream) {
  const float* feats = (const float*)d_in[0];
  const float* reff  = (const float*)d_in[1];
  const int*   idxs  = (const int*)d_in[2];
  const float* moco  = (const float*)d_in[3];
  const float* refq  = (const float*)d_in[4];
  const float* iq    = (const float*)d_in[5];
  const float* w[4]  = {(const float*)d_in[6],  (const float*)d_in[10],
                        (const float*)d_in[14], (const float*)d_in[18]};
  const float* b[4]  = {(const float*)d_in[7],  (const float*)d_in[11],
                        (const float*)d_in[15], (const float*)d_in[19]};
  const float* g[4]  = {(const float*)d_in[8],  (const float*)d_in[12],
                        (const float*)d_in[16], (const float*)d_in[20]};
  const float* be[4] = {(const float*)d_in[9],  (const float*)d_in[13],
                        (const float*)d_in[17], (const float*)d_in[21]};
  float* out = (float*)d_out;

  // workspace layout (floats)
  const size_t BIG = 33554432;  // 2*128*131072
  float* X    = (float*)d_ws;
  float* Y    = X + BIG;
  float* ST   = Y + BIG;            // 4 layers x 512
  float* WT1  = ST + 2048;          // 36
  float* WT2  = WT1 + 64;           // 576
  unsigned short* WB3 = (unsigned short*)(WT2 + 640);   // 64*160 bf16
  unsigned short* WB4 = WB3 + 64 * 160;                 // 128*576 bf16
  float* QK   = (float*)(WB4 + 128 * 576);              // 2*128*128
  float* QKT  = QK + 32768;         // 128*128
  float* RINV = QKT + 16384;        // 128
  float* RFT  = RINV + 128;         // 2304*128
  float* SNEG = RFT + 294912;       // 128*2048
  float* SREF = SNEG + 262144;      // 128*2048
  int*   TOP  = (int*)(SREF + 262144);                  // 128*5
  unsigned short* BB = (unsigned short*)(TOP + 256);    // im2col: 83.9 MB max
  // stats partials alias the (dead-until-head) SNEG area (L1 needs 16*8192)
  float* PART1 = SNEG;
  float* PART2 = SNEG + 131072;
  // sref split-K partials alias the (dead-after-L4) BB area: 6 x 1M floats
  float* SPART = (float*)BB;

  wtr2_k<<<288, 256, 0, stream>>>(w[0], w[1], w[2], w[3], WT1, WT2, WB3, WB4);

  // ---- layer 1: (1 -> 4), 1024x128 -> 512x64 (fp32 direct) ----
  conv2_k<1, 4, 4, 1024, 128, 8, 1, 2, true>
      <<<dim3(64, 1, 256), 256, 0, stream>>>(feats, WT1, b[0], Y, PART1, PART2);
  redstat_k<<<8, 256, 0, stream>>>(PART1, PART2, ST, 0, 8, 8192);
  bnpool2_k<<<dim3(128, 4, 256), 256, 0, stream>>>(Y, ST, g[0], be[0], X, 4, 512, 64,
                                                   1.f / (128.f * 32768.f));
  // ---- layer 2: (4 -> 16), 512x64 -> 256x32 (fp32 direct) ----
  conv2_k<4, 16, 16, 512, 64, 16, 2, 2, false>
      <<<dim3(16, 1, 256), 256, 0, stream>>>(X, WT2, b[1], Y, PART1, PART2);
  redstat_k<<<32, 256, 0, stream>>>(PART1, PART2, ST + 512, 0, 32, 2048);
  bnpool2_k<<<dim3(32, 16, 256), 256, 0, stream>>>(Y, ST + 512, g[1], be[1], X, 16, 256, 32,
                                                   1.f / (128.f * 8192.f));
  // ---- layer 3: (16 -> 64), 256x32 -> 128x16 via MFMA, 2 pn-passes ----
  for (int pass = 0; pass < 2; ++pass) {
    const size_t xo = (size_t)pass * 128 * 16 * 8192;
    const size_t yo = (size_t)pass * 128 * 64 * 2048;
    im2col_k<16, 256, 32, 160><<<dim3(16, 128), 256, 0, stream>>>(X + xo, BB);
    cgemm_k<64, 256, 160, 32, 64, 64, 2048, 64>
        <<<dim3(8, 128), 256, 0, stream>>>(BB, WB3, b[2], Y + yo, PART1, PART2);
    redstat_k<<<64, 256, 0, stream>>>(PART1, PART2, ST + 1024, pass, 64, 8 * 128);
  }
  bnpool2_k<<<dim3(8, 64, 256), 256, 0, stream>>>(Y, ST + 1024, g[2], be[2], X, 64, 128, 16,
                                                  1.f / (128.f * 2048.f));
  // ---- layer 4: (64 -> 128), 128x16 -> 64x8 via MFMA, 2 pn-passes ----
  for (int pass = 0; pass < 2; ++pass) {
    const size_t xo = (size_t)pass * 128 * 64 * 2048;
    const size_t yo = (size_t)pass * 128 * 128 * 512;
    im2col_k<64, 128, 16, 576><<<dim3(4, 128), 256, 0, stream>>>(X + xo, BB);
    cgemm_k<128, 128, 576, 64, 32, 128, 512, 128>
        <<<dim3(4, 128), 256, 0, stream>>>(BB, WB4, b[3], Y + yo, PART1, PART2);
    redstat_k<<<128, 256, 0, stream>>>(PART1, PART2, ST + 1536, pass, 128, 4 * 128);
  }
  bnpool2_k<<<dim3(2, 128, 256), 256, 0, stream>>>(Y, ST + 1536, g[3], be[3], X, 128, 64, 8,
                                                   1.f / (128.f * 512.f));

  // ---- head ----
  feat2_k<<<256, 256, 0, stream>>>(X, QK, QKT);
  refnorm_k<<<128, 256, 0, stream>>>(reff, RINV);
  reft_k<<<1152, 256, 0, stream>>>(reff, RINV, RFT);
  sneg2_k<<<dim3(8, 16), 256, 0, stream>>>(QKT, moco, SNEG);
  sref3_k<384><<<dim3(8, 16, 6), 256, 0, stream>>>(RFT, refq, SPART);
  sredr_k<6><<<dim3(8, 128), 256, 0, stream>>>(SPART, SREF);
  topk_k<<<128, 256, 0, stream>>>(SREF, iq, idxs, TOP);
  spos_k<<<1, 128, 0, stream>>>(QK, out);
  asm_k<<<dim3(8, 128), 256, 0, stream>>>(SNEG, SREF, iq, idxs, TOP, out);
}

// Round 13
// 1022.867 us; speedup vs baseline: 2.7265x; 1.4082x over previous
//
#include <hip/hip_runtime.h>

// ---------------------------------------------------------------------------
// CoSSL round 13 (resubmit of R12 after container infra failure):
// bnpool rewrite — float4 + rolling row horizontal-sums.
// conv stats via partials+redstat. L3/L4 = im2col(bf16)+MFMA. sref split-K.
// Activations: [p*128+n][c][h][w], p=0 -> q (feats[:,1]), p=1 -> k (feats[:,0]).
// ---------------------------------------------------------------------------

#define NIMG 128
typedef __attribute__((ext_vector_type(8))) short bf16x8;
typedef __attribute__((ext_vector_type(4))) float f32x4;
typedef __attribute__((ext_vector_type(4))) unsigned int u32x4;
typedef unsigned long long ull;

__device__ __forceinline__ unsigned short f2bf(float f) {
  unsigned u = __float_as_uint(f);
  unsigned r = (u + 0x7fffu + ((u >> 16) & 1u)) >> 16;
  return (unsigned short)r;
}

// ---------------- weight prep ------------------------------------------------
__global__ __launch_bounds__(256) void wtr2_k(
    const float* __restrict__ w1, const float* __restrict__ w2,
    const float* __restrict__ w3, const float* __restrict__ w4,
    float* __restrict__ t1, float* __restrict__ t2,
    unsigned short* __restrict__ wb3, unsigned short* __restrict__ wb4) {
  const int i = blockIdx.x * 256 + threadIdx.x;
  if (i < 36) { int co = i / 9, r = i % 9; t1[r * 4 + co] = w1[i]; }
  if (i < 576) { int co = i / 36, r = i % 36; t2[r * 16 + co] = w2[i]; }
  if (i < 64 * 160) {
    int co = i / 160, k = i % 160;
    int tap = k >> 4, ci = k & 15;
    float v = (k < 144) ? w3[co * 144 + ci * 9 + tap] : 0.f;
    wb3[i] = f2bf(v);
  }
  if (i < 128 * 576) {
    int co = i / 576, k = i % 576;
    int tap = k / 64, ci = k & 63;
    wb4[i] = f2bf(w4[co * 576 + ci * 9 + tap]);
  }
}

// ---------------- direct conv (L1/L2) + per-block stats partials ------------
template<int Cin, int Cout, int COB, int Hin, int Win, int TH, int CIC, int SPT, bool FIRST>
__global__ __launch_bounds__(256) void conv2_k(const float* __restrict__ in,
    const float* __restrict__ wt, const float* __restrict__ bias,
    float* __restrict__ y, float* __restrict__ part1, float* __restrict__ part2) {
  constexpr int Hout = Hin / 2, Wout = Win / 2, HW = Hout * Wout;
  constexpr int R2 = 2 * TH + 1, W2 = Win + 2;
  constexpr int TILE = CIC * R2 * W2;
  __shared__ float tile[TILE];
  __shared__ float ws1[4][COB], ws2[4][COB];
  const int tid = threadIdx.x;
  const int pn = blockIdx.z;
  const int co0 = blockIdx.y * COB;
  const int h0 = blockIdx.x * TH;
  const int base_ih = 2 * h0 - 1;
  const float* ibase;
  if (FIRST) {
    const int n = pn & 127;
    const int sel = (pn >> 7) == 0 ? 1 : 0;
    ibase = in + (size_t)(n * 2 + sel) * (size_t)(Hin * Win);
  } else {
    ibase = in + (size_t)pn * Cin * (size_t)(Hin * Win);
  }
  int th[SPT], tw[SPT];
#pragma unroll
  for (int s = 0; s < SPT; ++s) {
    const int sp = tid + s * 256;
    th[s] = sp / Wout; tw[s] = sp - th[s] * Wout;
  }
  float acc[COB * SPT];
#pragma unroll
  for (int i = 0; i < COB * SPT; ++i) acc[i] = 0.f;
  for (int st0 = 0; st0 < Cin; st0 += CIC) {
    for (int idx = tid; idx < TILE; idx += 256) {
      const int ci = idx / (R2 * W2);
      const int rem = idx - ci * (R2 * W2);
      const int r = rem / W2;
      const int c = rem - r * W2;
      const int ih = base_ih + r;
      const int iw = c - 1;
      float v = 0.f;
      if (ih >= 0 && iw >= 0 && iw < Win)
        v = ibase[(size_t)(st0 + ci) * (Hin * Win) + ih * Win + iw];
      tile[idx] = v;
    }
    __syncthreads();
    for (int ci = 0; ci < CIC; ++ci) {
      const float* tci = tile + ci * (R2 * W2);
      const size_t wrow = ((size_t)(st0 + ci) * 9) * Cout + co0;
#pragma unroll
      for (int kh = 0; kh < 3; ++kh) {
        float2 fa[SPT], fb[SPT];
#pragma unroll
        for (int s = 0; s < SPT; ++s) {
          const float* p = tci + (2 * th[s] + kh) * W2 + 2 * tw[s];
          fa[s] = *(const float2*)p;
          fb[s] = *(const float2*)(p + 2);
        }
#pragma unroll
        for (int kw = 0; kw < 3; ++kw) {
          const float* wp = wt + wrow + (kh * 3 + kw) * Cout;
#pragma unroll
          for (int co = 0; co < COB; ++co) {
            const float wv = wp[co];
#pragma unroll
            for (int s = 0; s < SPT; ++s) {
              const float fv = (kw == 0) ? fa[s].x : (kw == 1) ? fa[s].y : fb[s].x;
              acc[co * SPT + s] = fmaf(fv, wv, acc[co * SPT + s]);
            }
          }
        }
      }
    }
    __syncthreads();
  }
  const int lane = tid & 63, wid = tid >> 6;
  const int p = pn >> 7;
  const size_t obase = ((size_t)pn * Cout + co0) * (size_t)HW + (size_t)h0 * Wout;
#pragma unroll
  for (int co = 0; co < COB; ++co) {
    const float bv = bias[co0 + co];
    float s1 = 0.f, s2 = 0.f;
#pragma unroll
    for (int s = 0; s < SPT; ++s) {
      const float v = acc[co * SPT + s] + bv;
      y[obase + (size_t)co * HW + tid + s * 256] = v;
      s1 += v; s2 += v * v;
    }
#pragma unroll
    for (int m = 32; m >= 1; m >>= 1) { s1 += __shfl_xor(s1, m); s2 += __shfl_xor(s2, m); }
    if (lane == 0) { ws1[wid][co] = s1; ws2[wid][co] = s2; }
  }
  __syncthreads();
  if (tid < COB) {
    const float t1 = ws1[0][tid] + ws1[1][tid] + ws1[2][tid] + ws1[3][tid];
    const float t2 = ws2[0][tid] + ws2[1][tid] + ws2[2][tid] + ws2[3][tid];
    const int nblk = 128 * gridDim.x * gridDim.y;
    const int blk = ((pn & 127) * gridDim.y + blockIdx.y) * gridDim.x + blockIdx.x;
    part1[(size_t)(p * Cout + co0 + tid) * nblk + blk] = t1;
    part2[(size_t)(p * Cout + co0 + tid) * nblk + blk] = t2;
  }
}

// ---------------- im2col: X[pnl][Cin][H][W] f32 -> bb[pnl][SP][KP] bf16 ------
template<int Cin, int H, int W, int KP>
__global__ __launch_bounds__(256) void im2col_k(const float* __restrict__ x,
    unsigned short* __restrict__ bb) {
  constexpr int Ho = H / 2, Wo = W / 2;
  constexpr int SPC = 128;
  const int pnl = blockIdx.y;
  const int sp0 = blockIdx.x * SPC;
  const float* xb = x + (size_t)pnl * Cin * (H * W);
  unsigned short* bbase = bb + ((size_t)pnl * (Ho * Wo)) * KP;
  for (int idx = threadIdx.x; idx < SPC * 9; idx += 256) {
    const int spl = idx / 9, tap = idx - spl * 9;
    const int sp = sp0 + spl;
    const int ho = sp / Wo, wo = sp - ho * Wo;
    const int kh = tap / 3, kw = tap - kh * 3;
    const int ih = 2 * ho - 1 + kh, iw = 2 * wo - 1 + kw;
    unsigned short* dst = bbase + (size_t)sp * KP + tap * Cin;
    if ((unsigned)ih < (unsigned)H && (unsigned)iw < (unsigned)W) {
      const float* src = xb + ih * W + iw;
#pragma unroll
      for (int c0 = 0; c0 < Cin; c0 += 4) {
        ull pk = (ull)f2bf(src[(size_t)(c0 + 0) * (H * W)])
               | ((ull)f2bf(src[(size_t)(c0 + 1) * (H * W)]) << 16)
               | ((ull)f2bf(src[(size_t)(c0 + 2) * (H * W)]) << 32)
               | ((ull)f2bf(src[(size_t)(c0 + 3) * (H * W)]) << 48);
        *(ull*)(dst + c0) = pk;
      }
    } else {
#pragma unroll
      for (int c0 = 0; c0 < Cin; c0 += 4) *(ull*)(dst + c0) = 0ull;
    }
  }
  constexpr int PADK = KP - 9 * Cin;
  if (PADK > 0) {
    for (int idx = threadIdx.x; idx < SPC * PADK; idx += 256) {
      const int spl = idx / PADK, k = 9 * Cin + (idx - spl * PADK);
      bbase[((size_t)(sp0 + spl)) * KP + k] = 0;
    }
  }
}

// ---------------- MFMA conv-GEMM + per-block partial stats ------------------
template<int M, int SPB, int KP, int KC, int WCO, int WSP, int HWout, int Cout>
__global__ __launch_bounds__(256) void cgemm_k(
    const unsigned short* __restrict__ bb, const unsigned short* __restrict__ wb,
    const float* __restrict__ bias, float* __restrict__ y,
    float* __restrict__ part1, float* __restrict__ part2) {
  constexpr int KCP = KC + 8;
  constexpr int MT = WCO / 16, NT = WSP / 16, KS = KC / 32;
  constexpr int NWN = SPB / WSP;
  __shared__ unsigned short wl[M][KCP];
  __shared__ unsigned short bl[SPB][KCP];
  __shared__ float ss1[Cout], ss2[Cout];
  const int tid = threadIdx.x;
  const int pnl = blockIdx.y;
  const int sp0 = blockIdx.x * SPB;
  const int lane = tid & 63, wid = tid >> 6;
  const int wm = wid / NWN, wn = wid - wm * NWN;
  const int l15 = lane & 15, lg = lane >> 4;
  const unsigned short* bsrc = bb + ((size_t)pnl * HWout + sp0) * KP;

  for (int i = tid; i < Cout; i += 256) { ss1[i] = 0.f; ss2[i] = 0.f; }

  f32x4 acc[MT][NT];
#pragma unroll
  for (int mt = 0; mt < MT; ++mt)
#pragma unroll
    for (int nt = 0; nt < NT; ++nt) acc[mt][nt] = (f32x4){0.f, 0.f, 0.f, 0.f};

  for (int k0 = 0; k0 < KP; k0 += KC) {
    for (int it = tid; it < M * (KC / 8); it += 256) {
      const int row = it / (KC / 8), seg = it - row * (KC / 8);
      const u32x4 v = *(const u32x4*)(wb + (size_t)row * KP + k0 + seg * 8);
      *(u32x4*)(&wl[row][seg * 8]) = v;
    }
    for (int it = tid; it < SPB * (KC / 8); it += 256) {
      const int row = it / (KC / 8), seg = it - row * (KC / 8);
      const u32x4 v = *(const u32x4*)(bsrc + (size_t)row * KP + k0 + seg * 8);
      *(u32x4*)(&bl[row][seg * 8]) = v;
    }
    __syncthreads();
#pragma unroll
    for (int ks = 0; ks < KS; ++ks) {
      bf16x8 af[MT], bfr[NT];
#pragma unroll
      for (int mt = 0; mt < MT; ++mt)
        af[mt] = *(const bf16x8*)(&wl[wm * WCO + mt * 16 + l15][ks * 32 + lg * 8]);
#pragma unroll
      for (int nt = 0; nt < NT; ++nt)
        bfr[nt] = *(const bf16x8*)(&bl[wn * WSP + nt * 16 + l15][ks * 32 + lg * 8]);
#pragma unroll
      for (int mt = 0; mt < MT; ++mt)
#pragma unroll
        for (int nt = 0; nt < NT; ++nt)
          acc[mt][nt] = __builtin_amdgcn_mfma_f32_16x16x32_bf16(af[mt], bfr[nt], acc[mt][nt], 0, 0, 0);
    }
    __syncthreads();
  }

  float* yb = y + (size_t)pnl * Cout * HWout;
#pragma unroll
  for (int mt = 0; mt < MT; ++mt) {
#pragma unroll
    for (int i = 0; i < 4; ++i) {
      const int co = wm * WCO + mt * 16 + lg * 4 + i;
      const float bv = bias[co];
      float s1 = 0.f, s2 = 0.f;
#pragma unroll
      for (int nt = 0; nt < NT; ++nt) {
        const float v = acc[mt][nt][i] + bv;
        yb[(size_t)co * HWout + sp0 + wn * WSP + nt * 16 + l15] = v;
        s1 += v; s2 += v * v;
      }
#pragma unroll
      for (int m = 1; m < 16; m <<= 1) { s1 += __shfl_xor(s1, m); s2 += __shfl_xor(s2, m); }
      if (l15 == 0) {
        atomicAdd(&ss1[co], s1);
        atomicAdd(&ss2[co], s2);
      }
    }
  }
  __syncthreads();
  const int blkid = blockIdx.y * gridDim.x + blockIdx.x;
  const int nblk = gridDim.x * gridDim.y;
  for (int i = tid; i < Cout; i += 256) {
    part1[(size_t)i * nblk + blkid] = ss1[i];
    part2[(size_t)i * nblk + blkid] = ss2[i];
  }
}

// ---------------- reduce partials -> st (deterministic) ---------------------
__global__ __launch_bounds__(256) void redstat_k(const float* __restrict__ p1,
    const float* __restrict__ p2, float* __restrict__ st, int path, int Cout,
    int nblk) {
  const int co = blockIdx.x;
  float s1 = 0.f, s2 = 0.f;
  for (int i = threadIdx.x; i < nblk; i += 256) {
    s1 += p1[(size_t)co * nblk + i];
    s2 += p2[(size_t)co * nblk + i];
  }
  __shared__ float r1[256], r2[256];
  r1[threadIdx.x] = s1; r2[threadIdx.x] = s2;
  __syncthreads();
  for (int stp = 128; stp > 0; stp >>= 1) {
    if (threadIdx.x < stp) {
      r1[threadIdx.x] += r1[threadIdx.x + stp];
      r2[threadIdx.x] += r2[threadIdx.x + stp];
    }
    __syncthreads();
  }
  if (threadIdx.x == 0) {
    st[path * Cout + co] = r1[0];
    st[256 + path * Cout + co] = r2[0];
  }
}

// ---------------- BN + relu + 3x3 s1 p1 avgpool, float4 rolling rows --------
// hs[i] = horizontal sum of relu(a*y+b) over cols w0+i-1..w0+i+1 (OOB -> 0).
template<int W>
__device__ __forceinline__ void row_hs(const float* __restrict__ yp, int hh, int H,
                                       int w0, float a, float b, float* hs) {
  if ((unsigned)hh >= (unsigned)H) { hs[0] = hs[1] = hs[2] = hs[3] = 0.f; return; }
  const float* rp = yp + hh * W;
  const float4 B = *(const float4*)(rp + w0);
  float r0 = 0.f, r5 = 0.f;
  if (w0 > 0) r0 = fmaxf(fmaf(a, rp[w0 - 1], b), 0.f);
  if (w0 + 4 < W) r5 = fmaxf(fmaf(a, rp[w0 + 4], b), 0.f);
  const float r1 = fmaxf(fmaf(a, B.x, b), 0.f);
  const float r2 = fmaxf(fmaf(a, B.y, b), 0.f);
  const float r3 = fmaxf(fmaf(a, B.z, b), 0.f);
  const float r4 = fmaxf(fmaf(a, B.w, b), 0.f);
  hs[0] = r0 + r1 + r2;
  hs[1] = r1 + r2 + r3;
  hs[2] = r2 + r3 + r4;
  hs[3] = r3 + r4 + r5;
}

template<int Cout, int H, int W, int TH>
__global__ __launch_bounds__(256) void bnpool3_k(const float* __restrict__ y,
    const float* __restrict__ st, const float* __restrict__ g,
    const float* __restrict__ be, float* __restrict__ x, float invCnt) {
  constexpr int W4 = W / 4;
  constexpr int GROUPS = 256 / W4;
  constexpr int HW = H * W;
  const int tid = threadIdx.x;
  const int grp = tid / W4, lw = tid - grp * W4;
  const int w0 = lw * 4;
  const int h0 = (blockIdx.x * GROUPS + grp) * TH;
  if (h0 >= H) return;
  const int pn = blockIdx.z, c = blockIdx.y;
  const int p = pn >> 7;
  const float mean = st[p * Cout + c] * invCnt;
  const float var = fmaxf(st[256 + p * Cout + c] * invCnt - mean * mean, 0.f);
  const float a = g[c] * rsqrtf(var + 1e-5f);
  const float b = be[c] - mean * a;
  const float* yp = y + ((size_t)pn * Cout + c) * (size_t)HW;
  float* xp = x + ((size_t)pn * Cout + c) * (size_t)HW;

  float hsA[4], hsB[4], hsC[4];
  row_hs<W>(yp, h0 - 1, H, w0, a, b, hsA);
  row_hs<W>(yp, h0, H, w0, a, b, hsB);
#pragma unroll
  for (int t = 0; t < TH; ++t) {
    const int h = h0 + t;
    if (h >= H) break;
    row_hs<W>(yp, h + 1, H, w0, a, b, hsC);
    float4 o;
    o.x = (hsA[0] + hsB[0] + hsC[0]) * (1.f / 9.f);
    o.y = (hsA[1] + hsB[1] + hsC[1]) * (1.f / 9.f);
    o.z = (hsA[2] + hsB[2] + hsC[2]) * (1.f / 9.f);
    o.w = (hsA[3] + hsB[3] + hsC[3]) * (1.f / 9.f);
    *(float4*)(xp + h * W + w0) = o;
#pragma unroll
    for (int i = 0; i < 4; ++i) { hsA[i] = hsB[i]; hsB[i] = hsC[i]; }
  }
}

// ---------------- global mean + l2norm, coalesced; also writes qkT ----------
__global__ __launch_bounds__(256) void feat2_k(const float* __restrict__ x,
    float* __restrict__ qk, float* __restrict__ qkT) {
  const int pn = blockIdx.x;
  const int tid = threadIdx.x;
  const int lane = tid & 63, wid = tid >> 6;
  __shared__ float fm[128];
  __shared__ float red[128];
  const float* xb = x + (size_t)pn * 128 * 512;
  for (int c = wid; c < 128; c += 4) {
    const float* xp = xb + (size_t)c * 512;
    float s = 0.f;
#pragma unroll
    for (int r = 0; r < 8; ++r) s += xp[lane + r * 64];
#pragma unroll
    for (int m = 32; m >= 1; m >>= 1) s += __shfl_xor(s, m);
    if (lane == 0) fm[c] = s * (1.f / 512.f);
  }
  __syncthreads();
  if (tid < 128) red[tid] = fm[tid] * fm[tid];
  __syncthreads();
  for (int step = 64; step > 0; step >>= 1) {
    if (tid < step) red[tid] += red[tid + step];
    __syncthreads();
  }
  const float inv = 1.f / fmaxf(sqrtf(red[0]), 1e-12f);
  if (tid < 128) {
    const float v = fm[tid] * inv;
    qk[(size_t)pn * 128 + tid] = v;
    if (pn < 128) qkT[(size_t)tid * 128 + pn] = v;
  }
}

// ---------------- 1/||ref row|| ---------------------------------------------
__global__ __launch_bounds__(256) void refnorm_k(const float* __restrict__ rf,
    float* __restrict__ rinv) {
  const int n = blockIdx.x;
  float s = 0.f;
  for (int i = threadIdx.x; i < 2304; i += 256) {
    float v = rf[(size_t)n * 2304 + i];
    s += v * v;
  }
  __shared__ float red[256];
  red[threadIdx.x] = s;
  __syncthreads();
  for (int step = 128; step > 0; step >>= 1) {
    if (threadIdx.x < step) red[threadIdx.x] += red[threadIdx.x + step];
    __syncthreads();
  }
  if (threadIdx.x == 0) rinv[n] = 1.f / fmaxf(sqrtf(red[0]), 1e-12f);
}

// ---------------- rfT[k][n] = reff[n][k] * rinv[n] --------------------------
__global__ __launch_bounds__(256) void reft_k(const float* __restrict__ rf,
    const float* __restrict__ rinv, float* __restrict__ rfT) {
  const int flat = blockIdx.x * 256 + threadIdx.x;
  const int n = flat / 2304, k = flat - n * 2304;
  rfT[(size_t)k * 128 + n] = rf[flat] * rinv[n];
}

// ---------------- score_neg = q @ MoCoQueue (8 rows/block) ------------------
__global__ __launch_bounds__(256) void sneg2_k(const float* __restrict__ qkT,
    const float* __restrict__ moco, float* __restrict__ out) {
  const int j = blockIdx.x * 256 + threadIdx.x;
  const int n0 = blockIdx.y * 8;
  float acc[8] = {0.f};
#pragma unroll 4
  for (int k = 0; k < 128; ++k) {
    const float rv = moco[(size_t)k * 2048 + j];
    const float* qp = qkT + (size_t)k * 128 + n0;
#pragma unroll
    for (int i = 0; i < 8; ++i) acc[i] = fmaf(qp[i], rv, acc[i]);
  }
#pragma unroll
  for (int i = 0; i < 8; ++i) out[(size_t)(n0 + i) * 2048 + j] = acc[i];
}

// ---------------- score_ref split-K: partial over k-chunk -------------------
template<int KCH>
__global__ __launch_bounds__(256) void sref3_k(const float* __restrict__ rfT,
    const float* __restrict__ rq, float* __restrict__ part) {
  const int j = blockIdx.x * 256 + threadIdx.x;
  const int n0 = blockIdx.y * 8;
  const int kc = blockIdx.z;
  const int kbeg = kc * KCH;
  float acc[8] = {0.f};
#pragma unroll 4
  for (int k = kbeg; k < kbeg + KCH; ++k) {
    const float rv = rq[(size_t)k * 2048 + j];
    const float* rp = rfT + (size_t)k * 128 + n0;
#pragma unroll
    for (int i = 0; i < 8; ++i) acc[i] = fmaf(rp[i], rv, acc[i]);
  }
  float* pb = part + (size_t)kc * (128 * 2048);
#pragma unroll
  for (int i = 0; i < 8; ++i) pb[(size_t)(n0 + i) * 2048 + j] = acc[i];
}

// ---------------- reduce split-K partials -> SREF ---------------------------
template<int NCH>
__global__ __launch_bounds__(256) void sredr_k(const float* __restrict__ part,
    float* __restrict__ out) {
  const int j = blockIdx.x * 256 + threadIdx.x;
  const int n = blockIdx.y;
  const size_t off = (size_t)n * 2048 + j;
  float s = 0.f;
#pragma unroll
  for (int c = 0; c < NCH; ++c) s += part[(size_t)c * (128 * 2048) + off];
  out[off] = s;
}

// ---------------- top-5 per row of masked score_ref -------------------------
__global__ __launch_bounds__(256) void topk_k(const float* __restrict__ sref,
    const float* __restrict__ iq, const int* __restrict__ idxs,
    int* __restrict__ top) {
  const int n = blockIdx.x;
  const float target = (float)idxs[n];
  float vals[8];
#pragma unroll
  for (int r = 0; r < 8; ++r) {
    const int j = threadIdx.x + r * 256;
    const bool m = (iq[j] == target);
    vals[r] = m ? -__builtin_inff() : sref[(size_t)n * 2048 + j];
  }
  __shared__ float sv[256];
  __shared__ int si[256];
  __shared__ int chosen[5];
  for (int rnd = 0; rnd < 5; ++rnd) {
    float bv = -__builtin_inff();
    int bi = 1 << 30;
#pragma unroll
    for (int r = 0; r < 8; ++r) {
      const int j = threadIdx.x + r * 256;
      bool taken = false;
      for (int t = 0; t < rnd; ++t) taken |= (chosen[t] == j);
      const float v = vals[r];
      if (!taken && (v > bv || (v == bv && j < bi))) { bv = v; bi = j; }
    }
    sv[threadIdx.x] = bv; si[threadIdx.x] = bi;
    __syncthreads();
    for (int step = 128; step > 0; step >>= 1) {
      if (threadIdx.x < step) {
        const float ov = sv[threadIdx.x + step];
        const int oi = si[threadIdx.x + step];
        if (ov > sv[threadIdx.x] || (ov == sv[threadIdx.x] && oi < si[threadIdx.x])) {
          sv[threadIdx.x] = ov; si[threadIdx.x] = oi;
        }
      }
      __syncthreads();
    }
    if (threadIdx.x == 0) chosen[rnd] = si[0];
    __syncthreads();
  }
  if (threadIdx.x < 5) top[n * 5 + threadIdx.x] = chosen[threadIdx.x];
}

// ---------------- score_pos + first columns ---------------------------------
__global__ __launch_bounds__(128) void spos_k(const float* __restrict__ qk,
    float* __restrict__ out) {
  const int n = threadIdx.x;
  float s = 0.f;
  for (int c = 0; c < 128; ++c)
    s = fmaf(qk[(size_t)n * 128 + c], qk[(size_t)(NIMG + n) * 128 + c], s);
  out[(size_t)n * 2049] = s;
  out[(size_t)NIMG * 2049 + (size_t)n * 2049] = 1.f;
}

// ---------------- final assembly --------------------------------------------
__global__ __launch_bounds__(256) void asm_k(const float* __restrict__ sneg,
    const float* __restrict__ sref, const float* __restrict__ iq,
    const int* __restrict__ idxs, const int* __restrict__ top,
    float* __restrict__ out) {
  const int n = blockIdx.y;
  const int j = blockIdx.x * 256 + threadIdx.x;
  const int t0 = top[n * 5 + 0], t1 = top[n * 5 + 1], t2 = top[n * 5 + 2];
  const int t3 = top[n * 5 + 3], t4 = top[n * 5 + 4];
  const float target = (float)idxs[n];
  const bool m = (iq[j] == target);
  const float sr = sref[(size_t)n * 2048 + j];
  const float sr2 = m ? 1.f : sr;
  const bool istop = (j == t0) | (j == t1) | (j == t2) | (j == t3) | (j == t4);
  const float wgt = istop ? 1.f : -1.f;
  out[(size_t)n * 2049 + 1 + j] = sneg[(size_t)n * 2048 + j] * sr2 * wgt;
  const float mf = istop ? 1.f : (m ? 1.f : 0.f);
  out[(size_t)NIMG * 2049 + (size_t)n * 2049 + 1 + j] = mf;
}

// ---------------------------------------------------------------------------
extern "C" void kernel_launch(void* const* d_in, const int* in_sizes, int n_in,
                              void* d_out, int out_size, void* d_ws, size_t ws_size,
                              hipStream_t stream) {
  const float* feats = (const float*)d_in[0];
  const float* reff  = (const float*)d_in[1];
  const int*   idxs  = (const int*)d_in[2];
  const float* moco  = (const float*)d_in[3];
  const float* refq  = (const float*)d_in[4];
  const float* iq    = (const float*)d_in[5];
  const float* w[4]  = {(const float*)d_in[6],  (const float*)d_in[10],
                        (const float*)d_in[14], (const float*)d_in[18]};
  const float* b[4]  = {(const float*)d_in[7],  (const float*)d_in[11],
                        (const float*)d_in[15], (const float*)d_in[19]};
  const float* g[4]  = {(const float*)d_in[8],  (const float*)d_in[12],
                        (const float*)d_in[16], (const float*)d_in[20]};
  const float* be[4] = {(const float*)d_in[9],  (const float*)d_in[13],
                        (const float*)d_in[17], (const float*)d_in[21]};
  float* out = (float*)d_out;

  // workspace layout (floats)
  const size_t BIG = 33554432;  // 2*128*131072
  float* X    = (float*)d_ws;
  float* Y    = X + BIG;
  float* ST   = Y + BIG;            // 4 layers x 512
  float* WT1  = ST + 2048;          // 36
  float* WT2  = WT1 + 64;           // 576
  unsigned short* WB3 = (unsigned short*)(WT2 + 640);   // 64*160 bf16
  unsigned short* WB4 = WB3 + 64 * 160;                 // 128*576 bf16
  float* QK   = (float*)(WB4 + 128 * 576);              // 2*128*128
  float* QKT  = QK + 32768;         // 128*128
  float* RINV = QKT + 16384;        // 128
  float* RFT  = RINV + 128;         // 2304*128
  float* SNEG = RFT + 294912;       // 128*2048
  float* SREF = SNEG + 262144;      // 128*2048
  int*   TOP  = (int*)(SREF + 262144);                  // 128*5
  unsigned short* BB = (unsigned short*)(TOP + 256);    // im2col: 83.9 MB max
  // stats partials alias the (dead-until-head) SNEG area (L1 needs 16*8192)
  float* PART1 = SNEG;
  float* PART2 = SNEG + 131072;
  // sref split-K partials alias the (dead-after-L4) BB area: 6 x 1M floats
  float* SPART = (float*)BB;

  wtr2_k<<<288, 256, 0, stream>>>(w[0], w[1], w[2], w[3], WT1, WT2, WB3, WB4);

  // ---- layer 1: (1 -> 4), 1024x128 -> 512x64 (fp32 direct) ----
  conv2_k<1, 4, 4, 1024, 128, 8, 1, 2, true>
      <<<dim3(64, 1, 256), 256, 0, stream>>>(feats, WT1, b[0], Y, PART1, PART2);
  redstat_k<<<8, 256, 0, stream>>>(PART1, PART2, ST, 0, 8, 8192);
  bnpool3_k<4, 512, 64, 8><<<dim3(4, 4, 256), 256, 0, stream>>>(Y, ST, g[0], be[0], X,
                                                                1.f / (128.f * 32768.f));
  // ---- layer 2: (4 -> 16), 512x64 -> 256x32 (fp32 direct) ----
  conv2_k<4, 16, 16, 512, 64, 16, 2, 2, false>
      <<<dim3(16, 1, 256), 256, 0, stream>>>(X, WT2, b[1], Y, PART1, PART2);
  redstat_k<<<32, 256, 0, stream>>>(PART1, PART2, ST + 512, 0, 32, 2048);
  bnpool3_k<16, 256, 32, 4><<<dim3(2, 16, 256), 256, 0, stream>>>(Y, ST + 512, g[1], be[1], X,
                                                                  1.f / (128.f * 8192.f));
  // ---- layer 3: (16 -> 64), 256x32 -> 128x16 via MFMA, 2 pn-passes ----
  for (int pass = 0; pass < 2; ++pass) {
    const size_t xo = (size_t)pass * 128 * 16 * 8192;
    const size_t yo = (size_t)pass * 128 * 64 * 2048;
    im2col_k<16, 256, 32, 160><<<dim3(16, 128), 256, 0, stream>>>(X + xo, BB);
    cgemm_k<64, 256, 160, 32, 64, 64, 2048, 64>
        <<<dim3(8, 128), 256, 0, stream>>>(BB, WB3, b[2], Y + yo, PART1, PART2);
    redstat_k<<<64, 256, 0, stream>>>(PART1, PART2, ST + 1024, pass, 64, 8 * 128);
  }
  bnpool3_k<64, 128, 16, 2><<<dim3(1, 64, 256), 256, 0, stream>>>(Y, ST + 1024, g[2], be[2], X,
                                                                  1.f / (128.f * 2048.f));
  // ---- layer 4: (64 -> 128), 128x16 -> 64x8 via MFMA, 2 pn-passes ----
  for (int pass = 0; pass < 2; ++pass) {
    const size_t xo = (size_t)pass * 128 * 64 * 2048;
    const size_t yo = (size_t)pass * 128 * 128 * 512;
    im2col_k<64, 128, 16, 576><<<dim3(4, 128), 256, 0, stream>>>(X + xo, BB);
    cgemm_k<128, 128, 576, 64, 32, 128, 512, 128>
        <<<dim3(4, 128), 256, 0, stream>>>(BB, WB4, b[3], Y + yo, PART1, PART2);
    redstat_k<<<128, 256, 0, stream>>>(PART1, PART2, ST + 1536, pass, 128, 4 * 128);
  }
  bnpool3_k<128, 64, 8, 1><<<dim3(1, 128, 256), 256, 0, stream>>>(Y, ST + 1536, g[3], be[3], X,
                                                                  1.f / (128.f * 512.f));

  // ---- head ----
  feat2_k<<<256, 256, 0, stream>>>(X, QK, QKT);
  refnorm_k<<<128, 256, 0, stream>>>(reff, RINV);
  reft_k<<<1152, 256, 0, stream>>>(reff, RINV, RFT);
  sneg2_k<<<dim3(8, 16), 256, 0, stream>>>(QKT, moco, SNEG);
  sref3_k<384><<<dim3(8, 16, 6), 256, 0, stream>>>(RFT, refq, SPART);
  sredr_k<6><<<dim3(8, 128), 256, 0, stream>>>(SPART, SREF);
  topk_k<<<128, 256, 0, stream>>>(SREF, iq, idxs, TOP);
  spos_k<<<1, 128, 0, stream>>>(QK, out);
  asm_k<<<dim3(8, 128), 256, 0, stream>>>(SNEG, SREF, iq, idxs, TOP, out);
}

// Round 14
// 779.998 us; speedup vs baseline: 3.5755x; 1.3114x over previous
//
#include <hip/hip_runtime.h>

// ---------------------------------------------------------------------------
// CoSSL round 14: bf16 activation storage (X,Y) — halves all inter-stage
// activation traffic (L2 conv was 134us @ 203MB fp32; pipeline ~1.3GB).
// Conv accumulates fp32, rounds on store; stats fp32 pre-rounding; im2col
// becomes pure repack. L3/L4 = im2col(bf16)+MFMA. sref split-K fp32 (topk
// selection unchanged).
// Activations: [p*128+n][c][h][w], p=0 -> q (feats[:,1]), p=1 -> k (feats[:,0]).
// ---------------------------------------------------------------------------

#define NIMG 128
typedef __attribute__((ext_vector_type(8))) short bf16x8;
typedef __attribute__((ext_vector_type(4))) float f32x4;
typedef __attribute__((ext_vector_type(4))) unsigned int u32x4;
typedef unsigned long long ull;

__device__ __forceinline__ unsigned short f2bf(float f) {
  unsigned u = __float_as_uint(f);
  unsigned r = (u + 0x7fffu + ((u >> 16) & 1u)) >> 16;
  return (unsigned short)r;
}
__device__ __forceinline__ float bf2f(unsigned short u) {
  return __uint_as_float((unsigned)u << 16);
}

// ---------------- weight prep ------------------------------------------------
__global__ __launch_bounds__(256) void wtr2_k(
    const float* __restrict__ w1, const float* __restrict__ w2,
    const float* __restrict__ w3, const float* __restrict__ w4,
    float* __restrict__ t1, float* __restrict__ t2,
    unsigned short* __restrict__ wb3, unsigned short* __restrict__ wb4) {
  const int i = blockIdx.x * 256 + threadIdx.x;
  if (i < 36) { int co = i / 9, r = i % 9; t1[r * 4 + co] = w1[i]; }
  if (i < 576) { int co = i / 36, r = i % 36; t2[r * 16 + co] = w2[i]; }
  if (i < 64 * 160) {
    int co = i / 160, k = i % 160;
    int tap = k >> 4, ci = k & 15;
    float v = (k < 144) ? w3[co * 144 + ci * 9 + tap] : 0.f;
    wb3[i] = f2bf(v);
  }
  if (i < 128 * 576) {
    int co = i / 576, k = i % 576;
    int tap = k / 64, ci = k & 63;
    wb4[i] = f2bf(w4[co * 576 + ci * 9 + tap]);
  }
}

// ---------------- direct conv (L1/L2), bf16 y, per-block stats partials -----
template<int Cin, int Cout, int COB, int Hin, int Win, int TH, int CIC, int SPT, bool FIRST>
__global__ __launch_bounds__(256) void conv2_k(const void* __restrict__ in_,
    const float* __restrict__ wt, const float* __restrict__ bias,
    unsigned short* __restrict__ y, float* __restrict__ part1,
    float* __restrict__ part2) {
  constexpr int Hout = Hin / 2, Wout = Win / 2, HW = Hout * Wout;
  constexpr int R2 = 2 * TH + 1, W2 = Win + 2;
  constexpr int TILE = CIC * R2 * W2;
  __shared__ float tile[TILE];
  __shared__ float ws1[4][COB], ws2[4][COB];
  const int tid = threadIdx.x;
  const int pn = blockIdx.z;
  const int co0 = blockIdx.y * COB;
  const int h0 = blockIdx.x * TH;
  const int base_ih = 2 * h0 - 1;
  const float* ibF = nullptr;
  const unsigned short* ibH = nullptr;
  if constexpr (FIRST) {
    const int n = pn & 127;
    const int sel = (pn >> 7) == 0 ? 1 : 0;
    ibF = (const float*)in_ + (size_t)(n * 2 + sel) * (size_t)(Hin * Win);
  } else {
    ibH = (const unsigned short*)in_ + (size_t)pn * Cin * (size_t)(Hin * Win);
  }
  int th[SPT], tw[SPT];
#pragma unroll
  for (int s = 0; s < SPT; ++s) {
    const int sp = tid + s * 256;
    th[s] = sp / Wout; tw[s] = sp - th[s] * Wout;
  }
  float acc[COB * SPT];
#pragma unroll
  for (int i = 0; i < COB * SPT; ++i) acc[i] = 0.f;
  for (int st0 = 0; st0 < Cin; st0 += CIC) {
    for (int idx = tid; idx < TILE; idx += 256) {
      const int ci = idx / (R2 * W2);
      const int rem = idx - ci * (R2 * W2);
      const int r = rem / W2;
      const int c = rem - r * W2;
      const int ih = base_ih + r;
      const int iw = c - 1;
      float v = 0.f;
      if (ih >= 0 && iw >= 0 && iw < Win) {
        const size_t off = (size_t)(st0 + ci) * (Hin * Win) + ih * Win + iw;
        if constexpr (FIRST) v = ibF[off]; else v = bf2f(ibH[off]);
      }
      tile[idx] = v;
    }
    __syncthreads();
    for (int ci = 0; ci < CIC; ++ci) {
      const float* tci = tile + ci * (R2 * W2);
      const size_t wrow = ((size_t)(st0 + ci) * 9) * Cout + co0;
#pragma unroll
      for (int kh = 0; kh < 3; ++kh) {
        float2 fa[SPT], fb[SPT];
#pragma unroll
        for (int s = 0; s < SPT; ++s) {
          const float* p = tci + (2 * th[s] + kh) * W2 + 2 * tw[s];
          fa[s] = *(const float2*)p;
          fb[s] = *(const float2*)(p + 2);
        }
#pragma unroll
        for (int kw = 0; kw < 3; ++kw) {
          const float* wp = wt + wrow + (kh * 3 + kw) * Cout;
#pragma unroll
          for (int co = 0; co < COB; ++co) {
            const float wv = wp[co];
#pragma unroll
            for (int s = 0; s < SPT; ++s) {
              const float fv = (kw == 0) ? fa[s].x : (kw == 1) ? fa[s].y : fb[s].x;
              acc[co * SPT + s] = fmaf(fv, wv, acc[co * SPT + s]);
            }
          }
        }
      }
    }
    __syncthreads();
  }
  const int lane = tid & 63, wid = tid >> 6;
  const int p = pn >> 7;
  const size_t obase = ((size_t)pn * Cout + co0) * (size_t)HW + (size_t)h0 * Wout;
#pragma unroll
  for (int co = 0; co < COB; ++co) {
    const float bv = bias[co0 + co];
    float s1 = 0.f, s2 = 0.f;
#pragma unroll
    for (int s = 0; s < SPT; ++s) {
      const float v = acc[co * SPT + s] + bv;
      y[obase + (size_t)co * HW + tid + s * 256] = f2bf(v);
      s1 += v; s2 += v * v;
    }
#pragma unroll
    for (int m = 32; m >= 1; m >>= 1) { s1 += __shfl_xor(s1, m); s2 += __shfl_xor(s2, m); }
    if (lane == 0) { ws1[wid][co] = s1; ws2[wid][co] = s2; }
  }
  __syncthreads();
  if (tid < COB) {
    const float t1 = ws1[0][tid] + ws1[1][tid] + ws1[2][tid] + ws1[3][tid];
    const float t2 = ws2[0][tid] + ws2[1][tid] + ws2[2][tid] + ws2[3][tid];
    const int nblk = 128 * gridDim.x * gridDim.y;
    const int blk = ((pn & 127) * gridDim.y + blockIdx.y) * gridDim.x + blockIdx.x;
    part1[(size_t)(p * Cout + co0 + tid) * nblk + blk] = t1;
    part2[(size_t)(p * Cout + co0 + tid) * nblk + blk] = t2;
  }
}

// ---------------- im2col: X[pnl][Cin][H][W] bf16 -> bb[pnl][SP][KP] bf16 ----
template<int Cin, int H, int W, int KP>
__global__ __launch_bounds__(256) void im2col_k(const unsigned short* __restrict__ x,
    unsigned short* __restrict__ bb) {
  constexpr int Ho = H / 2, Wo = W / 2;
  constexpr int SPC = 128;
  const int pnl = blockIdx.y;
  const int sp0 = blockIdx.x * SPC;
  const unsigned short* xb = x + (size_t)pnl * Cin * (H * W);
  unsigned short* bbase = bb + ((size_t)pnl * (Ho * Wo)) * KP;
  for (int idx = threadIdx.x; idx < SPC * 9; idx += 256) {
    const int spl = idx / 9, tap = idx - spl * 9;
    const int sp = sp0 + spl;
    const int ho = sp / Wo, wo = sp - ho * Wo;
    const int kh = tap / 3, kw = tap - kh * 3;
    const int ih = 2 * ho - 1 + kh, iw = 2 * wo - 1 + kw;
    unsigned short* dst = bbase + (size_t)sp * KP + tap * Cin;
    if ((unsigned)ih < (unsigned)H && (unsigned)iw < (unsigned)W) {
      const unsigned short* src = xb + ih * W + iw;
#pragma unroll
      for (int c0 = 0; c0 < Cin; c0 += 4) {
        ull pk = (ull)src[(size_t)(c0 + 0) * (H * W)]
               | ((ull)src[(size_t)(c0 + 1) * (H * W)] << 16)
               | ((ull)src[(size_t)(c0 + 2) * (H * W)] << 32)
               | ((ull)src[(size_t)(c0 + 3) * (H * W)] << 48);
        *(ull*)(dst + c0) = pk;
      }
    } else {
#pragma unroll
      for (int c0 = 0; c0 < Cin; c0 += 4) *(ull*)(dst + c0) = 0ull;
    }
  }
  constexpr int PADK = KP - 9 * Cin;
  if (PADK > 0) {
    for (int idx = threadIdx.x; idx < SPC * PADK; idx += 256) {
      const int spl = idx / PADK, k = 9 * Cin + (idx - spl * PADK);
      bbase[((size_t)(sp0 + spl)) * KP + k] = 0;
    }
  }
}

// ---------------- MFMA conv-GEMM (bf16 y out) + per-block partial stats -----
template<int M, int SPB, int KP, int KC, int WCO, int WSP, int HWout, int Cout>
__global__ __launch_bounds__(256) void cgemm_k(
    const unsigned short* __restrict__ bb, const unsigned short* __restrict__ wb,
    const float* __restrict__ bias, unsigned short* __restrict__ y,
    float* __restrict__ part1, float* __restrict__ part2) {
  constexpr int KCP = KC + 8;
  constexpr int MT = WCO / 16, NT = WSP / 16, KS = KC / 32;
  constexpr int NWN = SPB / WSP;
  __shared__ unsigned short wl[M][KCP];
  __shared__ unsigned short bl[SPB][KCP];
  __shared__ float ss1[Cout], ss2[Cout];
  const int tid = threadIdx.x;
  const int pnl = blockIdx.y;
  const int sp0 = blockIdx.x * SPB;
  const int lane = tid & 63, wid = tid >> 6;
  const int wm = wid / NWN, wn = wid - wm * NWN;
  const int l15 = lane & 15, lg = lane >> 4;
  const unsigned short* bsrc = bb + ((size_t)pnl * HWout + sp0) * KP;

  for (int i = tid; i < Cout; i += 256) { ss1[i] = 0.f; ss2[i] = 0.f; }

  f32x4 acc[MT][NT];
#pragma unroll
  for (int mt = 0; mt < MT; ++mt)
#pragma unroll
    for (int nt = 0; nt < NT; ++nt) acc[mt][nt] = (f32x4){0.f, 0.f, 0.f, 0.f};

  for (int k0 = 0; k0 < KP; k0 += KC) {
    for (int it = tid; it < M * (KC / 8); it += 256) {
      const int row = it / (KC / 8), seg = it - row * (KC / 8);
      const u32x4 v = *(const u32x4*)(wb + (size_t)row * KP + k0 + seg * 8);
      *(u32x4*)(&wl[row][seg * 8]) = v;
    }
    for (int it = tid; it < SPB * (KC / 8); it += 256) {
      const int row = it / (KC / 8), seg = it - row * (KC / 8);
      const u32x4 v = *(const u32x4*)(bsrc + (size_t)row * KP + k0 + seg * 8);
      *(u32x4*)(&bl[row][seg * 8]) = v;
    }
    __syncthreads();
#pragma unroll
    for (int ks = 0; ks < KS; ++ks) {
      bf16x8 af[MT], bfr[NT];
#pragma unroll
      for (int mt = 0; mt < MT; ++mt)
        af[mt] = *(const bf16x8*)(&wl[wm * WCO + mt * 16 + l15][ks * 32 + lg * 8]);
#pragma unroll
      for (int nt = 0; nt < NT; ++nt)
        bfr[nt] = *(const bf16x8*)(&bl[wn * WSP + nt * 16 + l15][ks * 32 + lg * 8]);
#pragma unroll
      for (int mt = 0; mt < MT; ++mt)
#pragma unroll
        for (int nt = 0; nt < NT; ++nt)
          acc[mt][nt] = __builtin_amdgcn_mfma_f32_16x16x32_bf16(af[mt], bfr[nt], acc[mt][nt], 0, 0, 0);
    }
    __syncthreads();
  }

  unsigned short* yb = y + (size_t)pnl * Cout * HWout;
#pragma unroll
  for (int mt = 0; mt < MT; ++mt) {
#pragma unroll
    for (int i = 0; i < 4; ++i) {
      const int co = wm * WCO + mt * 16 + lg * 4 + i;
      const float bv = bias[co];
      float s1 = 0.f, s2 = 0.f;
#pragma unroll
      for (int nt = 0; nt < NT; ++nt) {
        const float v = acc[mt][nt][i] + bv;
        yb[(size_t)co * HWout + sp0 + wn * WSP + nt * 16 + l15] = f2bf(v);
        s1 += v; s2 += v * v;
      }
#pragma unroll
      for (int m = 1; m < 16; m <<= 1) { s1 += __shfl_xor(s1, m); s2 += __shfl_xor(s2, m); }
      if (l15 == 0) {
        atomicAdd(&ss1[co], s1);
        atomicAdd(&ss2[co], s2);
      }
    }
  }
  __syncthreads();
  const int blkid = blockIdx.y * gridDim.x + blockIdx.x;
  const int nblk = gridDim.x * gridDim.y;
  for (int i = tid; i < Cout; i += 256) {
    part1[(size_t)i * nblk + blkid] = ss1[i];
    part2[(size_t)i * nblk + blkid] = ss2[i];
  }
}

// ---------------- reduce partials -> st (deterministic) ---------------------
__global__ __launch_bounds__(256) void redstat_k(const float* __restrict__ p1,
    const float* __restrict__ p2, float* __restrict__ st, int path, int Cout,
    int nblk) {
  const int co = blockIdx.x;
  float s1 = 0.f, s2 = 0.f;
  for (int i = threadIdx.x; i < nblk; i += 256) {
    s1 += p1[(size_t)co * nblk + i];
    s2 += p2[(size_t)co * nblk + i];
  }
  __shared__ float r1[256], r2[256];
  r1[threadIdx.x] = s1; r2[threadIdx.x] = s2;
  __syncthreads();
  for (int stp = 128; stp > 0; stp >>= 1) {
    if (threadIdx.x < stp) {
      r1[threadIdx.x] += r1[threadIdx.x + stp];
      r2[threadIdx.x] += r2[threadIdx.x + stp];
    }
    __syncthreads();
  }
  if (threadIdx.x == 0) {
    st[path * Cout + co] = r1[0];
    st[256 + path * Cout + co] = r2[0];
  }
}

// ---------------- BN + relu + avgpool, bf16 in/out, rolling rows ------------
template<int W>
__device__ __forceinline__ void row_hs(const unsigned short* __restrict__ yp,
                                       int hh, int H, int w0, float a, float b,
                                       float* hs) {
  if ((unsigned)hh >= (unsigned)H) { hs[0] = hs[1] = hs[2] = hs[3] = 0.f; return; }
  const unsigned short* rp = yp + hh * W;
  const ull B = *(const ull*)(rp + w0);
  float r0 = 0.f, r5 = 0.f;
  if (w0 > 0) r0 = fmaxf(fmaf(a, bf2f(rp[w0 - 1]), b), 0.f);
  if (w0 + 4 < W) r5 = fmaxf(fmaf(a, bf2f(rp[w0 + 4]), b), 0.f);
  const float r1 = fmaxf(fmaf(a, bf2f((unsigned short)(B & 0xffff)), b), 0.f);
  const float r2 = fmaxf(fmaf(a, bf2f((unsigned short)((B >> 16) & 0xffff)), b), 0.f);
  const float r3 = fmaxf(fmaf(a, bf2f((unsigned short)((B >> 32) & 0xffff)), b), 0.f);
  const float r4 = fmaxf(fmaf(a, bf2f((unsigned short)(B >> 48)), b), 0.f);
  hs[0] = r0 + r1 + r2;
  hs[1] = r1 + r2 + r3;
  hs[2] = r2 + r3 + r4;
  hs[3] = r3 + r4 + r5;
}

template<int Cout, int H, int W, int TH>
__global__ __launch_bounds__(256) void bnpool3_k(const unsigned short* __restrict__ y,
    const float* __restrict__ st, const float* __restrict__ g,
    const float* __restrict__ be, unsigned short* __restrict__ x, float invCnt) {
  constexpr int W4 = W / 4;
  constexpr int GROUPS = 256 / W4;
  constexpr int HW = H * W;
  const int tid = threadIdx.x;
  const int grp = tid / W4, lw = tid - grp * W4;
  const int w0 = lw * 4;
  const int h0 = (blockIdx.x * GROUPS + grp) * TH;
  if (h0 >= H) return;
  const int pn = blockIdx.z, c = blockIdx.y;
  const int p = pn >> 7;
  const float mean = st[p * Cout + c] * invCnt;
  const float var = fmaxf(st[256 + p * Cout + c] * invCnt - mean * mean, 0.f);
  const float a = g[c] * rsqrtf(var + 1e-5f);
  const float b = be[c] - mean * a;
  const unsigned short* yp = y + ((size_t)pn * Cout + c) * (size_t)HW;
  unsigned short* xp = x + ((size_t)pn * Cout + c) * (size_t)HW;

  float hsA[4], hsB[4], hsC[4];
  row_hs<W>(yp, h0 - 1, H, w0, a, b, hsA);
  row_hs<W>(yp, h0, H, w0, a, b, hsB);
#pragma unroll
  for (int t = 0; t < TH; ++t) {
    const int h = h0 + t;
    if (h >= H) break;
    row_hs<W>(yp, h + 1, H, w0, a, b, hsC);
    const ull o = (ull)f2bf((hsA[0] + hsB[0] + hsC[0]) * (1.f / 9.f))
                | ((ull)f2bf((hsA[1] + hsB[1] + hsC[1]) * (1.f / 9.f)) << 16)
                | ((ull)f2bf((hsA[2] + hsB[2] + hsC[2]) * (1.f / 9.f)) << 32)
                | ((ull)f2bf((hsA[3] + hsB[3] + hsC[3]) * (1.f / 9.f)) << 48);
    *(ull*)(xp + h * W + w0) = o;
#pragma unroll
    for (int i = 0; i < 4; ++i) { hsA[i] = hsB[i]; hsB[i] = hsC[i]; }
  }
}

// ---------------- global mean + l2norm (bf16 in); also writes qkT -----------
__global__ __launch_bounds__(256) void feat2_k(const unsigned short* __restrict__ x,
    float* __restrict__ qk, float* __restrict__ qkT) {
  const int pn = blockIdx.x;
  const int tid = threadIdx.x;
  const int lane = tid & 63, wid = tid >> 6;
  __shared__ float fm[128];
  __shared__ float red[128];
  const unsigned short* xb = x + (size_t)pn * 128 * 512;
  for (int c = wid; c < 128; c += 4) {
    const unsigned short* xp = xb + (size_t)c * 512;
    float s = 0.f;
#pragma unroll
    for (int r = 0; r < 4; ++r) {
      const unsigned v = *(const unsigned*)(xp + lane * 2 + r * 128);
      s += bf2f((unsigned short)(v & 0xffff)) + bf2f((unsigned short)(v >> 16));
    }
#pragma unroll
    for (int m = 32; m >= 1; m >>= 1) s += __shfl_xor(s, m);
    if (lane == 0) fm[c] = s * (1.f / 512.f);
  }
  __syncthreads();
  if (tid < 128) red[tid] = fm[tid] * fm[tid];
  __syncthreads();
  for (int step = 64; step > 0; step >>= 1) {
    if (tid < step) red[tid] += red[tid + step];
    __syncthreads();
  }
  const float inv = 1.f / fmaxf(sqrtf(red[0]), 1e-12f);
  if (tid < 128) {
    const float v = fm[tid] * inv;
    qk[(size_t)pn * 128 + tid] = v;
    if (pn < 128) qkT[(size_t)tid * 128 + pn] = v;
  }
}

// ---------------- 1/||ref row|| ---------------------------------------------
__global__ __launch_bounds__(256) void refnorm_k(const float* __restrict__ rf,
    float* __restrict__ rinv) {
  const int n = blockIdx.x;
  float s = 0.f;
  for (int i = threadIdx.x; i < 2304; i += 256) {
    float v = rf[(size_t)n * 2304 + i];
    s += v * v;
  }
  __shared__ float red[256];
  red[threadIdx.x] = s;
  __syncthreads();
  for (int step = 128; step > 0; step >>= 1) {
    if (threadIdx.x < step) red[threadIdx.x] += red[threadIdx.x + step];
    __syncthreads();
  }
  if (threadIdx.x == 0) rinv[n] = 1.f / fmaxf(sqrtf(red[0]), 1e-12f);
}

// ---------------- rfT[k][n] = reff[n][k] * rinv[n] --------------------------
__global__ __launch_bounds__(256) void reft_k(const float* __restrict__ rf,
    const float* __restrict__ rinv, float* __restrict__ rfT) {
  const int flat = blockIdx.x * 256 + threadIdx.x;
  const int n = flat / 2304, k = flat - n * 2304;
  rfT[(size_t)k * 128 + n] = rf[flat] * rinv[n];
}

// ---------------- score_neg = q @ MoCoQueue (8 rows/block) ------------------
__global__ __launch_bounds__(256) void sneg2_k(const float* __restrict__ qkT,
    const float* __restrict__ moco, float* __restrict__ out) {
  const int j = blockIdx.x * 256 + threadIdx.x;
  const int n0 = blockIdx.y * 8;
  float acc[8] = {0.f};
#pragma unroll 4
  for (int k = 0; k < 128; ++k) {
    const float rv = moco[(size_t)k * 2048 + j];
    const float* qp = qkT + (size_t)k * 128 + n0;
#pragma unroll
    for (int i = 0; i < 8; ++i) acc[i] = fmaf(qp[i], rv, acc[i]);
  }
#pragma unroll
  for (int i = 0; i < 8; ++i) out[(size_t)(n0 + i) * 2048 + j] = acc[i];
}

// ---------------- score_ref split-K: partial over k-chunk -------------------
template<int KCH>
__global__ __launch_bounds__(256) void sref3_k(const float* __restrict__ rfT,
    const float* __restrict__ rq, float* __restrict__ part) {
  const int j = blockIdx.x * 256 + threadIdx.x;
  const int n0 = blockIdx.y * 8;
  const int kc = blockIdx.z;
  const int kbeg = kc * KCH;
  float acc[8] = {0.f};
#pragma unroll 4
  for (int k = kbeg; k < kbeg + KCH; ++k) {
    const float rv = rq[(size_t)k * 2048 + j];
    const float* rp = rfT + (size_t)k * 128 + n0;
#pragma unroll
    for (int i = 0; i < 8; ++i) acc[i] = fmaf(rp[i], rv, acc[i]);
  }
  float* pb = part + (size_t)kc * (128 * 2048);
#pragma unroll
  for (int i = 0; i < 8; ++i) pb[(size_t)(n0 + i) * 2048 + j] = acc[i];
}

// ---------------- reduce split-K partials -> SREF ---------------------------
template<int NCH>
__global__ __launch_bounds__(256) void sredr_k(const float* __restrict__ part,
    float* __restrict__ out) {
  const int j = blockIdx.x * 256 + threadIdx.x;
  const int n = blockIdx.y;
  const size_t off = (size_t)n * 2048 + j;
  float s = 0.f;
#pragma unroll
  for (int c = 0; c < NCH; ++c) s += part[(size_t)c * (128 * 2048) + off];
  out[off] = s;
}

// ---------------- top-5 per row of masked score_ref -------------------------
__global__ __launch_bounds__(256) void topk_k(const float* __restrict__ sref,
    const float* __restrict__ iq, const int* __restrict__ idxs,
    int* __restrict__ top) {
  const int n = blockIdx.x;
  const float target = (float)idxs[n];
  float vals[8];
#pragma unroll
  for (int r = 0; r < 8; ++r) {
    const int j = threadIdx.x + r * 256;
    const bool m = (iq[j] == target);
    vals[r] = m ? -__builtin_inff() : sref[(size_t)n * 2048 + j];
  }
  __shared__ float sv[256];
  __shared__ int si[256];
  __shared__ int chosen[5];
  for (int rnd = 0; rnd < 5; ++rnd) {
    float bv = -__builtin_inff();
    int bi = 1 << 30;
#pragma unroll
    for (int r = 0; r < 8; ++r) {
      const int j = threadIdx.x + r * 256;
      bool taken = false;
      for (int t = 0; t < rnd; ++t) taken |= (chosen[t] == j);
      const float v = vals[r];
      if (!taken && (v > bv || (v == bv && j < bi))) { bv = v; bi = j; }
    }
    sv[threadIdx.x] = bv; si[threadIdx.x] = bi;
    __syncthreads();
    for (int step = 128; step > 0; step >>= 1) {
      if (threadIdx.x < step) {
        const float ov = sv[threadIdx.x + step];
        const int oi = si[threadIdx.x + step];
        if (ov > sv[threadIdx.x] || (ov == sv[threadIdx.x] && oi < si[threadIdx.x])) {
          sv[threadIdx.x] = ov; si[threadIdx.x] = oi;
        }
      }
      __syncthreads();
    }
    if (threadIdx.x == 0) chosen[rnd] = si[0];
    __syncthreads();
  }
  if (threadIdx.x < 5) top[n * 5 + threadIdx.x] = chosen[threadIdx.x];
}

// ---------------- score_pos + first columns ---------------------------------
__global__ __launch_bounds__(128) void spos_k(const float* __restrict__ qk,
    float* __restrict__ out) {
  const int n = threadIdx.x;
  float s = 0.f;
  for (int c = 0; c < 128; ++c)
    s = fmaf(qk[(size_t)n * 128 + c], qk[(size_t)(NIMG + n) * 128 + c], s);
  out[(size_t)n * 2049] = s;
  out[(size_t)NIMG * 2049 + (size_t)n * 2049] = 1.f;
}

// ---------------- final assembly --------------------------------------------
__global__ __launch_bounds__(256) void asm_k(const float* __restrict__ sneg,
    const float* __restrict__ sref, const float* __restrict__ iq,
    const int* __restrict__ idxs, const int* __restrict__ top,
    float* __restrict__ out) {
  const int n = blockIdx.y;
  const int j = blockIdx.x * 256 + threadIdx.x;
  const int t0 = top[n * 5 + 0], t1 = top[n * 5 + 1], t2 = top[n * 5 + 2];
  const int t3 = top[n * 5 + 3], t4 = top[n * 5 + 4];
  const float target = (float)idxs[n];
  const bool m = (iq[j] == target);
  const float sr = sref[(size_t)n * 2048 + j];
  const float sr2 = m ? 1.f : sr;
  const bool istop = (j == t0) | (j == t1) | (j == t2) | (j == t3) | (j == t4);
  const float wgt = istop ? 1.f : -1.f;
  out[(size_t)n * 2049 + 1 + j] = sneg[(size_t)n * 2048 + j] * sr2 * wgt;
  const float mf = istop ? 1.f : (m ? 1.f : 0.f);
  out[(size_t)NIMG * 2049 + (size_t)n * 2049 + 1 + j] = mf;
}

// ---------------------------------------------------------------------------
extern "C" void kernel_launch(void* const* d_in, const int* in_sizes, int n_in,
                              void* d_out, int out_size, void* d_ws, size_t ws_size,
                              hipStream_t stream) {
  const float* feats = (const float*)d_in[0];
  const float* reff  = (const float*)d_in[1];
  const int*   idxs  = (const int*)d_in[2];
  const float* moco  = (const float*)d_in[3];
  const float* refq  = (const float*)d_in[4];
  const float* iq    = (const float*)d_in[5];
  const float* w[4]  = {(const float*)d_in[6],  (const float*)d_in[10],
                        (const float*)d_in[14], (const float*)d_in[18]};
  const float* b[4]  = {(const float*)d_in[7],  (const float*)d_in[11],
                        (const float*)d_in[15], (const float*)d_in[19]};
  const float* g[4]  = {(const float*)d_in[8],  (const float*)d_in[12],
                        (const float*)d_in[16], (const float*)d_in[20]};
  const float* be[4] = {(const float*)d_in[9],  (const float*)d_in[13],
                        (const float*)d_in[17], (const float*)d_in[21]};
  float* out = (float*)d_out;

  // workspace layout
  const size_t BIG = 33554432;  // 2*128*131072 elements
  unsigned short* X = (unsigned short*)d_ws;            // BIG bf16
  unsigned short* Y = X + BIG;                          // BIG bf16
  float* ST   = (float*)(Y + BIG);  // 4 layers x 512
  float* WT1  = ST + 2048;          // 36
  float* WT2  = WT1 + 64;           // 576
  unsigned short* WB3 = (unsigned short*)(WT2 + 640);   // 64*160 bf16
  unsigned short* WB4 = WB3 + 64 * 160;                 // 128*576 bf16
  float* QK   = (float*)(WB4 + 128 * 576);              // 2*128*128
  float* QKT  = QK + 32768;         // 128*128
  float* RINV = QKT + 16384;        // 128
  float* RFT  = RINV + 128;         // 2304*128
  float* SNEG = RFT + 294912;       // 128*2048
  float* SREF = SNEG + 262144;      // 128*2048
  int*   TOP  = (int*)(SREF + 262144);                  // 128*5
  unsigned short* BB = (unsigned short*)(TOP + 256);    // im2col: 83.9 MB max
  // stats partials alias the (dead-until-head) SNEG area
  float* PART1 = SNEG;
  float* PART2 = SNEG + 131072;
  // sref split-K partials alias the (dead-after-L4) BB area: 6 x 1M floats
  float* SPART = (float*)BB;

  wtr2_k<<<288, 256, 0, stream>>>(w[0], w[1], w[2], w[3], WT1, WT2, WB3, WB4);

  // ---- layer 1: (1 -> 4), 1024x128 -> 512x64 (fp32 direct, bf16 out) ----
  conv2_k<1, 4, 4, 1024, 128, 8, 1, 2, true>
      <<<dim3(64, 1, 256), 256, 0, stream>>>(feats, WT1, b[0], Y, PART1, PART2);
  redstat_k<<<8, 256, 0, stream>>>(PART1, PART2, ST, 0, 8, 8192);
  bnpool3_k<4, 512, 64, 8><<<dim3(4, 4, 256), 256, 0, stream>>>(Y, ST, g[0], be[0], X,
                                                                1.f / (128.f * 32768.f));
  // ---- layer 2: (4 -> 16), 512x64 -> 256x32 (bf16 direct) ----
  conv2_k<4, 16, 16, 512, 64, 16, 2, 2, false>
      <<<dim3(16, 1, 256), 256, 0, stream>>>(X, WT2, b[1], Y, PART1, PART2);
  redstat_k<<<32, 256, 0, stream>>>(PART1, PART2, ST + 512, 0, 32, 2048);
  bnpool3_k<16, 256, 32, 4><<<dim3(2, 16, 256), 256, 0, stream>>>(Y, ST + 512, g[1], be[1], X,
                                                                  1.f / (128.f * 8192.f));
  // ---- layer 3: (16 -> 64), 256x32 -> 128x16 via MFMA, 2 pn-passes ----
  for (int pass = 0; pass < 2; ++pass) {
    const size_t xo = (size_t)pass * 128 * 16 * 8192;
    const size_t yo = (size_t)pass * 128 * 64 * 2048;
    im2col_k<16, 256, 32, 160><<<dim3(16, 128), 256, 0, stream>>>(X + xo, BB);
    cgemm_k<64, 256, 160, 32, 64, 64, 2048, 64>
        <<<dim3(8, 128), 256, 0, stream>>>(BB, WB3, b[2], Y + yo, PART1, PART2);
    redstat_k<<<64, 256, 0, stream>>>(PART1, PART2, ST + 1024, pass, 64, 8 * 128);
  }
  bnpool3_k<64, 128, 16, 2><<<dim3(1, 64, 256), 256, 0, stream>>>(Y, ST + 1024, g[2], be[2], X,
                                                                  1.f / (128.f * 2048.f));
  // ---- layer 4: (64 -> 128), 128x16 -> 64x8 via MFMA, 2 pn-passes ----
  for (int pass = 0; pass < 2; ++pass) {
    const size_t xo = (size_t)pass * 128 * 64 * 2048;
    const size_t yo = (size_t)pass * 128 * 128 * 512;
    im2col_k<64, 128, 16, 576><<<dim3(4, 128), 256, 0, stream>>>(X + xo, BB);
    cgemm_k<128, 128, 576, 64, 32, 128, 512, 128>
        <<<dim3(4, 128), 256, 0, stream>>>(BB, WB4, b[3], Y + yo, PART1, PART2);
    redstat_k<<<128, 256, 0, stream>>>(PART1, PART2, ST + 1536, pass, 128, 4 * 128);
  }
  bnpool3_k<128, 64, 8, 1><<<dim3(1, 128, 256), 256, 0, stream>>>(Y, ST + 1536, g[3], be[3], X,
                                                                  1.f / (128.f * 512.f));

  // ---- head ----
  feat2_k<<<256, 256, 0, stream>>>(X, QK, QKT);
  refnorm_k<<<128, 256, 0, stream>>>(reff, RINV);
  reft_k<<<1152, 256, 0, stream>>>(reff, RINV, RFT);
  sneg2_k<<<dim3(8, 16), 256, 0, stream>>>(QKT, moco, SNEG);
  sref3_k<384><<<dim3(8, 16, 6), 256, 0, stream>>>(RFT, refq, SPART);
  sredr_k<6><<<dim3(8, 128), 256, 0, stream>>>(SPART, SREF);
  topk_k<<<128, 256, 0, stream>>>(SREF, iq, idxs, TOP);
  spos_k<<<1, 128, 0, stream>>>(QK, out);
  asm_k<<<dim3(8, 128), 256, 0, stream>>>(SNEG, SREF, iq, idxs, TOP, out);
}

// Round 16
// 734.434 us; speedup vs baseline: 3.7973x; 1.0620x over previous
//
#include <hip/hip_runtime.h>

// ---------------------------------------------------------------------------
// CoSSL round 16 (resubmit of R15 after container infra failure):
// implicit-im2col MFMA conv-GEMM (cgemmi_k) for L2/L3/L4 — gathers B-tile
// from X during LDS staging (no materialized im2col, no BB round-trip);
// L1 stays fp32 direct (streaming-bound). bf16 activations. sref split-K.
// Activations: [p*128+n][c][h][w], p=0 -> q (feats[:,1]), p=1 -> k (feats[:,0]).
// ---------------------------------------------------------------------------

#define NIMG 128
typedef __attribute__((ext_vector_type(8))) short bf16x8;
typedef __attribute__((ext_vector_type(4))) float f32x4;
typedef __attribute__((ext_vector_type(4))) unsigned int u32x4;
typedef unsigned long long ull;

__device__ __forceinline__ unsigned short f2bf(float f) {
  unsigned u = __float_as_uint(f);
  unsigned r = (u + 0x7fffu + ((u >> 16) & 1u)) >> 16;
  return (unsigned short)r;
}
__device__ __forceinline__ float bf2f(unsigned short u) {
  return __uint_as_float((unsigned)u << 16);
}

// ---------------- weight prep ------------------------------------------------
__global__ __launch_bounds__(256) void wtr3_k(
    const float* __restrict__ w1, const float* __restrict__ w2,
    const float* __restrict__ w3, const float* __restrict__ w4,
    float* __restrict__ t1, unsigned short* __restrict__ wb2,
    unsigned short* __restrict__ wb3, unsigned short* __restrict__ wb4) {
  const int i = blockIdx.x * 256 + threadIdx.x;
  if (i < 36) { int co = i / 9, r = i % 9; t1[r * 4 + co] = w1[i]; }
  if (i < 16 * 64) {
    int co = i / 64, k = i % 64;
    int tap = k >> 2, ci = k & 3;
    float v = (k < 36) ? w2[co * 36 + ci * 9 + tap] : 0.f;
    wb2[i] = f2bf(v);
  }
  if (i < 64 * 160) {
    int co = i / 160, k = i % 160;
    int tap = k >> 4, ci = k & 15;
    float v = (k < 144) ? w3[co * 144 + ci * 9 + tap] : 0.f;
    wb3[i] = f2bf(v);
  }
  if (i < 128 * 576) {
    int co = i / 576, k = i % 576;
    int tap = k / 64, ci = k & 63;
    wb4[i] = f2bf(w4[co * 576 + ci * 9 + tap]);
  }
}

// ---------------- direct conv (L1 only), bf16 y, per-block stats partials ---
template<int Cin, int Cout, int COB, int Hin, int Win, int TH, int CIC, int SPT, bool FIRST>
__global__ __launch_bounds__(256) void conv2_k(const void* __restrict__ in_,
    const float* __restrict__ wt, const float* __restrict__ bias,
    unsigned short* __restrict__ y, float* __restrict__ part1,
    float* __restrict__ part2) {
  constexpr int Hout = Hin / 2, Wout = Win / 2, HW = Hout * Wout;
  constexpr int R2 = 2 * TH + 1, W2 = Win + 2;
  constexpr int TILE = CIC * R2 * W2;
  __shared__ float tile[TILE];
  __shared__ float ws1[4][COB], ws2[4][COB];
  const int tid = threadIdx.x;
  const int pn = blockIdx.z;
  const int co0 = blockIdx.y * COB;
  const int h0 = blockIdx.x * TH;
  const int base_ih = 2 * h0 - 1;
  const float* ibF = nullptr;
  const unsigned short* ibH = nullptr;
  if constexpr (FIRST) {
    const int n = pn & 127;
    const int sel = (pn >> 7) == 0 ? 1 : 0;
    ibF = (const float*)in_ + (size_t)(n * 2 + sel) * (size_t)(Hin * Win);
  } else {
    ibH = (const unsigned short*)in_ + (size_t)pn * Cin * (size_t)(Hin * Win);
  }
  int th[SPT], tw[SPT];
#pragma unroll
  for (int s = 0; s < SPT; ++s) {
    const int sp = tid + s * 256;
    th[s] = sp / Wout; tw[s] = sp - th[s] * Wout;
  }
  float acc[COB * SPT];
#pragma unroll
  for (int i = 0; i < COB * SPT; ++i) acc[i] = 0.f;
  for (int st0 = 0; st0 < Cin; st0 += CIC) {
    for (int idx = tid; idx < TILE; idx += 256) {
      const int ci = idx / (R2 * W2);
      const int rem = idx - ci * (R2 * W2);
      const int r = rem / W2;
      const int c = rem - r * W2;
      const int ih = base_ih + r;
      const int iw = c - 1;
      float v = 0.f;
      if (ih >= 0 && iw >= 0 && iw < Win) {
        const size_t off = (size_t)(st0 + ci) * (Hin * Win) + ih * Win + iw;
        if constexpr (FIRST) v = ibF[off]; else v = bf2f(ibH[off]);
      }
      tile[idx] = v;
    }
    __syncthreads();
    for (int ci = 0; ci < CIC; ++ci) {
      const float* tci = tile + ci * (R2 * W2);
      const size_t wrow = ((size_t)(st0 + ci) * 9) * Cout + co0;
#pragma unroll
      for (int kh = 0; kh < 3; ++kh) {
        float2 fa[SPT], fb[SPT];
#pragma unroll
        for (int s = 0; s < SPT; ++s) {
          const float* p = tci + (2 * th[s] + kh) * W2 + 2 * tw[s];
          fa[s] = *(const float2*)p;
          fb[s] = *(const float2*)(p + 2);
        }
#pragma unroll
        for (int kw = 0; kw < 3; ++kw) {
          const float* wp = wt + wrow + (kh * 3 + kw) * Cout;
#pragma unroll
          for (int co = 0; co < COB; ++co) {
            const float wv = wp[co];
#pragma unroll
            for (int s = 0; s < SPT; ++s) {
              const float fv = (kw == 0) ? fa[s].x : (kw == 1) ? fa[s].y : fb[s].x;
              acc[co * SPT + s] = fmaf(fv, wv, acc[co * SPT + s]);
            }
          }
        }
      }
    }
    __syncthreads();
  }
  const int lane = tid & 63, wid = tid >> 6;
  const int p = pn >> 7;
  const size_t obase = ((size_t)pn * Cout + co0) * (size_t)HW + (size_t)h0 * Wout;
#pragma unroll
  for (int co = 0; co < COB; ++co) {
    const float bv = bias[co0 + co];
    float s1 = 0.f, s2 = 0.f;
#pragma unroll
    for (int s = 0; s < SPT; ++s) {
      const float v = acc[co * SPT + s] + bv;
      y[obase + (size_t)co * HW + tid + s * 256] = f2bf(v);
      s1 += v; s2 += v * v;
    }
#pragma unroll
    for (int m = 32; m >= 1; m >>= 1) { s1 += __shfl_xor(s1, m); s2 += __shfl_xor(s2, m); }
    if (lane == 0) { ws1[wid][co] = s1; ws2[wid][co] = s2; }
  }
  __syncthreads();
  if (tid < COB) {
    const float t1 = ws1[0][tid] + ws1[1][tid] + ws1[2][tid] + ws1[3][tid];
    const float t2 = ws2[0][tid] + ws2[1][tid] + ws2[2][tid] + ws2[3][tid];
    const int nblk = 128 * gridDim.x * gridDim.y;
    const int blk = ((pn & 127) * gridDim.y + blockIdx.y) * gridDim.x + blockIdx.x;
    part1[(size_t)(p * Cout + co0 + tid) * nblk + blk] = t1;
    part2[(size_t)(p * Cout + co0 + tid) * nblk + blk] = t2;
  }
}

// ---------------- implicit-im2col MFMA conv-GEMM + partial stats ------------
template<int Cin, int H, int W, int M, int SPB, int KP, int KC, int WCO, int WSP, int Cout>
__global__ __launch_bounds__(256) void cgemmi_k(
    const unsigned short* __restrict__ x,   // [pnl][Cin][H][W] bf16 (pass base)
    const unsigned short* __restrict__ wb,  // [M][KP] bf16
    const float* __restrict__ bias, unsigned short* __restrict__ y,
    float* __restrict__ part1, float* __restrict__ part2) {
  constexpr int Ho = H / 2, Wo = W / 2, HWout = Ho * Wo;
  constexpr int lgWo = (Wo == 8 ? 3 : (Wo == 16 ? 4 : 5));
  constexpr int lgCin = (Cin == 4 ? 2 : (Cin == 16 ? 4 : 6));
  constexpr int KCP = KC + 8;
  constexpr int MT = WCO / 16, NT = WSP / 16, KS = KC / 32;
  constexpr int NWN = SPB / WSP;
  constexpr int GR = (Cin < 8) ? 4 : 8;   // gather granularity (one tap span)
  __shared__ unsigned short wl[M][KCP];
  __shared__ unsigned short bl[SPB][KCP];
  __shared__ float ss1[Cout], ss2[Cout];
  const int tid = threadIdx.x;
  const int pnl = blockIdx.y;
  const int sp0 = blockIdx.x * SPB;
  const int lane = tid & 63, wid = tid >> 6;
  const int wm = wid / NWN, wn = wid - wm * NWN;
  const int l15 = lane & 15, lg = lane >> 4;
  const unsigned short* xb = x + (size_t)pnl * Cin * (H * W);

  for (int i = tid; i < Cout; i += 256) { ss1[i] = 0.f; ss2[i] = 0.f; }

  f32x4 acc[MT][NT];
#pragma unroll
  for (int mt = 0; mt < MT; ++mt)
#pragma unroll
    for (int nt = 0; nt < NT; ++nt) acc[mt][nt] = (f32x4){0.f, 0.f, 0.f, 0.f};

  for (int k0 = 0; k0 < KP; k0 += KC) {
    // A: weights (contiguous)
    for (int it = tid; it < M * (KC / 8); it += 256) {
      const int row = it / (KC / 8), seg = it - row * (KC / 8);
      const u32x4 v = *(const u32x4*)(wb + (size_t)row * KP + k0 + seg * 8);
      *(u32x4*)(&wl[row][seg * 8]) = v;
    }
    // B: implicit im2col gather from x
    for (int it = tid; it < SPB * (KC / GR); it += 256) {
      const int row = it / (KC / GR);
      const int rem = it - row * (KC / GR);
      const int k = k0 + rem * GR;
      const int tap = k >> lgCin;
      const int ci0 = k & (Cin - 1);
      const int sp = sp0 + row;
      const int ho = sp >> lgWo, wo = sp & (Wo - 1);
      const int kh = tap / 3, kw = tap - kh * 3;
      const int ih = 2 * ho - 1 + kh, iw = 2 * wo - 1 + kw;
      unsigned short* dst = &bl[row][k - k0];
      if (tap < 9 && (unsigned)ih < (unsigned)H && (unsigned)iw < (unsigned)W) {
        const unsigned short* src = xb + (size_t)ci0 * (H * W) + ih * W + iw;
        if constexpr (GR == 4) {
          const ull pk = (ull)src[0]
                       | ((ull)src[(size_t)(H * W)] << 16)
                       | ((ull)src[2 * (size_t)(H * W)] << 32)
                       | ((ull)src[3 * (size_t)(H * W)] << 48);
          *(ull*)dst = pk;
        } else {
          const ull lo = (ull)src[0]
                       | ((ull)src[(size_t)(H * W)] << 16)
                       | ((ull)src[2 * (size_t)(H * W)] << 32)
                       | ((ull)src[3 * (size_t)(H * W)] << 48);
          const ull hi = (ull)src[4 * (size_t)(H * W)]
                       | ((ull)src[5 * (size_t)(H * W)] << 16)
                       | ((ull)src[6 * (size_t)(H * W)] << 32)
                       | ((ull)src[7 * (size_t)(H * W)] << 48);
          *(ull*)dst = lo;
          *(ull*)(dst + 4) = hi;
        }
      } else {
        *(ull*)dst = 0ull;
        if constexpr (GR == 8) *(ull*)(dst + 4) = 0ull;
      }
    }
    __syncthreads();
#pragma unroll
    for (int ks = 0; ks < KS; ++ks) {
      bf16x8 af[MT], bfr[NT];
#pragma unroll
      for (int mt = 0; mt < MT; ++mt)
        af[mt] = *(const bf16x8*)(&wl[wm * WCO + mt * 16 + l15][ks * 32 + lg * 8]);
#pragma unroll
      for (int nt = 0; nt < NT; ++nt)
        bfr[nt] = *(const bf16x8*)(&bl[wn * WSP + nt * 16 + l15][ks * 32 + lg * 8]);
#pragma unroll
      for (int mt = 0; mt < MT; ++mt)
#pragma unroll
        for (int nt = 0; nt < NT; ++nt)
          acc[mt][nt] = __builtin_amdgcn_mfma_f32_16x16x32_bf16(af[mt], bfr[nt], acc[mt][nt], 0, 0, 0);
    }
    __syncthreads();
  }

  unsigned short* yb = y + (size_t)pnl * Cout * HWout;
#pragma unroll
  for (int mt = 0; mt < MT; ++mt) {
#pragma unroll
    for (int i = 0; i < 4; ++i) {
      const int co = wm * WCO + mt * 16 + lg * 4 + i;
      const float bv = bias[co];
      float s1 = 0.f, s2 = 0.f;
#pragma unroll
      for (int nt = 0; nt < NT; ++nt) {
        const float v = acc[mt][nt][i] + bv;
        yb[(size_t)co * HWout + sp0 + wn * WSP + nt * 16 + l15] = f2bf(v);
        s1 += v; s2 += v * v;
      }
#pragma unroll
      for (int m = 1; m < 16; m <<= 1) { s1 += __shfl_xor(s1, m); s2 += __shfl_xor(s2, m); }
      if (l15 == 0) {
        atomicAdd(&ss1[co], s1);
        atomicAdd(&ss2[co], s2);
      }
    }
  }
  __syncthreads();
  const int blkid = blockIdx.y * gridDim.x + blockIdx.x;
  const int nblk = gridDim.x * gridDim.y;
  for (int i = tid; i < Cout; i += 256) {
    part1[(size_t)i * nblk + blkid] = ss1[i];
    part2[(size_t)i * nblk + blkid] = ss2[i];
  }
}

// ---------------- reduce partials -> st (deterministic) ---------------------
__global__ __launch_bounds__(256) void redstat_k(const float* __restrict__ p1,
    const float* __restrict__ p2, float* __restrict__ st, int path, int Cout,
    int nblk) {
  const int co = blockIdx.x;
  float s1 = 0.f, s2 = 0.f;
  for (int i = threadIdx.x; i < nblk; i += 256) {
    s1 += p1[(size_t)co * nblk + i];
    s2 += p2[(size_t)co * nblk + i];
  }
  __shared__ float r1[256], r2[256];
  r1[threadIdx.x] = s1; r2[threadIdx.x] = s2;
  __syncthreads();
  for (int stp = 128; stp > 0; stp >>= 1) {
    if (threadIdx.x < stp) {
      r1[threadIdx.x] += r1[threadIdx.x + stp];
      r2[threadIdx.x] += r2[threadIdx.x + stp];
    }
    __syncthreads();
  }
  if (threadIdx.x == 0) {
    st[path * Cout + co] = r1[0];
    st[256 + path * Cout + co] = r2[0];
  }
}

// ---------------- BN + relu + avgpool, bf16 in/out, rolling rows ------------
template<int W>
__device__ __forceinline__ void row_hs(const unsigned short* __restrict__ yp,
                                       int hh, int H, int w0, float a, float b,
                                       float* hs) {
  if ((unsigned)hh >= (unsigned)H) { hs[0] = hs[1] = hs[2] = hs[3] = 0.f; return; }
  const unsigned short* rp = yp + hh * W;
  const ull B = *(const ull*)(rp + w0);
  float r0 = 0.f, r5 = 0.f;
  if (w0 > 0) r0 = fmaxf(fmaf(a, bf2f(rp[w0 - 1]), b), 0.f);
  if (w0 + 4 < W) r5 = fmaxf(fmaf(a, bf2f(rp[w0 + 4]), b), 0.f);
  const float r1 = fmaxf(fmaf(a, bf2f((unsigned short)(B & 0xffff)), b), 0.f);
  const float r2 = fmaxf(fmaf(a, bf2f((unsigned short)((B >> 16) & 0xffff)), b), 0.f);
  const float r3 = fmaxf(fmaf(a, bf2f((unsigned short)((B >> 32) & 0xffff)), b), 0.f);
  const float r4 = fmaxf(fmaf(a, bf2f((unsigned short)(B >> 48)), b), 0.f);
  hs[0] = r0 + r1 + r2;
  hs[1] = r1 + r2 + r3;
  hs[2] = r2 + r3 + r4;
  hs[3] = r3 + r4 + r5;
}

template<int Cout, int H, int W, int TH>
__global__ __launch_bounds__(256) void bnpool3_k(const unsigned short* __restrict__ y,
    const float* __restrict__ st, const float* __restrict__ g,
    const float* __restrict__ be, unsigned short* __restrict__ x, float invCnt) {
  constexpr int W4 = W / 4;
  constexpr int GROUPS = 256 / W4;
  constexpr int HW = H * W;
  const int tid = threadIdx.x;
  const int grp = tid / W4, lw = tid - grp * W4;
  const int w0 = lw * 4;
  const int h0 = (blockIdx.x * GROUPS + grp) * TH;
  if (h0 >= H) return;
  const int pn = blockIdx.z, c = blockIdx.y;
  const int p = pn >> 7;
  const float mean = st[p * Cout + c] * invCnt;
  const float var = fmaxf(st[256 + p * Cout + c] * invCnt - mean * mean, 0.f);
  const float a = g[c] * rsqrtf(var + 1e-5f);
  const float b = be[c] - mean * a;
  const unsigned short* yp = y + ((size_t)pn * Cout + c) * (size_t)HW;
  unsigned short* xp = x + ((size_t)pn * Cout + c) * (size_t)HW;

  float hsA[4], hsB[4], hsC[4];
  row_hs<W>(yp, h0 - 1, H, w0, a, b, hsA);
  row_hs<W>(yp, h0, H, w0, a, b, hsB);
#pragma unroll
  for (int t = 0; t < TH; ++t) {
    const int h = h0 + t;
    if (h >= H) break;
    row_hs<W>(yp, h + 1, H, w0, a, b, hsC);
    const ull o = (ull)f2bf((hsA[0] + hsB[0] + hsC[0]) * (1.f / 9.f))
                | ((ull)f2bf((hsA[1] + hsB[1] + hsC[1]) * (1.f / 9.f)) << 16)
                | ((ull)f2bf((hsA[2] + hsB[2] + hsC[2]) * (1.f / 9.f)) << 32)
                | ((ull)f2bf((hsA[3] + hsB[3] + hsC[3]) * (1.f / 9.f)) << 48);
    *(ull*)(xp + h * W + w0) = o;
#pragma unroll
    for (int i = 0; i < 4; ++i) { hsA[i] = hsB[i]; hsB[i] = hsC[i]; }
  }
}

// ---------------- global mean + l2norm (bf16 in); also writes qkT -----------
__global__ __launch_bounds__(256) void feat2_k(const unsigned short* __restrict__ x,
    float* __restrict__ qk, float* __restrict__ qkT) {
  const int pn = blockIdx.x;
  const int tid = threadIdx.x;
  const int lane = tid & 63, wid = tid >> 6;
  __shared__ float fm[128];
  __shared__ float red[128];
  const unsigned short* xb = x + (size_t)pn * 128 * 512;
  for (int c = wid; c < 128; c += 4) {
    const unsigned short* xp = xb + (size_t)c * 512;
    float s = 0.f;
#pragma unroll
    for (int r = 0; r < 4; ++r) {
      const unsigned v = *(const unsigned*)(xp + lane * 2 + r * 128);
      s += bf2f((unsigned short)(v & 0xffff)) + bf2f((unsigned short)(v >> 16));
    }
#pragma unroll
    for (int m = 32; m >= 1; m >>= 1) s += __shfl_xor(s, m);
    if (lane == 0) fm[c] = s * (1.f / 512.f);
  }
  __syncthreads();
  if (tid < 128) red[tid] = fm[tid] * fm[tid];
  __syncthreads();
  for (int step = 64; step > 0; step >>= 1) {
    if (tid < step) red[tid] += red[tid + step];
    __syncthreads();
  }
  const float inv = 1.f / fmaxf(sqrtf(red[0]), 1e-12f);
  if (tid < 128) {
    const float v = fm[tid] * inv;
    qk[(size_t)pn * 128 + tid] = v;
    if (pn < 128) qkT[(size_t)tid * 128 + pn] = v;
  }
}

// ---------------- 1/||ref row|| ---------------------------------------------
__global__ __launch_bounds__(256) void refnorm_k(const float* __restrict__ rf,
    float* __restrict__ rinv) {
  const int n = blockIdx.x;
  float s = 0.f;
  for (int i = threadIdx.x; i < 2304; i += 256) {
    float v = rf[(size_t)n * 2304 + i];
    s += v * v;
  }
  __shared__ float red[256];
  red[threadIdx.x] = s;
  __syncthreads();
  for (int step = 128; step > 0; step >>= 1) {
    if (threadIdx.x < step) red[threadIdx.x] += red[threadIdx.x + step];
    __syncthreads();
  }
  if (threadIdx.x == 0) rinv[n] = 1.f / fmaxf(sqrtf(red[0]), 1e-12f);
}

// ---------------- rfT[k][n] = reff[n][k] * rinv[n] --------------------------
__global__ __launch_bounds__(256) void reft_k(const float* __restrict__ rf,
    const float* __restrict__ rinv, float* __restrict__ rfT) {
  const int flat = blockIdx.x * 256 + threadIdx.x;
  const int n = flat / 2304, k = flat - n * 2304;
  rfT[(size_t)k * 128 + n] = rf[flat] * rinv[n];
}

// ---------------- score_neg = q @ MoCoQueue (8 rows/block) ------------------
__global__ __launch_bounds__(256) void sneg2_k(const float* __restrict__ qkT,
    const float* __restrict__ moco, float* __restrict__ out) {
  const int j = blockIdx.x * 256 + threadIdx.x;
  const int n0 = blockIdx.y * 8;
  float acc[8] = {0.f};
#pragma unroll 4
  for (int k = 0; k < 128; ++k) {
    const float rv = moco[(size_t)k * 2048 + j];
    const float* qp = qkT + (size_t)k * 128 + n0;
#pragma unroll
    for (int i = 0; i < 8; ++i) acc[i] = fmaf(qp[i], rv, acc[i]);
  }
#pragma unroll
  for (int i = 0; i < 8; ++i) out[(size_t)(n0 + i) * 2048 + j] = acc[i];
}

// ---------------- score_ref split-K: partial over k-chunk -------------------
template<int KCH>
__global__ __launch_bounds__(256) void sref3_k(const float* __restrict__ rfT,
    const float* __restrict__ rq, float* __restrict__ part) {
  const int j = blockIdx.x * 256 + threadIdx.x;
  const int n0 = blockIdx.y * 8;
  const int kc = blockIdx.z;
  const int kbeg = kc * KCH;
  float acc[8] = {0.f};
#pragma unroll 4
  for (int k = kbeg; k < kbeg + KCH; ++k) {
    const float rv = rq[(size_t)k * 2048 + j];
    const float* rp = rfT + (size_t)k * 128 + n0;
#pragma unroll
    for (int i = 0; i < 8; ++i) acc[i] = fmaf(rp[i], rv, acc[i]);
  }
  float* pb = part + (size_t)kc * (128 * 2048);
#pragma unroll
  for (int i = 0; i < 8; ++i) pb[(size_t)(n0 + i) * 2048 + j] = acc[i];
}

// ---------------- reduce split-K partials -> SREF ---------------------------
template<int NCH>
__global__ __launch_bounds__(256) void sredr_k(const float* __restrict__ part,
    float* __restrict__ out) {
  const int j = blockIdx.x * 256 + threadIdx.x;
  const int n = blockIdx.y;
  const size_t off = (size_t)n * 2048 + j;
  float s = 0.f;
#pragma unroll
  for (int c = 0; c < NCH; ++c) s += part[(size_t)c * (128 * 2048) + off];
  out[off] = s;
}

// ---------------- top-5 per row of masked score_ref -------------------------
__global__ __launch_bounds__(256) void topk_k(const float* __restrict__ sref,
    const float* __restrict__ iq, const int* __restrict__ idxs,
    int* __restrict__ top) {
  const int n = blockIdx.x;
  const float target = (float)idxs[n];
  float vals[8];
#pragma unroll
  for (int r = 0; r < 8; ++r) {
    const int j = threadIdx.x + r * 256;
    const bool m = (iq[j] == target);
    vals[r] = m ? -__builtin_inff() : sref[(size_t)n * 2048 + j];
  }
  __shared__ float sv[256];
  __shared__ int si[256];
  __shared__ int chosen[5];
  for (int rnd = 0; rnd < 5; ++rnd) {
    float bv = -__builtin_inff();
    int bi = 1 << 30;
#pragma unroll
    for (int r = 0; r < 8; ++r) {
      const int j = threadIdx.x + r * 256;
      bool taken = false;
      for (int t = 0; t < rnd; ++t) taken |= (chosen[t] == j);
      const float v = vals[r];
      if (!taken && (v > bv || (v == bv && j < bi))) { bv = v; bi = j; }
    }
    sv[threadIdx.x] = bv; si[threadIdx.x] = bi;
    __syncthreads();
    for (int step = 128; step > 0; step >>= 1) {
      if (threadIdx.x < step) {
        const float ov = sv[threadIdx.x + step];
        const int oi = si[threadIdx.x + step];
        if (ov > sv[threadIdx.x] || (ov == sv[threadIdx.x] && oi < si[threadIdx.x])) {
          sv[threadIdx.x] = ov; si[threadIdx.x] = oi;
        }
      }
      __syncthreads();
    }
    if (threadIdx.x == 0) chosen[rnd] = si[0];
    __syncthreads();
  }
  if (threadIdx.x < 5) top[n * 5 + threadIdx.x] = chosen[threadIdx.x];
}

// ---------------- score_pos + first columns ---------------------------------
__global__ __launch_bounds__(128) void spos_k(const float* __restrict__ qk,
    float* __restrict__ out) {
  const int n = threadIdx.x;
  float s = 0.f;
  for (int c = 0; c < 128; ++c)
    s = fmaf(qk[(size_t)n * 128 + c], qk[(size_t)(NIMG + n) * 128 + c], s);
  out[(size_t)n * 2049] = s;
  out[(size_t)NIMG * 2049 + (size_t)n * 2049] = 1.f;
}

// ---------------- final assembly --------------------------------------------
__global__ __launch_bounds__(256) void asm_k(const float* __restrict__ sneg,
    const float* __restrict__ sref, const float* __restrict__ iq,
    const int* __restrict__ idxs, const int* __restrict__ top,
    float* __restrict__ out) {
  const int n = blockIdx.y;
  const int j = blockIdx.x * 256 + threadIdx.x;
  const int t0 = top[n * 5 + 0], t1 = top[n * 5 + 1], t2 = top[n * 5 + 2];
  const int t3 = top[n * 5 + 3], t4 = top[n * 5 + 4];
  const float target = (float)idxs[n];
  const bool m = (iq[j] == target);
  const float sr = sref[(size_t)n * 2048 + j];
  const float sr2 = m ? 1.f : sr;
  const bool istop = (j == t0) | (j == t1) | (j == t2) | (j == t3) | (j == t4);
  const float wgt = istop ? 1.f : -1.f;
  out[(size_t)n * 2049 + 1 + j] = sneg[(size_t)n * 2048 + j] * sr2 * wgt;
  const float mf = istop ? 1.f : (m ? 1.f : 0.f);
  out[(size_t)NIMG * 2049 + (size_t)n * 2049 + 1 + j] = mf;
}

// ---------------------------------------------------------------------------
extern "C" void kernel_launch(void* const* d_in, const int* in_sizes, int n_in,
                              void* d_out, int out_size, void* d_ws, size_t ws_size,
                              hipStream_t stream) {
  const float* feats = (const float*)d_in[0];
  const float* reff  = (const float*)d_in[1];
  const int*   idxs  = (const int*)d_in[2];
  const float* moco  = (const float*)d_in[3];
  const float* refq  = (const float*)d_in[4];
  const float* iq    = (const float*)d_in[5];
  const float* w[4]  = {(const float*)d_in[6],  (const float*)d_in[10],
                        (const float*)d_in[14], (const float*)d_in[18]};
  const float* b[4]  = {(const float*)d_in[7],  (const float*)d_in[11],
                        (const float*)d_in[15], (const float*)d_in[19]};
  const float* g[4]  = {(const float*)d_in[8],  (const float*)d_in[12],
                        (const float*)d_in[16], (const float*)d_in[20]};
  const float* be[4] = {(const float*)d_in[9],  (const float*)d_in[13],
                        (const float*)d_in[17], (const float*)d_in[21]};
  float* out = (float*)d_out;

  // workspace layout
  const size_t BIG = 33554432;  // 2*128*131072 elements
  unsigned short* X = (unsigned short*)d_ws;            // BIG bf16
  unsigned short* Y = X + BIG;                          // BIG bf16
  float* ST   = (float*)(Y + BIG);  // 4 layers x 512
  float* WT1  = ST + 2048;          // 36 (reserve 64)
  unsigned short* WB2 = (unsigned short*)(WT1 + 64);    // 16*64
  unsigned short* WB3 = WB2 + 1024;                     // 64*160
  unsigned short* WB4 = WB3 + 10240;                    // 128*576
  float* QK   = (float*)(WB4 + 73728);                  // 2*128*128
  float* QKT  = QK + 32768;         // 128*128
  float* RINV = QKT + 16384;        // 128
  float* RFT  = RINV + 128;         // 2304*128
  float* SNEG = RFT + 294912;       // 128*2048
  float* SREF = SNEG + 262144;      // 128*2048
  int*   TOP  = (int*)(SREF + 262144);                  // 128*5
  float* SPART = (float*)(TOP + 256);                   // 6 x 1M floats
  // stats partials alias the (dead-until-head) SNEG area (max 65536 each)
  float* PART1 = SNEG;
  float* PART2 = SNEG + 65536;

  wtr3_k<<<288, 256, 0, stream>>>(w[0], w[1], w[2], w[3], WT1, WB2, WB3, WB4);

  // ---- layer 1: (1 -> 4), 1024x128 -> 512x64 (fp32 direct, bf16 out) ----
  conv2_k<1, 4, 4, 1024, 128, 8, 1, 2, true>
      <<<dim3(64, 1, 256), 256, 0, stream>>>(feats, WT1, b[0], Y, PART1, PART2);
  redstat_k<<<8, 256, 0, stream>>>(PART1, PART2, ST, 0, 8, 8192);
  bnpool3_k<4, 512, 64, 8><<<dim3(4, 4, 256), 256, 0, stream>>>(Y, ST, g[0], be[0], X,
                                                                1.f / (128.f * 32768.f));
  // ---- layer 2: (4 -> 16), 512x64 -> 256x32 via implicit MFMA, 2 passes ----
  for (int pass = 0; pass < 2; ++pass) {
    const size_t xo = (size_t)pass * 128 * 4 * 512 * 64;
    const size_t yo = (size_t)pass * 128 * 16 * 8192;
    cgemmi_k<4, 512, 64, 16, 256, 64, 64, 16, 64, 16>
        <<<dim3(32, 128), 256, 0, stream>>>(X + xo, WB2, b[1], Y + yo, PART1, PART2);
    redstat_k<<<16, 256, 0, stream>>>(PART1, PART2, ST + 512, pass, 16, 32 * 128);
  }
  bnpool3_k<16, 256, 32, 4><<<dim3(2, 16, 256), 256, 0, stream>>>(Y, ST + 512, g[1], be[1], X,
                                                                  1.f / (128.f * 8192.f));
  // ---- layer 3: (16 -> 64), 256x32 -> 128x16 via implicit MFMA, 2 passes ----
  for (int pass = 0; pass < 2; ++pass) {
    const size_t xo = (size_t)pass * 128 * 16 * 8192;
    const size_t yo = (size_t)pass * 128 * 64 * 2048;
    cgemmi_k<16, 256, 32, 64, 256, 160, 32, 64, 64, 64>
        <<<dim3(8, 128), 256, 0, stream>>>(X + xo, WB3, b[2], Y + yo, PART1, PART2);
    redstat_k<<<64, 256, 0, stream>>>(PART1, PART2, ST + 1024, pass, 64, 8 * 128);
  }
  bnpool3_k<64, 128, 16, 2><<<dim3(1, 64, 256), 256, 0, stream>>>(Y, ST + 1024, g[2], be[2], X,
                                                                  1.f / (128.f * 2048.f));
  // ---- layer 4: (64 -> 128), 128x16 -> 64x8 via implicit MFMA, 2 passes ----
  for (int pass = 0; pass < 2; ++pass) {
    const size_t xo = (size_t)pass * 128 * 64 * 2048;
    const size_t yo = (size_t)pass * 128 * 128 * 512;
    cgemmi_k<64, 128, 16, 128, 128, 576, 64, 32, 128, 128>
        <<<dim3(4, 128), 256, 0, stream>>>(X + xo, WB4, b[3], Y + yo, PART1, PART2);
    redstat_k<<<128, 256, 0, stream>>>(PART1, PART2, ST + 1536, pass, 128, 4 * 128);
  }
  bnpool3_k<128, 64, 8, 1><<<dim3(1, 128, 256), 256, 0, stream>>>(Y, ST + 1536, g[3], be[3], X,
                                                                  1.f / (128.f * 512.f));

  // ---- head ----
  feat2_k<<<256, 256, 0, stream>>>(X, QK, QKT);
  refnorm_k<<<128, 256, 0, stream>>>(reff, RINV);
  reft_k<<<1152, 256, 0, stream>>>(reff, RINV, RFT);
  sneg2_k<<<dim3(8, 16), 256, 0, stream>>>(QKT, moco, SNEG);
  sref3_k<384><<<dim3(8, 16, 6), 256, 0, stream>>>(RFT, refq, SPART);
  sredr_k<6><<<dim3(8, 128), 256, 0, stream>>>(SPART, SREF);
  topk_k<<<128, 256, 0, stream>>>(SREF, iq, idxs, TOP);
  spos_k<<<1, 128, 0, stream>>>(QK, out);
  asm_k<<<dim3(8, 128), 256, 0, stream>>>(SNEG, SREF, iq, idxs, TOP, out);
}

// Round 17
// 668.801 us; speedup vs baseline: 4.1700x; 1.0981x over previous
//
#include <hip/hip_runtime.h>

// ---------------------------------------------------------------------------
// CoSSL round 17: (1) L1 conv -> conv1s_k rolling-row register conv (no LDS,
// no div/mod; was 88us @ 43% VALU for a 40us streaming job). (2) cgemmi/redstat
// single-pass over all 256 pn (2-pass loop was vestigial post-im2col removal).
// bf16 activations; implicit-im2col MFMA for L2/L3/L4; sref split-K.
// Activations: [p*128+n][c][h][w], p=0 -> q (feats[:,1]), p=1 -> k (feats[:,0]).
// ---------------------------------------------------------------------------

#define NIMG 128
typedef __attribute__((ext_vector_type(8))) short bf16x8;
typedef __attribute__((ext_vector_type(4))) float f32x4;
typedef __attribute__((ext_vector_type(4))) unsigned int u32x4;
typedef unsigned long long ull;

__device__ __forceinline__ unsigned short f2bf(float f) {
  unsigned u = __float_as_uint(f);
  unsigned r = (u + 0x7fffu + ((u >> 16) & 1u)) >> 16;
  return (unsigned short)r;
}
__device__ __forceinline__ float bf2f(unsigned short u) {
  return __uint_as_float((unsigned)u << 16);
}

// ---------------- weight prep ------------------------------------------------
// wb2: [16][64] bf16, k=tap*4+ci (zeros k>=36).
// wb3: [64][160] bf16, k=tap*16+ci (zeros k>=144). wb4: [128][576], k=tap*64+ci.
__global__ __launch_bounds__(256) void wtr4_k(
    const float* __restrict__ w2, const float* __restrict__ w3,
    const float* __restrict__ w4, unsigned short* __restrict__ wb2,
    unsigned short* __restrict__ wb3, unsigned short* __restrict__ wb4) {
  const int i = blockIdx.x * 256 + threadIdx.x;
  if (i < 16 * 64) {
    int co = i / 64, k = i % 64;
    int tap = k >> 2, ci = k & 3;
    float v = (k < 36) ? w2[co * 36 + ci * 9 + tap] : 0.f;
    wb2[i] = f2bf(v);
  }
  if (i < 64 * 160) {
    int co = i / 160, k = i % 160;
    int tap = k >> 4, ci = k & 15;
    float v = (k < 144) ? w3[co * 144 + ci * 9 + tap] : 0.f;
    wb3[i] = f2bf(v);
  }
  if (i < 128 * 576) {
    int co = i / 576, k = i % 576;
    int tap = k / 64, ci = k & 63;
    wb4[i] = f2bf(w4[co * 576 + ci * 9 + tap]);
  }
}

// ---------------- L1 conv: rolling-row register conv (Cin=1, Cout=4) --------
// 1024x128 fp32 -> 512x64 bf16, stride 2, pad 1. Thread: 4 outputs/row,
// TH=8 rows; 3 input rows live in registers, stride-2 roll reuses one.
__device__ __forceinline__ void l1row(const float* __restrict__ ib, int ih,
                                      int w0i, float* r) {
  if (ih < 0) {
#pragma unroll
    for (int q = 0; q < 9; ++q) r[q] = 0.f;
    return;
  }
  const float* rp = ib + ih * 128 + 2 * w0i;
  const float4 a = *(const float4*)rp;
  const float4 b = *(const float4*)(rp + 4);
  r[0] = (w0i > 0) ? rp[-1] : 0.f;
  r[1] = a.x; r[2] = a.y; r[3] = a.z; r[4] = a.w;
  r[5] = b.x; r[6] = b.y; r[7] = b.z; r[8] = b.w;
}

__global__ __launch_bounds__(256) void conv1s_k(const float* __restrict__ feats,
    const float* __restrict__ w1, const float* __restrict__ b1,
    unsigned short* __restrict__ y, float* __restrict__ part1,
    float* __restrict__ part2) {
  constexpr int TH = 8;
  const int tid = threadIdx.x;
  const int lw = tid & 15, grp = tid >> 4;      // 16 threads/row, 16 groups
  const int h0 = (blockIdx.x * 16 + grp) * TH;  // gridx=4 -> 512 rows
  const int pn = blockIdx.z;
  const int p = pn >> 7, n = pn & 127;
  const int sel = (p == 0) ? 1 : 0;
  const float* ib = feats + (size_t)(n * 2 + sel) * 131072;
  const int w0i = lw * 4;

  float wgt[36];
#pragma unroll
  for (int t = 0; t < 36; ++t) wgt[t] = w1[t];  // [co][kh][kw], wave-uniform
  float bv[4];
#pragma unroll
  for (int c = 0; c < 4; ++c) bv[c] = b1[c];

  float s1[4] = {0.f, 0.f, 0.f, 0.f}, s2[4] = {0.f, 0.f, 0.f, 0.f};
  float r0[9], r1[9], r2[9];
  l1row(ib, 2 * h0 - 1, w0i, r0);
  l1row(ib, 2 * h0, w0i, r1);
#pragma unroll
  for (int t = 0; t < TH; ++t) {
    const int h = h0 + t;
    l1row(ib, 2 * h + 1, w0i, r2);
#pragma unroll
    for (int co = 0; co < 4; ++co) {
      unsigned short ob[4];
#pragma unroll
      for (int i = 0; i < 4; ++i) {
        float v = bv[co];
#pragma unroll
        for (int kw = 0; kw < 3; ++kw) {
          v = fmaf(wgt[co * 9 + kw],     r0[2 * i + kw], v);
          v = fmaf(wgt[co * 9 + 3 + kw], r1[2 * i + kw], v);
          v = fmaf(wgt[co * 9 + 6 + kw], r2[2 * i + kw], v);
        }
        ob[i] = f2bf(v);
        s1[co] += v; s2[co] += v * v;
      }
      const ull o = (ull)ob[0] | ((ull)ob[1] << 16) | ((ull)ob[2] << 32)
                  | ((ull)ob[3] << 48);
      *(ull*)(y + (((size_t)pn * 4 + co) * 512 + h) * 64 + w0i) = o;
    }
    if (t + 1 < TH) {
#pragma unroll
      for (int q = 0; q < 9; ++q) r0[q] = r2[q];
      l1row(ib, 2 * h + 2, w0i, r1);
    }
  }
  __shared__ float ws1[4][4], ws2[4][4];
  const int lane = tid & 63, wid = tid >> 6;
#pragma unroll
  for (int co = 0; co < 4; ++co) {
#pragma unroll
    for (int m = 32; m >= 1; m >>= 1) {
      s1[co] += __shfl_xor(s1[co], m);
      s2[co] += __shfl_xor(s2[co], m);
    }
    if (lane == 0) { ws1[wid][co] = s1[co]; ws2[wid][co] = s2[co]; }
  }
  __syncthreads();
  if (tid < 4) {
    const float t1 = ws1[0][tid] + ws1[1][tid] + ws1[2][tid] + ws1[3][tid];
    const float t2 = ws2[0][tid] + ws2[1][tid] + ws2[2][tid] + ws2[3][tid];
    const int nblk = gridDim.x * 128;
    const int blk = (pn & 127) * gridDim.x + blockIdx.x;
    part1[(size_t)(p * 4 + tid) * nblk + blk] = t1;
    part2[(size_t)(p * 4 + tid) * nblk + blk] = t2;
  }
}

// ---------------- implicit-im2col MFMA conv-GEMM + partial stats ------------
// Single pass over all 256 pn (grid y = 256). Partial row = p*Cout+co.
template<int Cin, int H, int W, int M, int SPB, int KP, int KC, int WCO, int WSP, int Cout>
__global__ __launch_bounds__(256) void cgemmi_k(
    const unsigned short* __restrict__ x,   // [pn][Cin][H][W] bf16
    const unsigned short* __restrict__ wb,  // [M][KP] bf16
    const float* __restrict__ bias, unsigned short* __restrict__ y,
    float* __restrict__ part1, float* __restrict__ part2) {
  constexpr int Ho = H / 2, Wo = W / 2, HWout = Ho * Wo;
  constexpr int lgWo = (Wo == 8 ? 3 : (Wo == 16 ? 4 : 5));
  constexpr int lgCin = (Cin == 4 ? 2 : (Cin == 16 ? 4 : 6));
  constexpr int KCP = KC + 8;
  constexpr int MT = WCO / 16, NT = WSP / 16, KS = KC / 32;
  constexpr int NWN = SPB / WSP;
  constexpr int GR = (Cin < 8) ? 4 : 8;
  __shared__ unsigned short wl[M][KCP];
  __shared__ unsigned short bl[SPB][KCP];
  __shared__ float ss1[Cout], ss2[Cout];
  const int tid = threadIdx.x;
  const int pnl = blockIdx.y;
  const int p = pnl >> 7;
  const int sp0 = blockIdx.x * SPB;
  const int lane = tid & 63, wid = tid >> 6;
  const int wm = wid / NWN, wn = wid - wm * NWN;
  const int l15 = lane & 15, lg = lane >> 4;
  const unsigned short* xb = x + (size_t)pnl * Cin * (H * W);

  for (int i = tid; i < Cout; i += 256) { ss1[i] = 0.f; ss2[i] = 0.f; }

  f32x4 acc[MT][NT];
#pragma unroll
  for (int mt = 0; mt < MT; ++mt)
#pragma unroll
    for (int nt = 0; nt < NT; ++nt) acc[mt][nt] = (f32x4){0.f, 0.f, 0.f, 0.f};

  for (int k0 = 0; k0 < KP; k0 += KC) {
    for (int it = tid; it < M * (KC / 8); it += 256) {
      const int row = it / (KC / 8), seg = it - row * (KC / 8);
      const u32x4 v = *(const u32x4*)(wb + (size_t)row * KP + k0 + seg * 8);
      *(u32x4*)(&wl[row][seg * 8]) = v;
    }
    for (int it = tid; it < SPB * (KC / GR); it += 256) {
      const int row = it / (KC / GR);
      const int rem = it - row * (KC / GR);
      const int k = k0 + rem * GR;
      const int tap = k >> lgCin;
      const int ci0 = k & (Cin - 1);
      const int sp = sp0 + row;
      const int ho = sp >> lgWo, wo = sp & (Wo - 1);
      const int kh = tap / 3, kw = tap - kh * 3;
      const int ih = 2 * ho - 1 + kh, iw = 2 * wo - 1 + kw;
      unsigned short* dst = &bl[row][k - k0];
      if (tap < 9 && (unsigned)ih < (unsigned)H && (unsigned)iw < (unsigned)W) {
        const unsigned short* src = xb + (size_t)ci0 * (H * W) + ih * W + iw;
        if constexpr (GR == 4) {
          const ull pk = (ull)src[0]
                       | ((ull)src[(size_t)(H * W)] << 16)
                       | ((ull)src[2 * (size_t)(H * W)] << 32)
                       | ((ull)src[3 * (size_t)(H * W)] << 48);
          *(ull*)dst = pk;
        } else {
          const ull lo = (ull)src[0]
                       | ((ull)src[(size_t)(H * W)] << 16)
                       | ((ull)src[2 * (size_t)(H * W)] << 32)
                       | ((ull)src[3 * (size_t)(H * W)] << 48);
          const ull hi = (ull)src[4 * (size_t)(H * W)]
                       | ((ull)src[5 * (size_t)(H * W)] << 16)
                       | ((ull)src[6 * (size_t)(H * W)] << 32)
                       | ((ull)src[7 * (size_t)(H * W)] << 48);
          *(ull*)dst = lo;
          *(ull*)(dst + 4) = hi;
        }
      } else {
        *(ull*)dst = 0ull;
        if constexpr (GR == 8) *(ull*)(dst + 4) = 0ull;
      }
    }
    __syncthreads();
#pragma unroll
    for (int ks = 0; ks < KS; ++ks) {
      bf16x8 af[MT], bfr[NT];
#pragma unroll
      for (int mt = 0; mt < MT; ++mt)
        af[mt] = *(const bf16x8*)(&wl[wm * WCO + mt * 16 + l15][ks * 32 + lg * 8]);
#pragma unroll
      for (int nt = 0; nt < NT; ++nt)
        bfr[nt] = *(const bf16x8*)(&bl[wn * WSP + nt * 16 + l15][ks * 32 + lg * 8]);
#pragma unroll
      for (int mt = 0; mt < MT; ++mt)
#pragma unroll
        for (int nt = 0; nt < NT; ++nt)
          acc[mt][nt] = __builtin_amdgcn_mfma_f32_16x16x32_bf16(af[mt], bfr[nt], acc[mt][nt], 0, 0, 0);
    }
    __syncthreads();
  }

  unsigned short* yb = y + (size_t)pnl * Cout * HWout;
#pragma unroll
  for (int mt = 0; mt < MT; ++mt) {
#pragma unroll
    for (int i = 0; i < 4; ++i) {
      const int co = wm * WCO + mt * 16 + lg * 4 + i;
      const float bv = bias[co];
      float s1 = 0.f, s2 = 0.f;
#pragma unroll
      for (int nt = 0; nt < NT; ++nt) {
        const float v = acc[mt][nt][i] + bv;
        yb[(size_t)co * HWout + sp0 + wn * WSP + nt * 16 + l15] = f2bf(v);
        s1 += v; s2 += v * v;
      }
#pragma unroll
      for (int m = 1; m < 16; m <<= 1) { s1 += __shfl_xor(s1, m); s2 += __shfl_xor(s2, m); }
      if (l15 == 0) {
        atomicAdd(&ss1[co], s1);
        atomicAdd(&ss2[co], s2);
      }
    }
  }
  __syncthreads();
  const int nblk = gridDim.x * 128;
  const int blkid = (pnl & 127) * gridDim.x + blockIdx.x;
  for (int i = tid; i < Cout; i += 256) {
    part1[(size_t)(p * Cout + i) * nblk + blkid] = ss1[i];
    part2[(size_t)(p * Cout + i) * nblk + blkid] = ss2[i];
  }
}

// ---------------- reduce partials -> st (row = blockIdx.x over 2*Cout) ------
__global__ __launch_bounds__(256) void redstat_k(const float* __restrict__ p1,
    const float* __restrict__ p2, float* __restrict__ st, int nblk) {
  const int row = blockIdx.x;
  float s1 = 0.f, s2 = 0.f;
  for (int i = threadIdx.x; i < nblk; i += 256) {
    s1 += p1[(size_t)row * nblk + i];
    s2 += p2[(size_t)row * nblk + i];
  }
  __shared__ float r1[256], r2[256];
  r1[threadIdx.x] = s1; r2[threadIdx.x] = s2;
  __syncthreads();
  for (int stp = 128; stp > 0; stp >>= 1) {
    if (threadIdx.x < stp) {
      r1[threadIdx.x] += r1[threadIdx.x + stp];
      r2[threadIdx.x] += r2[threadIdx.x + stp];
    }
    __syncthreads();
  }
  if (threadIdx.x == 0) {
    st[row] = r1[0];
    st[256 + row] = r2[0];
  }
}

// ---------------- BN + relu + avgpool, bf16 in/out, rolling rows ------------
template<int W>
__device__ __forceinline__ void row_hs(const unsigned short* __restrict__ yp,
                                       int hh, int H, int w0, float a, float b,
                                       float* hs) {
  if ((unsigned)hh >= (unsigned)H) { hs[0] = hs[1] = hs[2] = hs[3] = 0.f; return; }
  const unsigned short* rp = yp + hh * W;
  const ull B = *(const ull*)(rp + w0);
  float r0 = 0.f, r5 = 0.f;
  if (w0 > 0) r0 = fmaxf(fmaf(a, bf2f(rp[w0 - 1]), b), 0.f);
  if (w0 + 4 < W) r5 = fmaxf(fmaf(a, bf2f(rp[w0 + 4]), b), 0.f);
  const float r1 = fmaxf(fmaf(a, bf2f((unsigned short)(B & 0xffff)), b), 0.f);
  const float r2 = fmaxf(fmaf(a, bf2f((unsigned short)((B >> 16) & 0xffff)), b), 0.f);
  const float r3 = fmaxf(fmaf(a, bf2f((unsigned short)((B >> 32) & 0xffff)), b), 0.f);
  const float r4 = fmaxf(fmaf(a, bf2f((unsigned short)(B >> 48)), b), 0.f);
  hs[0] = r0 + r1 + r2;
  hs[1] = r1 + r2 + r3;
  hs[2] = r2 + r3 + r4;
  hs[3] = r3 + r4 + r5;
}

template<int Cout, int H, int W, int TH>
__global__ __launch_bounds__(256) void bnpool3_k(const unsigned short* __restrict__ y,
    const float* __restrict__ st, const float* __restrict__ g,
    const float* __restrict__ be, unsigned short* __restrict__ x, float invCnt) {
  constexpr int W4 = W / 4;
  constexpr int GROUPS = 256 / W4;
  constexpr int HW = H * W;
  const int tid = threadIdx.x;
  const int grp = tid / W4, lw = tid - grp * W4;
  const int w0 = lw * 4;
  const int h0 = (blockIdx.x * GROUPS + grp) * TH;
  if (h0 >= H) return;
  const int pn = blockIdx.z, c = blockIdx.y;
  const int p = pn >> 7;
  const float mean = st[p * Cout + c] * invCnt;
  const float var = fmaxf(st[256 + p * Cout + c] * invCnt - mean * mean, 0.f);
  const float a = g[c] * rsqrtf(var + 1e-5f);
  const float b = be[c] - mean * a;
  const unsigned short* yp = y + ((size_t)pn * Cout + c) * (size_t)HW;
  unsigned short* xp = x + ((size_t)pn * Cout + c) * (size_t)HW;

  float hsA[4], hsB[4], hsC[4];
  row_hs<W>(yp, h0 - 1, H, w0, a, b, hsA);
  row_hs<W>(yp, h0, H, w0, a, b, hsB);
#pragma unroll
  for (int t = 0; t < TH; ++t) {
    const int h = h0 + t;
    if (h >= H) break;
    row_hs<W>(yp, h + 1, H, w0, a, b, hsC);
    const ull o = (ull)f2bf((hsA[0] + hsB[0] + hsC[0]) * (1.f / 9.f))
                | ((ull)f2bf((hsA[1] + hsB[1] + hsC[1]) * (1.f / 9.f)) << 16)
                | ((ull)f2bf((hsA[2] + hsB[2] + hsC[2]) * (1.f / 9.f)) << 32)
                | ((ull)f2bf((hsA[3] + hsB[3] + hsC[3]) * (1.f / 9.f)) << 48);
    *(ull*)(xp + h * W + w0) = o;
#pragma unroll
    for (int i = 0; i < 4; ++i) { hsA[i] = hsB[i]; hsB[i] = hsC[i]; }
  }
}

// ---------------- global mean + l2norm (bf16 in); also writes qkT -----------
__global__ __launch_bounds__(256) void feat2_k(const unsigned short* __restrict__ x,
    float* __restrict__ qk, float* __restrict__ qkT) {
  const int pn = blockIdx.x;
  const int tid = threadIdx.x;
  const int lane = tid & 63, wid = tid >> 6;
  __shared__ float fm[128];
  __shared__ float red[128];
  const unsigned short* xb = x + (size_t)pn * 128 * 512;
  for (int c = wid; c < 128; c += 4) {
    const unsigned short* xp = xb + (size_t)c * 512;
    float s = 0.f;
#pragma unroll
    for (int r = 0; r < 4; ++r) {
      const unsigned v = *(const unsigned*)(xp + lane * 2 + r * 128);
      s += bf2f((unsigned short)(v & 0xffff)) + bf2f((unsigned short)(v >> 16));
    }
#pragma unroll
    for (int m = 32; m >= 1; m >>= 1) s += __shfl_xor(s, m);
    if (lane == 0) fm[c] = s * (1.f / 512.f);
  }
  __syncthreads();
  if (tid < 128) red[tid] = fm[tid] * fm[tid];
  __syncthreads();
  for (int step = 64; step > 0; step >>= 1) {
    if (tid < step) red[tid] += red[tid + step];
    __syncthreads();
  }
  const float inv = 1.f / fmaxf(sqrtf(red[0]), 1e-12f);
  if (tid < 128) {
    const float v = fm[tid] * inv;
    qk[(size_t)pn * 128 + tid] = v;
    if (pn < 128) qkT[(size_t)tid * 128 + pn] = v;
  }
}

// ---------------- 1/||ref row|| ---------------------------------------------
__global__ __launch_bounds__(256) void refnorm_k(const float* __restrict__ rf,
    float* __restrict__ rinv) {
  const int n = blockIdx.x;
  float s = 0.f;
  for (int i = threadIdx.x; i < 2304; i += 256) {
    float v = rf[(size_t)n * 2304 + i];
    s += v * v;
  }
  __shared__ float red[256];
  red[threadIdx.x] = s;
  __syncthreads();
  for (int step = 128; step > 0; step >>= 1) {
    if (threadIdx.x < step) red[threadIdx.x] += red[threadIdx.x + step];
    __syncthreads();
  }
  if (threadIdx.x == 0) rinv[n] = 1.f / fmaxf(sqrtf(red[0]), 1e-12f);
}

// ---------------- rfT[k][n] = reff[n][k] * rinv[n] --------------------------
__global__ __launch_bounds__(256) void reft_k(const float* __restrict__ rf,
    const float* __restrict__ rinv, float* __restrict__ rfT) {
  const int flat = blockIdx.x * 256 + threadIdx.x;
  const int n = flat / 2304, k = flat - n * 2304;
  rfT[(size_t)k * 128 + n] = rf[flat] * rinv[n];
}

// ---------------- score_neg = q @ MoCoQueue (8 rows/block) ------------------
__global__ __launch_bounds__(256) void sneg2_k(const float* __restrict__ qkT,
    const float* __restrict__ moco, float* __restrict__ out) {
  const int j = blockIdx.x * 256 + threadIdx.x;
  const int n0 = blockIdx.y * 8;
  float acc[8] = {0.f};
#pragma unroll 4
  for (int k = 0; k < 128; ++k) {
    const float rv = moco[(size_t)k * 2048 + j];
    const float* qp = qkT + (size_t)k * 128 + n0;
#pragma unroll
    for (int i = 0; i < 8; ++i) acc[i] = fmaf(qp[i], rv, acc[i]);
  }
#pragma unroll
  for (int i = 0; i < 8; ++i) out[(size_t)(n0 + i) * 2048 + j] = acc[i];
}

// ---------------- score_ref split-K: partial over k-chunk -------------------
template<int KCH>
__global__ __launch_bounds__(256) void sref3_k(const float* __restrict__ rfT,
    const float* __restrict__ rq, float* __restrict__ part) {
  const int j = blockIdx.x * 256 + threadIdx.x;
  const int n0 = blockIdx.y * 8;
  const int kc = blockIdx.z;
  const int kbeg = kc * KCH;
  float acc[8] = {0.f};
#pragma unroll 4
  for (int k = kbeg; k < kbeg + KCH; ++k) {
    const float rv = rq[(size_t)k * 2048 + j];
    const float* rp = rfT + (size_t)k * 128 + n0;
#pragma unroll
    for (int i = 0; i < 8; ++i) acc[i] = fmaf(rp[i], rv, acc[i]);
  }
  float* pb = part + (size_t)kc * (128 * 2048);
#pragma unroll
  for (int i = 0; i < 8; ++i) pb[(size_t)(n0 + i) * 2048 + j] = acc[i];
}

// ---------------- reduce split-K partials -> SREF ---------------------------
template<int NCH>
__global__ __launch_bounds__(256) void sredr_k(const float* __restrict__ part,
    float* __restrict__ out) {
  const int j = blockIdx.x * 256 + threadIdx.x;
  const int n = blockIdx.y;
  const size_t off = (size_t)n * 2048 + j;
  float s = 0.f;
#pragma unroll
  for (int c = 0; c < NCH; ++c) s += part[(size_t)c * (128 * 2048) + off];
  out[off] = s;
}

// ---------------- top-5 per row of masked score_ref -------------------------
__global__ __launch_bounds__(256) void topk_k(const float* __restrict__ sref,
    const float* __restrict__ iq, const int* __restrict__ idxs,
    int* __restrict__ top) {
  const int n = blockIdx.x;
  const float target = (float)idxs[n];
  float vals[8];
#pragma unroll
  for (int r = 0; r < 8; ++r) {
    const int j = threadIdx.x + r * 256;
    const bool m = (iq[j] == target);
    vals[r] = m ? -__builtin_inff() : sref[(size_t)n * 2048 + j];
  }
  __shared__ float sv[256];
  __shared__ int si[256];
  __shared__ int chosen[5];
  for (int rnd = 0; rnd < 5; ++rnd) {
    float bv = -__builtin_inff();
    int bi = 1 << 30;
#pragma unroll
    for (int r = 0; r < 8; ++r) {
      const int j = threadIdx.x + r * 256;
      bool taken = false;
      for (int t = 0; t < rnd; ++t) taken |= (chosen[t] == j);
      const float v = vals[r];
      if (!taken && (v > bv || (v == bv && j < bi))) { bv = v; bi = j; }
    }
    sv[threadIdx.x] = bv; si[threadIdx.x] = bi;
    __syncthreads();
    for (int step = 128; step > 0; step >>= 1) {
      if (threadIdx.x < step) {
        const float ov = sv[threadIdx.x + step];
        const int oi = si[threadIdx.x + step];
        if (ov > sv[threadIdx.x] || (ov == sv[threadIdx.x] && oi < si[threadIdx.x])) {
          sv[threadIdx.x] = ov; si[threadIdx.x] = oi;
        }
      }
      __syncthreads();
    }
    if (threadIdx.x == 0) chosen[rnd] = si[0];
    __syncthreads();
  }
  if (threadIdx.x < 5) top[n * 5 + threadIdx.x] = chosen[threadIdx.x];
}

// ---------------- score_pos + first columns ---------------------------------
__global__ __launch_bounds__(128) void spos_k(const float* __restrict__ qk,
    float* __restrict__ out) {
  const int n = threadIdx.x;
  float s = 0.f;
  for (int c = 0; c < 128; ++c)
    s = fmaf(qk[(size_t)n * 128 + c], qk[(size_t)(NIMG + n) * 128 + c], s);
  out[(size_t)n * 2049] = s;
  out[(size_t)NIMG * 2049 + (size_t)n * 2049] = 1.f;
}

// ---------------- final assembly --------------------------------------------
__global__ __launch_bounds__(256) void asm_k(const float* __restrict__ sneg,
    const float* __restrict__ sref, const float* __restrict__ iq,
    const int* __restrict__ idxs, const int* __restrict__ top,
    float* __restrict__ out) {
  const int n = blockIdx.y;
  const int j = blockIdx.x * 256 + threadIdx.x;
  const int t0 = top[n * 5 + 0], t1 = top[n * 5 + 1], t2 = top[n * 5 + 2];
  const int t3 = top[n * 5 + 3], t4 = top[n * 5 + 4];
  const float target = (float)idxs[n];
  const bool m = (iq[j] == target);
  const float sr = sref[(size_t)n * 2048 + j];
  const float sr2 = m ? 1.f : sr;
  const bool istop = (j == t0) | (j == t1) | (j == t2) | (j == t3) | (j == t4);
  const float wgt = istop ? 1.f : -1.f;
  out[(size_t)n * 2049 + 1 + j] = sneg[(size_t)n * 2048 + j] * sr2 * wgt;
  const float mf = istop ? 1.f : (m ? 1.f : 0.f);
  out[(size_t)NIMG * 2049 + (size_t)n * 2049 + 1 + j] = mf;
}

// ---------------------------------------------------------------------------
extern "C" void kernel_launch(void* const* d_in, const int* in_sizes, int n_in,
                              void* d_out, int out_size, void* d_ws, size_t ws_size,
                              hipStream_t stream) {
  const float* feats = (const float*)d_in[0];
  const float* reff  = (const float*)d_in[1];
  const int*   idxs  = (const int*)d_in[2];
  const float* moco  = (const float*)d_in[3];
  const float* refq  = (const float*)d_in[4];
  const float* iq    = (const float*)d_in[5];
  const float* w[4]  = {(const float*)d_in[6],  (const float*)d_in[10],
                        (const float*)d_in[14], (const float*)d_in[18]};
  const float* b[4]  = {(const float*)d_in[7],  (const float*)d_in[11],
                        (const float*)d_in[15], (const float*)d_in[19]};
  const float* g[4]  = {(const float*)d_in[8],  (const float*)d_in[12],
                        (const float*)d_in[16], (const float*)d_in[20]};
  const float* be[4] = {(const float*)d_in[9],  (const float*)d_in[13],
                        (const float*)d_in[17], (const float*)d_in[21]};
  float* out = (float*)d_out;

  // workspace layout
  const size_t BIG = 33554432;  // 2*128*131072 elements
  unsigned short* X = (unsigned short*)d_ws;            // BIG bf16
  unsigned short* Y = X + BIG;                          // BIG bf16
  float* ST   = (float*)(Y + BIG);  // 4 layers x 512
  unsigned short* WB2 = (unsigned short*)(ST + 2048);   // 16*64
  unsigned short* WB3 = WB2 + 1024;                     // 64*160
  unsigned short* WB4 = WB3 + 10240;                    // 128*576
  float* QK   = (float*)(WB4 + 73728);                  // 2*128*128
  float* QKT  = QK + 32768;         // 128*128
  float* RINV = QKT + 16384;        // 128
  float* RFT  = RINV + 128;         // 2304*128
  float* SNEG = RFT + 294912;       // 128*2048
  float* SREF = SNEG + 262144;      // 128*2048
  int*   TOP  = (int*)(SREF + 262144);                  // 128*5
  float* SPART = (float*)(TOP + 256);                   // 6 x 1M floats
  // stats partials alias the (dead-until-head) SNEG area: 2 x 131072 floats
  float* PART1 = SNEG;
  float* PART2 = SNEG + 131072;

  wtr4_k<<<288, 256, 0, stream>>>(w[1], w[2], w[3], WB2, WB3, WB4);

  // ---- layer 1: (1 -> 4), 1024x128 -> 512x64, rolling-row register conv ----
  conv1s_k<<<dim3(4, 1, 256), 256, 0, stream>>>(feats, w[0], b[0], Y, PART1, PART2);
  redstat_k<<<8, 256, 0, stream>>>(PART1, PART2, ST, 512);
  bnpool3_k<4, 512, 64, 8><<<dim3(4, 4, 256), 256, 0, stream>>>(Y, ST, g[0], be[0], X,
                                                                1.f / (128.f * 32768.f));
  // ---- layer 2: (4 -> 16), 512x64 -> 256x32 via implicit MFMA -------------
  cgemmi_k<4, 512, 64, 16, 256, 64, 64, 16, 64, 16>
      <<<dim3(32, 256), 256, 0, stream>>>(X, WB2, b[1], Y, PART1, PART2);
  redstat_k<<<32, 256, 0, stream>>>(PART1, PART2, ST + 512, 32 * 128);
  bnpool3_k<16, 256, 32, 4><<<dim3(2, 16, 256), 256, 0, stream>>>(Y, ST + 512, g[1], be[1], X,
                                                                  1.f / (128.f * 8192.f));
  // ---- layer 3: (16 -> 64), 256x32 -> 128x16 via implicit MFMA ------------
  cgemmi_k<16, 256, 32, 64, 256, 160, 32, 64, 64, 64>
      <<<dim3(8, 256), 256, 0, stream>>>(X, WB3, b[2], Y, PART1, PART2);
  redstat_k<<<128, 256, 0, stream>>>(PART1, PART2, ST + 1024, 8 * 128);
  bnpool3_k<64, 128, 16, 2><<<dim3(1, 64, 256), 256, 0, stream>>>(Y, ST + 1024, g[2], be[2], X,
                                                                  1.f / (128.f * 2048.f));
  // ---- layer 4: (64 -> 128), 128x16 -> 64x8 via implicit MFMA -------------
  cgemmi_k<64, 128, 16, 128, 128, 576, 64, 32, 128, 128>
      <<<dim3(4, 256), 256, 0, stream>>>(X, WB4, b[3], Y, PART1, PART2);
  redstat_k<<<256, 256, 0, stream>>>(PART1, PART2, ST + 1536, 4 * 128);
  bnpool3_k<128, 64, 8, 1><<<dim3(1, 128, 256), 256, 0, stream>>>(Y, ST + 1536, g[3], be[3], X,
                                                                  1.f / (128.f * 512.f));

  // ---- head ----
  feat2_k<<<256, 256, 0, stream>>>(X, QK, QKT);
  refnorm_k<<<128, 256, 0, stream>>>(reff, RINV);
  reft_k<<<1152, 256, 0, stream>>>(reff, RINV, RFT);
  sneg2_k<<<dim3(8, 16), 256, 0, stream>>>(QKT, moco, SNEG);
  sref3_k<384><<<dim3(8, 16, 6), 256, 0, stream>>>(RFT, refq, SPART);
  sredr_k<6><<<dim3(8, 128), 256, 0, stream>>>(SPART, SREF);
  topk_k<<<128, 256, 0, stream>>>(SREF, iq, idxs, TOP);
  spos_k<<<1, 128, 0, stream>>>(QK, out);
  asm_k<<<dim3(8, 128), 256, 0, stream>>>(SNEG, SREF, iq, idxs, TOP, out);
}